// Round 9
// baseline (892.611 us; speedup 1.0000x reference)
//
#include <hip/hip_runtime.h>
#include <math.h>

// Problem constants
#define LL   4096      // H*W
#define DI   128       // 2*C
#define CC   64        // C
#define BB   8         // batch
#define KK   4         // scan directions
#define LB   32768     // pixels per instance
#define NPIX 2097152   // B*H*W*C elements of s
#define EPSF 1e-5f

// Workspace layout (floats, per instance)
#define OFF_XCIN   ((size_t)0)
#define OFF_XCONV  ((size_t)4194304)
#define OFF_XCONVT ((size_t)8388608)
#define OFF_Z      ((size_t)12582912)
#define OFF_Y      ((size_t)16777216)
#define OFF_YT     ((size_t)20971520)
#define OFF_XDBL   ((size_t)25165824)
#define ISTRIDE    ((size_t)25952256)   // floats per instance
// Aliases (lifetime-disjoint reuse):
#define OFF_YCOMBT OFF_XCIN             // xcin dead after k2; ycombT (d-major) by k3c
#define OFF_XNEW   OFF_YT               // yT dead after k3c; xnew (pixel-major) by k4a
#define OFF_SB     OFF_Y                // y dead after k3c; sbuf by k4b

__device__ __forceinline__ float sigmoidf_(float x){ return 1.f/(1.f+expf(-x)); }
__device__ __forceinline__ float softplusf_(float x){ return fmaxf(x,0.f) + log1pf(expf(-fabsf(x))); }
__device__ __forceinline__ float geluf_(float x){ return 0.5f*x*(1.f+erff(x*0.70710678118f)); }

#define LD16(dst, ptr) { const float4* p4_=(const float4*)(ptr);                 \
  float4 v0_=p4_[0], v1_=p4_[1], v2_=p4_[2], v3_=p4_[3];                         \
  dst[0]=v0_.x; dst[1]=v0_.y; dst[2]=v0_.z; dst[3]=v0_.w;                        \
  dst[4]=v1_.x; dst[5]=v1_.y; dst[6]=v1_.z; dst[7]=v1_.w;                        \
  dst[8]=v2_.x; dst[9]=v2_.y; dst[10]=v2_.z; dst[11]=v2_.w;                      \
  dst[12]=v3_.x; dst[13]=v3_.y; dst[14]=v3_.z; dst[15]=v3_.w; }
#define LD16R(dst, ptr) { const float4* p4_=(const float4*)(ptr);                \
  float4 v0_=p4_[0], v1_=p4_[1], v2_=p4_[2], v3_=p4_[3];                         \
  dst[15]=v0_.x; dst[14]=v0_.y; dst[13]=v0_.z; dst[12]=v0_.w;                    \
  dst[11]=v1_.x; dst[10]=v1_.y; dst[9]=v1_.z;  dst[8]=v1_.w;                     \
  dst[7]=v2_.x;  dst[6]=v2_.y;  dst[5]=v2_.z;  dst[4]=v2_.w;                     \
  dst[3]=v3_.x;  dst[2]=v3_.y;  dst[1]=v3_.z;  dst[0]=v3_.w; }

// K1 v3 (known-good): block = 4 waves over SAME 64 pixels (lane=pixel). Wave ch
// handles a 64-row chunk of the 256 in_proj outputs (ch 0-1: xc, ch 2-3: z).
__global__ __launch_bounds__(256) void k1_ln_inproj(
    const float* __restrict__ xmag, const float* __restrict__ xph,
    const float* __restrict__ n1w_, const float* __restrict__ n1b_,
    const float* __restrict__ ipw_, float* __restrict__ ws)
{
  const int i = blockIdx.y;
  const float* xin = i ? xph : xmag;
  const float* n1w = n1w_ + i*CC;
  const float* n1b = n1b_ + i*CC;
  const float* ipw = ipw_ + i*2*DI*CC;
  float* base = ws + (size_t)i*ISTRIDE;
  const int t = threadIdx.x, lane = t & 63;
  const int ch = __builtin_amdgcn_readfirstlane(t >> 6);
  const int p = blockIdx.x*64 + lane;
  const int b = p >> 12, l = p & (LL-1);
  float hn[CC];
  LD16(hn, xin + (size_t)p*CC);
  LD16((hn+16), xin + (size_t)p*CC + 16);
  LD16((hn+32), xin + (size_t)p*CC + 32);
  LD16((hn+48), xin + (size_t)p*CC + 48);
  float s1=0.f, s2=0.f;
  #pragma unroll
  for(int c=0;c<CC;++c){ s1 += hn[c]; s2 += hn[c]*hn[c]; }
  const float mu = s1*(1.f/CC);
  const float rs = rsqrtf(s2*(1.f/CC) - mu*mu + EPSF);
  #pragma unroll
  for(int c=0;c<CC;++c) hn[c] = (hn[c]-mu)*rs*n1w[c] + n1b[c];
  if(ch < 2){
    float* xcb = base + OFF_XCIN + (size_t)b*DI*LL + l;
    #pragma unroll 2
    for(int jj=0;jj<64;++jj){
      const int j = ch*64 + jj;
      const float* wr = ipw + j*CC;
      float acc = 0.f;
      #pragma unroll
      for(int c=0;c<CC;++c) acc += hn[c]*wr[c];
      xcb[(size_t)j*LL] = acc;
    }
  } else {
    float* zT = base + OFF_Z;
    #pragma unroll 2
    for(int jj=0;jj<64;++jj){
      const int d = (ch-2)*64 + jj;
      const float* wr = ipw + (DI+d)*CC;
      float acc = 0.f;
      #pragma unroll
      for(int c=0;c<CC;++c) acc += hn[c]*wr[c];
      zT[(size_t)d*LB + p] = acc * sigmoidf_(acc);
    }
  }
}

// K2: depthwise 3x3 conv + silu; per (b,d) 64x64 tile via LDS; row-major + transposed out
__global__ __launch_bounds__(256) void k2_dwconv(
    const float* __restrict__ cw_, float* __restrict__ ws)
{
  const int i = blockIdx.y;
  const int bd = blockIdx.x;
  const int d = bd & (DI-1);
  const float* cw = cw_ + i*DI*9 + d*9;
  const float* xcin  = ws + (size_t)i*ISTRIDE + OFF_XCIN  + (size_t)bd*LL;
  float* xconv  = ws + (size_t)i*ISTRIDE + OFF_XCONV  + (size_t)bd*LL;
  float* xconvT = ws + (size_t)i*ISTRIDE + OFF_XCONVT + (size_t)bd*LL;
  __shared__ float tin[64*65];
  __shared__ float tout[64*65];
  const int t = threadIdx.x;
  float w9[9];
  #pragma unroll
  for(int q=0;q<9;++q) w9[q] = cw[q];
  for(int idx=t; idx<4096; idx+=256)
    tin[(idx>>6)*65 + (idx&63)] = xcin[idx];
  __syncthreads();
  const int w = t & 63, hb = (t>>6)*16;
  #pragma unroll
  for(int r=0;r<16;++r){
    const int h = hb + r;
    float acc = 0.f;
    #pragma unroll
    for(int dy=0;dy<3;++dy){
      const int hh = h + dy - 1;
      if(hh>=0 && hh<64){
        #pragma unroll
        for(int dx=0;dx<3;++dx){
          const int ww = w + dx - 1;
          if(ww>=0 && ww<64) acc += tin[hh*65+ww]*w9[dy*3+dx];
        }
      }
    }
    const float o = acc * sigmoidf_(acc);
    tout[h*65+w] = o;
    xconv[h*64+w] = o;
  }
  __syncthreads();
  const int hcol = t & 63, wb = (t>>6)*16;
  #pragma unroll
  for(int r=0;r<16;++r){
    const int wp = wb + r;
    xconvT[wp*64 + hcol] = tout[hcol*65 + wp];
  }
}

// K3a: x_dbl = x_proj(xs) -> (dts[4], Bs, Cs) per (b,k,scan-pos)
__global__ __launch_bounds__(256) void k3a_xproj(
    const float* __restrict__ xpw_, float* __restrict__ ws)
{
  const int i = blockIdx.z;
  const int b = blockIdx.y >> 2;
  const int k = blockIdx.y & 3;
  const int l = blockIdx.x*256 + threadIdx.x;
  const float* src = ws + (size_t)i*ISTRIDE + ((k&1)? OFF_XCONVT : OFF_XCONV) + (size_t)b*DI*LL;
  const int ridx = (k>=2) ? (LL-1-l) : l;
  const float* xpw = xpw_ + i*KK*6*DI + k*6*DI;
  float acc[6] = {0,0,0,0,0,0};
  for(int d=0; d<DI; ++d){
    const float xv = src[(size_t)d*LL + ridx];
    #pragma unroll
    for(int c=0;c<6;++c) acc[c] += xv * xpw[c*DI + d];
  }
  float* xdbl = ws + (size_t)i*ISTRIDE + OFF_XDBL + (size_t)(b*KK+k)*6*LL;
  #pragma unroll
  for(int c=0;c<6;++c) xdbl[(size_t)c*LL + l] = acc[c];
}

// K3b: paired fwd/bwd selective scan; phase-split regs + wave shuffle scan, 1 barrier.
__global__ __launch_bounds__(256,3) void k3b_scan(
    const float* __restrict__ dtw_, const float* __restrict__ dtb_,
    const float* __restrict__ alog_, const float* __restrict__ Ds_,
    float* __restrict__ ws)
{
  const int gid = blockIdx.x;           // b*256 + kp*128 + d
  const int i = blockIdx.y;
  const int d  = gid & (DI-1);
  const int kp = (gid >> 7) & 1;
  const int b  = gid >> 8;
  const int t = threadIdx.x, lane = t & 63, wv = t >> 6;
  float* base = ws + (size_t)i*ISTRIDE;
  const float* src = base + (kp? OFF_XCONVT : OFF_XCONV) + (size_t)(b*DI+d)*LL;
  float*       dst = base + (kp? OFF_YT    : OFF_Y    ) + (size_t)(b*DI+d)*LL;
  const float* xdF = base + OFF_XDBL + (size_t)(b*KK+kp  )*6*LL;
  const float* xdB = base + OFF_XDBL + (size_t)(b*KK+kp+2)*6*LL;
  const int kdF = kp*DI + d, kdB = (kp+2)*DI + d;
  const float4 wF = ((const float4*)dtw_)[i*KK*DI + kdF];
  const float4 wB = ((const float4*)dtw_)[i*KK*DI + kdB];
  const float biasF = dtb_[i*KK*DI + kdF], biasB = dtb_[i*KK*DI + kdB];
  const float AvF = -expf(alog_[i*KK*DI + kdF]);
  const float AvB = -expf(alog_[i*KK*DI + kdB]);
  const float Dsum = Ds_[i*KK*DI + kdF] + Ds_[i*KK*DI + kdB];
  const int l0 = t*16;
  const int s0 = LL - 16 - l0;

  float vX[16], aF[16], bF[16], aB[16], bB[16];
  float fA = 1.f, fB = 0.f, gA = 1.f, gB = 0.f;
  LD16(vX, src + l0);

  {
    float pre[16], r0[16];
    LD16(r0, xdF + 0*LL + l0);
    #pragma unroll
    for(int j=0;j<16;++j) pre[j] = biasF + wF.x*r0[j];
    LD16(r0, xdF + 1*LL + l0);
    #pragma unroll
    for(int j=0;j<16;++j) pre[j] += wF.y*r0[j];
    LD16(r0, xdF + 2*LL + l0);
    #pragma unroll
    for(int j=0;j<16;++j) pre[j] += wF.z*r0[j];
    LD16(r0, xdF + 3*LL + l0);
    #pragma unroll
    for(int j=0;j<16;++j) pre[j] += wF.w*r0[j];
    LD16(r0, xdF + 4*LL + l0);   // Bs
    #pragma unroll
    for(int j=0;j<16;++j){
      const float delta = softplusf_(pre[j]);
      aF[j] = expf(delta*AvF);
      bF[j] = delta*r0[j]*vX[j];
      fB = fB*aF[j] + bF[j];
      fA *= aF[j];
    }
  }
  {
    float pre[16], r0[16];
    LD16R(r0, xdB + 0*LL + s0);
    #pragma unroll
    for(int j=0;j<16;++j) pre[j] = biasB + wB.x*r0[j];
    LD16R(r0, xdB + 1*LL + s0);
    #pragma unroll
    for(int j=0;j<16;++j) pre[j] += wB.y*r0[j];
    LD16R(r0, xdB + 2*LL + s0);
    #pragma unroll
    for(int j=0;j<16;++j) pre[j] += wB.z*r0[j];
    LD16R(r0, xdB + 3*LL + s0);
    #pragma unroll
    for(int j=0;j<16;++j) pre[j] += wB.w*r0[j];
    LD16R(r0, xdB + 4*LL + s0);  // Bs reversed
    #pragma unroll
    for(int j=15;j>=0;--j){
      const float delta = softplusf_(pre[j]);
      aB[j] = expf(delta*AvB);
      bB[j] = delta*r0[j]*vX[j];
      gB = gB*aB[j] + bB[j];
      gA *= aB[j];
    }
  }

  #pragma unroll
  for(int off=1; off<64; off<<=1){
    const float aL = __shfl_up(fA, off);
    const float bL = __shfl_up(fB, off);
    if(lane >= off){ fB = bL*fA + fB; fA = aL*fA; }
  }
  float pA = __shfl_up(fA, 1), pB = __shfl_up(fB, 1);
  if(lane==0){ pA=1.f; pB=0.f; }
  #pragma unroll
  for(int off=1; off<64; off<<=1){
    const float aR = __shfl_down(gA, off);
    const float bR = __shfl_down(gB, off);
    if(lane + off < 64){ gB = gA*bR + gB; gA = gA*aR; }
  }
  float qA = __shfl_down(gA, 1), qB = __shfl_down(gB, 1);
  if(lane==63){ qA=1.f; qB=0.f; }

  __shared__ float wAg[4], wBg[4], vAg[4], vBg[4];
  if(lane==63){ wAg[wv]=fA; wBg[wv]=fB; }
  if(lane==0){ vAg[wv]=gA; vBg[wv]=gB; }
  __syncthreads();
  float eB=0.f;
  for(int u=0; u<wv; ++u){ eB = wAg[u]*eB + wBg[u]; }
  float rB=0.f;
  for(int u=3; u>wv; --u){ rB = vAg[u]*rB + vBg[u]; }

  float hf = pA*eB + pB;
  float hb = qA*rB + qB;

  float out[16], cc[16];
  LD16(cc, xdF + 5*LL + l0);
  #pragma unroll
  for(int j=0;j<16;++j){
    hf = aF[j]*hf + bF[j];
    out[j] = hf*cc[j] + Dsum*vX[j];
  }
  LD16R(cc, xdB + 5*LL + s0);
  #pragma unroll
  for(int j=15;j>=0;--j){
    hb = aB[j]*hb + bB[j];
    out[j] += hb*cc[j];
  }
  float4* d4 = (float4*)(dst + l0);
  d4[0] = make_float4(out[0],out[1],out[2],out[3]);
  d4[1] = make_float4(out[4],out[5],out[6],out[7]);
  d4[2] = make_float4(out[8],out[9],out[10],out[11]);
  d4[3] = make_float4(out[12],out[13],out[14],out[15]);
}

// K3c: combine y + transpose(yT) into d-major ycombT[d][b*LL+l].
__global__ __launch_bounds__(256) void k3c_combine(float* __restrict__ ws)
{
  const int i = blockIdx.y;
  const int b = blockIdx.x >> 4;
  const int tile = blockIdx.x & 15;
  const int h0 = (tile >> 2) * 16, w0 = (tile & 3) * 16;
  const int t = threadIdx.x;
  float* base = ws + (size_t)i*ISTRIDE;
  const float* y  = base + OFF_Y;
  const float* yT = base + OFF_YT;
  float* ycT = base + OFF_YCOMBT;
  __shared__ float ytile[16*16*16];
  __shared__ float ytT[16*16*17];
  const int r0 = t >> 4, c0 = t & 15;
  const int hi = t >> 4, wi = t & 15;
  const int l = (h0 + hi)*64 + (w0 + wi);
  for(int dc=0; dc<8; ++dc){
    #pragma unroll 4
    for(int dd=0; dd<16; ++dd){
      const int d = dc*16 + dd;
      const size_t rb = (size_t)(b*DI + d)*LL;
      ytile[dd*256 + t] = y[rb + (size_t)(h0 + r0)*64 + (w0 + c0)];
      ytT[dd*272 + r0*17 + c0] = yT[rb + (size_t)(w0 + r0)*64 + (h0 + c0)];
    }
    __syncthreads();
    #pragma unroll 4
    for(int dd=0; dd<16; ++dd){
      const int d = dc*16 + dd;
      ycT[(size_t)d*LB + b*LL + l] = ytile[dd*256 + t] + ytT[dd*272 + wi*17 + hi];
    }
    __syncthreads();
  }
}

// K4a: block = 4 waves = 2 pixel-groups x 2 K-chunks. lane = pixel.
__global__ __launch_bounds__(256) void k4a_proj(
    const float* __restrict__ xmag, const float* __restrict__ xph,
    const float* __restrict__ onw_, const float* __restrict__ onb_,
    const float* __restrict__ opw_, float* __restrict__ ws)
{
  const int i = blockIdx.y;
  const float* xin = i ? xph : xmag;
  const float* onw = onw_ + i*DI;
  const float* onb = onb_ + i*DI;
  const float* opw = opw_ + i*CC*DI;
  float* base = ws + (size_t)i*ISTRIDE;
  const float* ycT = base + OFF_YCOMBT;
  const float* zT  = base + OFF_Z;
  const int t = threadIdx.x, lane = t & 63, wv = t >> 6;
  const int g = wv >> 1;
  const int ch = __builtin_amdgcn_readfirstlane(wv & 1);
  const int p = blockIdx.x*128 + g*64 + lane;
  float yv[64];
  float s1=0.f, s2=0.f;
  #pragma unroll 8
  for(int c=0;c<64;++c){
    const float v = ycT[(size_t)(ch*64+c)*LB + p];
    yv[c]=v; s1+=v; s2+=v*v;
  }
  __shared__ float st[2][64][4];
  st[g][lane][ch*2]=s1; st[g][lane][ch*2+1]=s2;
  __syncthreads();
  const float S1 = st[g][lane][0]+st[g][lane][2];
  const float S2 = st[g][lane][1]+st[g][lane][3];
  const float mu = S1*(1.f/DI);
  const float rs = rsqrtf(S2*(1.f/DI) - mu*mu + EPSF);
  #pragma unroll 8
  for(int c=0;c<64;++c){
    const int d = ch*64+c;
    yv[c] = ((yv[c]-mu)*rs*onw[d] + onb[d]) * zT[(size_t)d*LB + p];
  }
  float acc[64];
  #pragma unroll 2
  for(int o=0;o<64;++o){
    const float* wr = opw + o*DI + ch*64;
    float a = 0.f;
    #pragma unroll
    for(int c=0;c<64;++c) a += yv[c]*wr[c];
    acc[o] = a;
  }
  __shared__ float ab[2][64*65];
  if(ch==0){
    #pragma unroll 8
    for(int o=0;o<64;++o) ab[g][lane*65+o] = acc[o];
  }
  __syncthreads();
  if(ch==1){
    #pragma unroll 8
    for(int o=0;o<64;++o) ab[g][lane*65+o] += acc[o];
  }
  __syncthreads();
  const int pxl = t >> 1, oh = (t & 1)*32;
  const int gg = pxl >> 6, ll = pxl & 63;
  const int pg = blockIdx.x*128 + pxl;
  float* xnew = base + OFF_XNEW + (size_t)pg*CC + oh;
  const float* xi = xin + (size_t)pg*CC + oh;
  #pragma unroll
  for(int q=0;q<8;++q){
    float4 v;
    v.x = ab[gg][ll*65+oh+4*q  ] + xi[4*q  ];
    v.y = ab[gg][ll*65+oh+4*q+1] + xi[4*q+1];
    v.z = ab[gg][ll*65+oh+4*q+2] + xi[4*q+2];
    v.w = ab[gg][ll*65+oh+4*q+3] + xi[4*q+3];
    ((float4*)xnew)[q] = v;
  }
}

// K4b v5: block = 4 waves over SAME 64 pixels (lane=pixel). fc1: wave's 64 rows
// (4-at-a-time s_load streams) -> GELU -> LDS g[256][64]; ONE barrier; fc2: wave
// owns o-chunk [16wv,+16), weights read DIRECTLY from f2w (d_in, row-major
// [o][j]) as uniform 4-float row chunks. No device-written weight buffer.
__global__ __launch_bounds__(256) void k4b_mlp(
    const float* __restrict__ n2w_, const float* __restrict__ n2b_,
    const float* __restrict__ f1w_, const float* __restrict__ f1b_,
    const float* __restrict__ f2w_, const float* __restrict__ f2b_,
    float* __restrict__ ws)
{
  const int i = blockIdx.y;
  const float* n2w = n2w_ + i*CC;
  const float* n2b = n2b_ + i*CC;
  const float* f1w = f1w_ + i*4*CC*CC;
  const float* f1b = f1b_ + i*4*CC;
  const float* f2w = f2w_ + i*4*CC*CC;   // [o][j] = [64][256]
  const float* f2b = f2b_ + i*CC;
  float* base = ws + (size_t)i*ISTRIDE;
  const float* xnew = base + OFF_XNEW;
  const int t = threadIdx.x, lane = t & 63;
  const int wv = __builtin_amdgcn_readfirstlane(t >> 6);
  const int p = blockIdx.x*64 + lane;
  float h2[64];
  LD16(h2, xnew + (size_t)p*CC);
  LD16((h2+16), xnew + (size_t)p*CC + 16);
  LD16((h2+32), xnew + (size_t)p*CC + 32);
  LD16((h2+48), xnew + (size_t)p*CC + 48);
  float s1=0.f, s2=0.f;
  #pragma unroll
  for(int c=0;c<CC;++c){ s1 += h2[c]; s2 += h2[c]*h2[c]; }
  const float mu = s1*(1.f/CC);
  const float rs = rsqrtf(s2*(1.f/CC) - mu*mu + EPSF);
  #pragma unroll
  for(int c=0;c<CC;++c) h2[c] = (h2[c]-mu)*rs*n2w[c] + n2b[c];

  __shared__ float g[256*64];   // 64 KB: g[j][pixel-lane]
  for(int mg=0; mg<16; ++mg){
    const int j = wv*64 + mg*4;
    const float* w0 = f1w + (j+0)*CC;
    const float* w1 = f1w + (j+1)*CC;
    const float* w2 = f1w + (j+2)*CC;
    const float* w3 = f1w + (j+3)*CC;
    float a0=f1b[j+0], a1=f1b[j+1], a2=f1b[j+2], a3=f1b[j+3];
    #pragma unroll
    for(int c=0;c<CC;++c){
      const float h = h2[c];
      a0 += h*w0[c]; a1 += h*w1[c]; a2 += h*w2[c]; a3 += h*w3[c];
    }
    g[(j+0)*64 + lane] = geluf_(a0);
    g[(j+1)*64 + lane] = geluf_(a1);
    g[(j+2)*64 + lane] = geluf_(a2);
    g[(j+3)*64 + lane] = geluf_(a3);
  }
  __syncthreads();

  float acc[16];
  #pragma unroll
  for(int o=0;o<16;++o) acc[o] = 0.f;
  for(int jg=0; jg<64; ++jg){
    const int j = jg*4;
    const float g0 = g[(j+0)*64 + lane];
    const float g1 = g[(j+1)*64 + lane];
    const float g2 = g[(j+2)*64 + lane];
    const float g3 = g[(j+3)*64 + lane];
    #pragma unroll
    for(int o=0;o<16;++o){
      const float4 w4 = *(const float4*)(f2w + (size_t)(wv*16+o)*256 + j);
      acc[o] += g0*w4.x + g1*w4.y + g2*w4.z + g3*w4.w;
    }
  }
  const float* xr = xnew + (size_t)p*CC + wv*16;
  float* sb = base + OFF_SB + (size_t)p*CC + wv*16;
  #pragma unroll
  for(int q=0;q<4;++q){
    const float4 x4 = ((const float4*)xr)[q];
    float4 v;
    v.x = acc[4*q  ] + f2b[wv*16+4*q  ] + x4.x;
    v.y = acc[4*q+1] + f2b[wv*16+4*q+1] + x4.y;
    v.z = acc[4*q+2] + f2b[wv*16+4*q+2] + x4.z;
    v.w = acc[4*q+3] + f2b[wv*16+4*q+3] + x4.w;
    ((float4*)sb)[q] = v;
  }
}

// K5: s = inst0 + inst1; write to both output halves
__global__ __launch_bounds__(256) void k5_final(
    const float* __restrict__ ws, float* __restrict__ out)
{
  const int idx = blockIdx.x*256 + threadIdx.x;
  const float v = ws[OFF_SB + idx] + ws[ISTRIDE + OFF_SB + idx];
  out[idx] = v;
  out[NPIX + idx] = v;
}

extern "C" void kernel_launch(void* const* d_in, const int* in_sizes, int n_in,
                              void* d_out, int out_size, void* d_ws, size_t ws_size,
                              hipStream_t stream)
{
  const float* mag  = (const float*)d_in[0];
  const float* ph   = (const float*)d_in[1];
  const float* n1w  = (const float*)d_in[2];
  const float* n1b  = (const float*)d_in[3];
  const float* ipw  = (const float*)d_in[4];
  const float* cw   = (const float*)d_in[5];
  const float* xpw  = (const float*)d_in[6];
  const float* dtw  = (const float*)d_in[7];
  const float* dtb  = (const float*)d_in[8];
  const float* alog = (const float*)d_in[9];
  const float* Ds   = (const float*)d_in[10];
  const float* onw  = (const float*)d_in[11];
  const float* onb  = (const float*)d_in[12];
  const float* opw  = (const float*)d_in[13];
  const float* n2w  = (const float*)d_in[14];
  const float* n2b  = (const float*)d_in[15];
  const float* f1w  = (const float*)d_in[16];
  const float* f1b  = (const float*)d_in[17];
  const float* f2w  = (const float*)d_in[18];
  const float* f2b  = (const float*)d_in[19];
  float* ws = (float*)d_ws;
  float* out = (float*)d_out;

  k1_ln_inproj<<<dim3(512,2),  256, 0, stream>>>(mag, ph, n1w, n1b, ipw, ws);
  k2_dwconv   <<<dim3(1024,2), 256, 0, stream>>>(cw, ws);
  k3a_xproj   <<<dim3(16,32,2),256, 0, stream>>>(xpw, ws);
  k3b_scan    <<<dim3(2048,2), 256, 0, stream>>>(dtw, dtb, alog, Ds, ws);
  k3c_combine <<<dim3(128,2),  256, 0, stream>>>(ws);
  k4a_proj    <<<dim3(256,2),  256, 0, stream>>>(mag, ph, onw, onb, opw, ws);
  k4b_mlp     <<<dim3(512,2),  256, 0, stream>>>(n2w, n2b, f1w, f1b, f2w, f2b, ws);
  k5_final    <<<dim3(8192),   256, 0, stream>>>(ws, out);
}

// Round 10
// 630.029 us; speedup vs baseline: 1.4168x; 1.4168x over previous
//
#include <hip/hip_runtime.h>
#include <math.h>

// Problem constants
#define LL   4096      // H*W
#define DI   128       // 2*C
#define CC   64        // C
#define BB   8         // batch
#define KK   4         // scan directions
#define LB   32768     // pixels per instance
#define NPIX 2097152   // B*H*W*C elements of s
#define EPSF 1e-5f

// Workspace layout (floats, per instance)
#define OFF_XCIN   ((size_t)0)
#define OFF_XCONV  ((size_t)4194304)
#define OFF_XCONVT ((size_t)8388608)
#define OFF_Z      ((size_t)12582912)
#define OFF_Y      ((size_t)16777216)
#define OFF_YT     ((size_t)20971520)
#define OFF_XDBL   ((size_t)25165824)
#define ISTRIDE    ((size_t)25952256)   // floats per instance
// Aliases (lifetime-disjoint reuse):
#define OFF_YCOMBT OFF_XCIN             // xcin dead after k2; ycombT (d-major) by k3c
#define OFF_XNEW   OFF_YT               // yT dead after k3c; xnew (pixel-major) by k4a
#define OFF_SB     OFF_Y                // y dead after k3c; sbuf by k4b

__device__ __forceinline__ float sigmoidf_(float x){ return 1.f/(1.f+expf(-x)); }
__device__ __forceinline__ float softplusf_(float x){ return fmaxf(x,0.f) + log1pf(expf(-fabsf(x))); }
__device__ __forceinline__ float geluf_(float x){ return 0.5f*x*(1.f+erff(x*0.70710678118f)); }

#define LD16(dst, ptr) { const float4* p4_=(const float4*)(ptr);                 \
  float4 v0_=p4_[0], v1_=p4_[1], v2_=p4_[2], v3_=p4_[3];                         \
  dst[0]=v0_.x; dst[1]=v0_.y; dst[2]=v0_.z; dst[3]=v0_.w;                        \
  dst[4]=v1_.x; dst[5]=v1_.y; dst[6]=v1_.z; dst[7]=v1_.w;                        \
  dst[8]=v2_.x; dst[9]=v2_.y; dst[10]=v2_.z; dst[11]=v2_.w;                      \
  dst[12]=v3_.x; dst[13]=v3_.y; dst[14]=v3_.z; dst[15]=v3_.w; }
#define LD16R(dst, ptr) { const float4* p4_=(const float4*)(ptr);                \
  float4 v0_=p4_[0], v1_=p4_[1], v2_=p4_[2], v3_=p4_[3];                         \
  dst[15]=v0_.x; dst[14]=v0_.y; dst[13]=v0_.z; dst[12]=v0_.w;                    \
  dst[11]=v1_.x; dst[10]=v1_.y; dst[9]=v1_.z;  dst[8]=v1_.w;                     \
  dst[7]=v2_.x;  dst[6]=v2_.y;  dst[5]=v2_.z;  dst[4]=v2_.w;                     \
  dst[3]=v3_.x;  dst[2]=v3_.y;  dst[1]=v3_.z;  dst[0]=v3_.w; }

// K1 v4: block = 4 waves over SAME 64 pixels (lane=pixel). Wave ch owns a 64-row
// chunk of the 256 in_proj outputs. Rows processed 4-at-a-time so 4 independent
// s_load weight streams are in flight between waits.
__global__ __launch_bounds__(256) void k1_ln_inproj(
    const float* __restrict__ xmag, const float* __restrict__ xph,
    const float* __restrict__ n1w_, const float* __restrict__ n1b_,
    const float* __restrict__ ipw_, float* __restrict__ ws)
{
  const int i = blockIdx.y;
  const float* xin = i ? xph : xmag;
  const float* n1w = n1w_ + i*CC;
  const float* n1b = n1b_ + i*CC;
  const float* ipw = ipw_ + i*2*DI*CC;
  float* base = ws + (size_t)i*ISTRIDE;
  const int t = threadIdx.x, lane = t & 63;
  const int ch = __builtin_amdgcn_readfirstlane(t >> 6);
  const int p = blockIdx.x*64 + lane;
  const int b = p >> 12, l = p & (LL-1);
  float hn[CC];
  LD16(hn, xin + (size_t)p*CC);
  LD16((hn+16), xin + (size_t)p*CC + 16);
  LD16((hn+32), xin + (size_t)p*CC + 32);
  LD16((hn+48), xin + (size_t)p*CC + 48);
  float s1=0.f, s2=0.f;
  #pragma unroll
  for(int c=0;c<CC;++c){ s1 += hn[c]; s2 += hn[c]*hn[c]; }
  const float mu = s1*(1.f/CC);
  const float rs = rsqrtf(s2*(1.f/CC) - mu*mu + EPSF);
  #pragma unroll
  for(int c=0;c<CC;++c) hn[c] = (hn[c]-mu)*rs*n1w[c] + n1b[c];
  if(ch < 2){
    float* xcb = base + OFF_XCIN + (size_t)b*DI*LL + l;
    for(int jg=0;jg<16;++jg){
      const int j = ch*64 + jg*4;
      const float* w0 = ipw + (j+0)*CC;
      const float* w1 = ipw + (j+1)*CC;
      const float* w2 = ipw + (j+2)*CC;
      const float* w3 = ipw + (j+3)*CC;
      float a0=0.f,a1=0.f,a2=0.f,a3=0.f;
      #pragma unroll
      for(int c=0;c<CC;++c){
        const float h = hn[c];
        a0 += h*w0[c]; a1 += h*w1[c]; a2 += h*w2[c]; a3 += h*w3[c];
      }
      xcb[(size_t)(j+0)*LL] = a0;
      xcb[(size_t)(j+1)*LL] = a1;
      xcb[(size_t)(j+2)*LL] = a2;
      xcb[(size_t)(j+3)*LL] = a3;
    }
  } else {
    float* zT = base + OFF_Z;
    for(int jg=0;jg<16;++jg){
      const int d = (ch-2)*64 + jg*4;
      const float* w0 = ipw + (DI+d+0)*CC;
      const float* w1 = ipw + (DI+d+1)*CC;
      const float* w2 = ipw + (DI+d+2)*CC;
      const float* w3 = ipw + (DI+d+3)*CC;
      float a0=0.f,a1=0.f,a2=0.f,a3=0.f;
      #pragma unroll
      for(int c=0;c<CC;++c){
        const float h = hn[c];
        a0 += h*w0[c]; a1 += h*w1[c]; a2 += h*w2[c]; a3 += h*w3[c];
      }
      zT[(size_t)(d+0)*LB + p] = a0 * sigmoidf_(a0);
      zT[(size_t)(d+1)*LB + p] = a1 * sigmoidf_(a1);
      zT[(size_t)(d+2)*LB + p] = a2 * sigmoidf_(a2);
      zT[(size_t)(d+3)*LB + p] = a3 * sigmoidf_(a3);
    }
  }
}

// K2: depthwise 3x3 conv + silu; per (b,d) 64x64 tile via LDS; row-major + transposed out
__global__ __launch_bounds__(256) void k2_dwconv(
    const float* __restrict__ cw_, float* __restrict__ ws)
{
  const int i = blockIdx.y;
  const int bd = blockIdx.x;
  const int d = bd & (DI-1);
  const float* cw = cw_ + i*DI*9 + d*9;
  const float* xcin  = ws + (size_t)i*ISTRIDE + OFF_XCIN  + (size_t)bd*LL;
  float* xconv  = ws + (size_t)i*ISTRIDE + OFF_XCONV  + (size_t)bd*LL;
  float* xconvT = ws + (size_t)i*ISTRIDE + OFF_XCONVT + (size_t)bd*LL;
  __shared__ float tin[64*65];
  __shared__ float tout[64*65];
  const int t = threadIdx.x;
  float w9[9];
  #pragma unroll
  for(int q=0;q<9;++q) w9[q] = cw[q];
  for(int idx=t; idx<4096; idx+=256)
    tin[(idx>>6)*65 + (idx&63)] = xcin[idx];
  __syncthreads();
  const int w = t & 63, hb = (t>>6)*16;
  #pragma unroll
  for(int r=0;r<16;++r){
    const int h = hb + r;
    float acc = 0.f;
    #pragma unroll
    for(int dy=0;dy<3;++dy){
      const int hh = h + dy - 1;
      if(hh>=0 && hh<64){
        #pragma unroll
        for(int dx=0;dx<3;++dx){
          const int ww = w + dx - 1;
          if(ww>=0 && ww<64) acc += tin[hh*65+ww]*w9[dy*3+dx];
        }
      }
    }
    const float o = acc * sigmoidf_(acc);
    tout[h*65+w] = o;
    xconv[h*64+w] = o;
  }
  __syncthreads();
  const int hcol = t & 63, wb = (t>>6)*16;
  #pragma unroll
  for(int r=0;r<16;++r){
    const int wp = wb + r;
    xconvT[wp*64 + hcol] = tout[hcol*65 + wp];
  }
}

// K3a: x_dbl = x_proj(xs) -> (dts[4], Bs, Cs) per (b,k,scan-pos)
__global__ __launch_bounds__(256) void k3a_xproj(
    const float* __restrict__ xpw_, float* __restrict__ ws)
{
  const int i = blockIdx.z;
  const int b = blockIdx.y >> 2;
  const int k = blockIdx.y & 3;
  const int l = blockIdx.x*256 + threadIdx.x;
  const float* src = ws + (size_t)i*ISTRIDE + ((k&1)? OFF_XCONVT : OFF_XCONV) + (size_t)b*DI*LL;
  const int ridx = (k>=2) ? (LL-1-l) : l;
  const float* xpw = xpw_ + i*KK*6*DI + k*6*DI;
  float acc[6] = {0,0,0,0,0,0};
  for(int d=0; d<DI; ++d){
    const float xv = src[(size_t)d*LL + ridx];
    #pragma unroll
    for(int c=0;c<6;++c) acc[c] += xv * xpw[c*DI + d];
  }
  float* xdbl = ws + (size_t)i*ISTRIDE + OFF_XDBL + (size_t)(b*KK+k)*6*LL;
  #pragma unroll
  for(int c=0;c<6;++c) xdbl[(size_t)c*LL + l] = acc[c];
}

// K3b: paired fwd/bwd selective scan; phase-split regs + wave shuffle scan, 1 barrier.
__global__ __launch_bounds__(256,3) void k3b_scan(
    const float* __restrict__ dtw_, const float* __restrict__ dtb_,
    const float* __restrict__ alog_, const float* __restrict__ Ds_,
    float* __restrict__ ws)
{
  const int gid = blockIdx.x;           // b*256 + kp*128 + d
  const int i = blockIdx.y;
  const int d  = gid & (DI-1);
  const int kp = (gid >> 7) & 1;
  const int b  = gid >> 8;
  const int t = threadIdx.x, lane = t & 63, wv = t >> 6;
  float* base = ws + (size_t)i*ISTRIDE;
  const float* src = base + (kp? OFF_XCONVT : OFF_XCONV) + (size_t)(b*DI+d)*LL;
  float*       dst = base + (kp? OFF_YT    : OFF_Y    ) + (size_t)(b*DI+d)*LL;
  const float* xdF = base + OFF_XDBL + (size_t)(b*KK+kp  )*6*LL;
  const float* xdB = base + OFF_XDBL + (size_t)(b*KK+kp+2)*6*LL;
  const int kdF = kp*DI + d, kdB = (kp+2)*DI + d;
  const float4 wF = ((const float4*)dtw_)[i*KK*DI + kdF];
  const float4 wB = ((const float4*)dtw_)[i*KK*DI + kdB];
  const float biasF = dtb_[i*KK*DI + kdF], biasB = dtb_[i*KK*DI + kdB];
  const float AvF = -expf(alog_[i*KK*DI + kdF]);
  const float AvB = -expf(alog_[i*KK*DI + kdB]);
  const float Dsum = Ds_[i*KK*DI + kdF] + Ds_[i*KK*DI + kdB];
  const int l0 = t*16;
  const int s0 = LL - 16 - l0;

  float vX[16], aF[16], bF[16], aB[16], bB[16];
  float fA = 1.f, fB = 0.f, gA = 1.f, gB = 0.f;
  LD16(vX, src + l0);

  {
    float pre[16], r0[16];
    LD16(r0, xdF + 0*LL + l0);
    #pragma unroll
    for(int j=0;j<16;++j) pre[j] = biasF + wF.x*r0[j];
    LD16(r0, xdF + 1*LL + l0);
    #pragma unroll
    for(int j=0;j<16;++j) pre[j] += wF.y*r0[j];
    LD16(r0, xdF + 2*LL + l0);
    #pragma unroll
    for(int j=0;j<16;++j) pre[j] += wF.z*r0[j];
    LD16(r0, xdF + 3*LL + l0);
    #pragma unroll
    for(int j=0;j<16;++j) pre[j] += wF.w*r0[j];
    LD16(r0, xdF + 4*LL + l0);   // Bs
    #pragma unroll
    for(int j=0;j<16;++j){
      const float delta = softplusf_(pre[j]);
      aF[j] = expf(delta*AvF);
      bF[j] = delta*r0[j]*vX[j];
      fB = fB*aF[j] + bF[j];
      fA *= aF[j];
    }
  }
  {
    float pre[16], r0[16];
    LD16R(r0, xdB + 0*LL + s0);
    #pragma unroll
    for(int j=0;j<16;++j) pre[j] = biasB + wB.x*r0[j];
    LD16R(r0, xdB + 1*LL + s0);
    #pragma unroll
    for(int j=0;j<16;++j) pre[j] += wB.y*r0[j];
    LD16R(r0, xdB + 2*LL + s0);
    #pragma unroll
    for(int j=0;j<16;++j) pre[j] += wB.z*r0[j];
    LD16R(r0, xdB + 3*LL + s0);
    #pragma unroll
    for(int j=0;j<16;++j) pre[j] += wB.w*r0[j];
    LD16R(r0, xdB + 4*LL + s0);  // Bs reversed
    #pragma unroll
    for(int j=15;j>=0;--j){
      const float delta = softplusf_(pre[j]);
      aB[j] = expf(delta*AvB);
      bB[j] = delta*r0[j]*vX[j];
      gB = gB*aB[j] + bB[j];
      gA *= aB[j];
    }
  }

  #pragma unroll
  for(int off=1; off<64; off<<=1){
    const float aL = __shfl_up(fA, off);
    const float bL = __shfl_up(fB, off);
    if(lane >= off){ fB = bL*fA + fB; fA = aL*fA; }
  }
  float pA = __shfl_up(fA, 1), pB = __shfl_up(fB, 1);
  if(lane==0){ pA=1.f; pB=0.f; }
  #pragma unroll
  for(int off=1; off<64; off<<=1){
    const float aR = __shfl_down(gA, off);
    const float bR = __shfl_down(gB, off);
    if(lane + off < 64){ gB = gA*bR + gB; gA = gA*aR; }
  }
  float qA = __shfl_down(gA, 1), qB = __shfl_down(gB, 1);
  if(lane==63){ qA=1.f; qB=0.f; }

  __shared__ float wAg[4], wBg[4], vAg[4], vBg[4];
  if(lane==63){ wAg[wv]=fA; wBg[wv]=fB; }
  if(lane==0){ vAg[wv]=gA; vBg[wv]=gB; }
  __syncthreads();
  float eB=0.f;
  for(int u=0; u<wv; ++u){ eB = wAg[u]*eB + wBg[u]; }
  float rB=0.f;
  for(int u=3; u>wv; --u){ rB = vAg[u]*rB + vBg[u]; }

  float hf = pA*eB + pB;
  float hb = qA*rB + qB;

  float out[16], cc[16];
  LD16(cc, xdF + 5*LL + l0);
  #pragma unroll
  for(int j=0;j<16;++j){
    hf = aF[j]*hf + bF[j];
    out[j] = hf*cc[j] + Dsum*vX[j];
  }
  LD16R(cc, xdB + 5*LL + s0);
  #pragma unroll
  for(int j=15;j>=0;--j){
    hb = aB[j]*hb + bB[j];
    out[j] += hb*cc[j];
  }
  float4* d4 = (float4*)(dst + l0);
  d4[0] = make_float4(out[0],out[1],out[2],out[3]);
  d4[1] = make_float4(out[4],out[5],out[6],out[7]);
  d4[2] = make_float4(out[8],out[9],out[10],out[11]);
  d4[3] = make_float4(out[12],out[13],out[14],out[15]);
}

// K3c: combine y + transpose(yT) into d-major ycombT[d][b*LL+l].
__global__ __launch_bounds__(256) void k3c_combine(float* __restrict__ ws)
{
  const int i = blockIdx.y;
  const int b = blockIdx.x >> 4;
  const int tile = blockIdx.x & 15;
  const int h0 = (tile >> 2) * 16, w0 = (tile & 3) * 16;
  const int t = threadIdx.x;
  float* base = ws + (size_t)i*ISTRIDE;
  const float* y  = base + OFF_Y;
  const float* yT = base + OFF_YT;
  float* ycT = base + OFF_YCOMBT;
  __shared__ float ytile[16*16*16];
  __shared__ float ytT[16*16*17];
  const int r0 = t >> 4, c0 = t & 15;
  const int hi = t >> 4, wi = t & 15;
  const int l = (h0 + hi)*64 + (w0 + wi);
  for(int dc=0; dc<8; ++dc){
    #pragma unroll 4
    for(int dd=0; dd<16; ++dd){
      const int d = dc*16 + dd;
      const size_t rb = (size_t)(b*DI + d)*LL;
      ytile[dd*256 + t] = y[rb + (size_t)(h0 + r0)*64 + (w0 + c0)];
      ytT[dd*272 + r0*17 + c0] = yT[rb + (size_t)(w0 + r0)*64 + (h0 + c0)];
    }
    __syncthreads();
    #pragma unroll 4
    for(int dd=0; dd<16; ++dd){
      const int d = dc*16 + dd;
      ycT[(size_t)d*LB + b*LL + l] = ytile[dd*256 + t] + ytT[dd*272 + wi*17 + hi];
    }
    __syncthreads();
  }
}

// K4a: block = 4 waves = 2 pixel-groups x 2 K-chunks. lane = pixel.
__global__ __launch_bounds__(256) void k4a_proj(
    const float* __restrict__ xmag, const float* __restrict__ xph,
    const float* __restrict__ onw_, const float* __restrict__ onb_,
    const float* __restrict__ opw_, float* __restrict__ ws)
{
  const int i = blockIdx.y;
  const float* xin = i ? xph : xmag;
  const float* onw = onw_ + i*DI;
  const float* onb = onb_ + i*DI;
  const float* opw = opw_ + i*CC*DI;
  float* base = ws + (size_t)i*ISTRIDE;
  const float* ycT = base + OFF_YCOMBT;
  const float* zT  = base + OFF_Z;
  const int t = threadIdx.x, lane = t & 63, wv = t >> 6;
  const int g = wv >> 1;
  const int ch = __builtin_amdgcn_readfirstlane(wv & 1);
  const int p = blockIdx.x*128 + g*64 + lane;
  float yv[64];
  float s1=0.f, s2=0.f;
  #pragma unroll 8
  for(int c=0;c<64;++c){
    const float v = ycT[(size_t)(ch*64+c)*LB + p];
    yv[c]=v; s1+=v; s2+=v*v;
  }
  __shared__ float st[2][64][4];
  st[g][lane][ch*2]=s1; st[g][lane][ch*2+1]=s2;
  __syncthreads();
  const float S1 = st[g][lane][0]+st[g][lane][2];
  const float S2 = st[g][lane][1]+st[g][lane][3];
  const float mu = S1*(1.f/DI);
  const float rs = rsqrtf(S2*(1.f/DI) - mu*mu + EPSF);
  #pragma unroll 8
  for(int c=0;c<64;++c){
    const int d = ch*64+c;
    yv[c] = ((yv[c]-mu)*rs*onw[d] + onb[d]) * zT[(size_t)d*LB + p];
  }
  float acc[64];
  #pragma unroll 2
  for(int o=0;o<64;++o){
    const float* wr = opw + o*DI + ch*64;
    float a = 0.f;
    #pragma unroll
    for(int c=0;c<64;++c) a += yv[c]*wr[c];
    acc[o] = a;
  }
  __shared__ float ab[2][64*65];
  if(ch==0){
    #pragma unroll 8
    for(int o=0;o<64;++o) ab[g][lane*65+o] = acc[o];
  }
  __syncthreads();
  if(ch==1){
    #pragma unroll 8
    for(int o=0;o<64;++o) ab[g][lane*65+o] += acc[o];
  }
  __syncthreads();
  const int pxl = t >> 1, oh = (t & 1)*32;
  const int gg = pxl >> 6, ll = pxl & 63;
  const int pg = blockIdx.x*128 + pxl;
  float* xnew = base + OFF_XNEW + (size_t)pg*CC + oh;
  const float* xi = xin + (size_t)pg*CC + oh;
  #pragma unroll
  for(int q=0;q<8;++q){
    float4 v;
    v.x = ab[gg][ll*65+oh+4*q  ] + xi[4*q  ];
    v.y = ab[gg][ll*65+oh+4*q+1] + xi[4*q+1];
    v.z = ab[gg][ll*65+oh+4*q+2] + xi[4*q+2];
    v.w = ab[gg][ll*65+oh+4*q+3] + xi[4*q+3];
    ((float4*)xnew)[q] = v;
  }
}

// K4b v6: block = 4 waves over SAME 64 pixels (lane=pixel). GELU activations
// staged in TWO rounds of 128 hidden units (g[128][64] = 32 KB -> 4 blocks/CU).
// fc1: wave computes 32 rows/round (4-at-a-time s_load streams); fc2: wave owns
// o-chunk [16wv,+16), weights direct from f2w (d_in, row-major [o][j]).
__global__ __launch_bounds__(256) void k4b_mlp(
    const float* __restrict__ n2w_, const float* __restrict__ n2b_,
    const float* __restrict__ f1w_, const float* __restrict__ f1b_,
    const float* __restrict__ f2w_, const float* __restrict__ f2b_,
    float* __restrict__ ws)
{
  const int i = blockIdx.y;
  const float* n2w = n2w_ + i*CC;
  const float* n2b = n2b_ + i*CC;
  const float* f1w = f1w_ + i*4*CC*CC;
  const float* f1b = f1b_ + i*4*CC;
  const float* f2w = f2w_ + i*4*CC*CC;   // [o][j] = [64][256]
  const float* f2b = f2b_ + i*CC;
  float* base = ws + (size_t)i*ISTRIDE;
  const float* xnew = base + OFF_XNEW;
  const int t = threadIdx.x, lane = t & 63;
  const int wv = __builtin_amdgcn_readfirstlane(t >> 6);
  const int p = blockIdx.x*64 + lane;
  float h2[64];
  LD16(h2, xnew + (size_t)p*CC);
  LD16((h2+16), xnew + (size_t)p*CC + 16);
  LD16((h2+32), xnew + (size_t)p*CC + 32);
  LD16((h2+48), xnew + (size_t)p*CC + 48);
  float s1=0.f, s2=0.f;
  #pragma unroll
  for(int c=0;c<CC;++c){ s1 += h2[c]; s2 += h2[c]*h2[c]; }
  const float mu = s1*(1.f/CC);
  const float rs = rsqrtf(s2*(1.f/CC) - mu*mu + EPSF);
  #pragma unroll
  for(int c=0;c<CC;++c) h2[c] = (h2[c]-mu)*rs*n2w[c] + n2b[c];

  __shared__ float g[128*64];   // 32 KB: g[j-local][pixel-lane]
  float acc[16];
  #pragma unroll
  for(int o=0;o<16;++o) acc[o] = 0.f;
  for(int r=0;r<2;++r){
    if(r>0) __syncthreads();            // prior round's reads of g complete
    // fc1: this wave's 32 rows of the round's 128, 4-at-a-time
    for(int mg=0; mg<8; ++mg){
      const int jl = wv*32 + mg*4;      // local j in [0,128)
      const int j = r*128 + jl;
      const float* w0 = f1w + (j+0)*CC;
      const float* w1 = f1w + (j+1)*CC;
      const float* w2 = f1w + (j+2)*CC;
      const float* w3 = f1w + (j+3)*CC;
      float a0=f1b[j+0], a1=f1b[j+1], a2=f1b[j+2], a3=f1b[j+3];
      #pragma unroll
      for(int c=0;c<CC;++c){
        const float h = h2[c];
        a0 += h*w0[c]; a1 += h*w1[c]; a2 += h*w2[c]; a3 += h*w3[c];
      }
      g[(jl+0)*64 + lane] = geluf_(a0);
      g[(jl+1)*64 + lane] = geluf_(a1);
      g[(jl+2)*64 + lane] = geluf_(a2);
      g[(jl+3)*64 + lane] = geluf_(a3);
    }
    __syncthreads();
    // fc2: consume the round's 128 j's for this wave's 16 outputs
    for(int jg=0; jg<32; ++jg){
      const int jl = jg*4;
      const float g0 = g[(jl+0)*64 + lane];
      const float g1 = g[(jl+1)*64 + lane];
      const float g2 = g[(jl+2)*64 + lane];
      const float g3 = g[(jl+3)*64 + lane];
      #pragma unroll
      for(int o=0;o<16;++o){
        const float4 w4 = *(const float4*)(f2w + (size_t)(wv*16+o)*256 + r*128 + jl);
        acc[o] += g0*w4.x + g1*w4.y + g2*w4.z + g3*w4.w;
      }
    }
  }
  const float* xr = xnew + (size_t)p*CC + wv*16;
  float* sb = base + OFF_SB + (size_t)p*CC + wv*16;
  #pragma unroll
  for(int q=0;q<4;++q){
    const float4 x4 = ((const float4*)xr)[q];
    float4 v;
    v.x = acc[4*q  ] + f2b[wv*16+4*q  ] + x4.x;
    v.y = acc[4*q+1] + f2b[wv*16+4*q+1] + x4.y;
    v.z = acc[4*q+2] + f2b[wv*16+4*q+2] + x4.z;
    v.w = acc[4*q+3] + f2b[wv*16+4*q+3] + x4.w;
    ((float4*)sb)[q] = v;
  }
}

// K5: s = inst0 + inst1; write to both output halves
__global__ __launch_bounds__(256) void k5_final(
    const float* __restrict__ ws, float* __restrict__ out)
{
  const int idx = blockIdx.x*256 + threadIdx.x;
  const float v = ws[OFF_SB + idx] + ws[ISTRIDE + OFF_SB + idx];
  out[idx] = v;
  out[NPIX + idx] = v;
}

extern "C" void kernel_launch(void* const* d_in, const int* in_sizes, int n_in,
                              void* d_out, int out_size, void* d_ws, size_t ws_size,
                              hipStream_t stream)
{
  const float* mag  = (const float*)d_in[0];
  const float* ph   = (const float*)d_in[1];
  const float* n1w  = (const float*)d_in[2];
  const float* n1b  = (const float*)d_in[3];
  const float* ipw  = (const float*)d_in[4];
  const float* cw   = (const float*)d_in[5];
  const float* xpw  = (const float*)d_in[6];
  const float* dtw  = (const float*)d_in[7];
  const float* dtb  = (const float*)d_in[8];
  const float* alog = (const float*)d_in[9];
  const float* Ds   = (const float*)d_in[10];
  const float* onw  = (const float*)d_in[11];
  const float* onb  = (const float*)d_in[12];
  const float* opw  = (const float*)d_in[13];
  const float* n2w  = (const float*)d_in[14];
  const float* n2b  = (const float*)d_in[15];
  const float* f1w  = (const float*)d_in[16];
  const float* f1b  = (const float*)d_in[17];
  const float* f2w  = (const float*)d_in[18];
  const float* f2b  = (const float*)d_in[19];
  float* ws = (float*)d_ws;
  float* out = (float*)d_out;

  k1_ln_inproj<<<dim3(512,2),  256, 0, stream>>>(mag, ph, n1w, n1b, ipw, ws);
  k2_dwconv   <<<dim3(1024,2), 256, 0, stream>>>(cw, ws);
  k3a_xproj   <<<dim3(16,32,2),256, 0, stream>>>(xpw, ws);
  k3b_scan    <<<dim3(2048,2), 256, 0, stream>>>(dtw, dtb, alog, Ds, ws);
  k3c_combine <<<dim3(128,2),  256, 0, stream>>>(ws);
  k4a_proj    <<<dim3(256,2),  256, 0, stream>>>(mag, ph, onw, onb, opw, ws);
  k4b_mlp     <<<dim3(512,2),  256, 0, stream>>>(n2w, n2b, f1w, f1b, f2w, f2b, ws);
  k5_final    <<<dim3(8192),   256, 0, stream>>>(ws, out);
}

// Round 11
// 533.163 us; speedup vs baseline: 1.6742x; 1.1817x over previous
//
#include <hip/hip_runtime.h>
#include <math.h>

// Problem constants
#define LL   4096      // H*W
#define DI   128       // 2*C
#define CC   64        // C
#define BB   8         // batch
#define KK   4         // scan directions
#define LB   32768     // pixels per instance
#define NPIX 2097152   // B*H*W*C elements of s
#define EPSF 1e-5f

// Workspace layout (floats, per instance)
#define OFF_XCIN   ((size_t)0)
#define OFF_XCONV  ((size_t)4194304)
#define OFF_XCONVT ((size_t)8388608)
#define OFF_Z      ((size_t)12582912)
#define OFF_Y      ((size_t)16777216)
#define OFF_YT     ((size_t)20971520)
#define OFF_XDBL   ((size_t)25165824)
#define ISTRIDE    ((size_t)25952256)   // floats per instance
// Aliases (lifetime-disjoint reuse):
#define OFF_YCOMBT OFF_XCIN             // xcin dead after k2; ycombT (d-major) by k3c
#define OFF_XNEW   OFF_YT               // yT dead after k3c; xnew (pixel-major) by k4a
#define OFF_SB     OFF_Y                // y dead after k3c; sbuf by k4b

typedef short v8s __attribute__((ext_vector_type(8)));
typedef float v4f __attribute__((ext_vector_type(4)));

__device__ __forceinline__ float sigmoidf_(float x){ return 1.f/(1.f+expf(-x)); }
__device__ __forceinline__ float softplusf_(float x){ return fmaxf(x,0.f) + log1pf(expf(-fabsf(x))); }
__device__ __forceinline__ float geluf_(float x){ return 0.5f*x*(1.f+erff(x*0.70710678118f)); }
__device__ __forceinline__ short bf16_(float x){
  unsigned u = __float_as_uint(x);
  u += 0x7FFF + ((u>>16)&1);     // RNE
  return (short)(u>>16);
}

#define LD16(dst, ptr) { const float4* p4_=(const float4*)(ptr);                 \
  float4 v0_=p4_[0], v1_=p4_[1], v2_=p4_[2], v3_=p4_[3];                         \
  dst[0]=v0_.x; dst[1]=v0_.y; dst[2]=v0_.z; dst[3]=v0_.w;                        \
  dst[4]=v1_.x; dst[5]=v1_.y; dst[6]=v1_.z; dst[7]=v1_.w;                        \
  dst[8]=v2_.x; dst[9]=v2_.y; dst[10]=v2_.z; dst[11]=v2_.w;                      \
  dst[12]=v3_.x; dst[13]=v3_.y; dst[14]=v3_.z; dst[15]=v3_.w; }
#define LD16R(dst, ptr) { const float4* p4_=(const float4*)(ptr);                \
  float4 v0_=p4_[0], v1_=p4_[1], v2_=p4_[2], v3_=p4_[3];                         \
  dst[15]=v0_.x; dst[14]=v0_.y; dst[13]=v0_.z; dst[12]=v0_.w;                    \
  dst[11]=v1_.x; dst[10]=v1_.y; dst[9]=v1_.z;  dst[8]=v1_.w;                     \
  dst[7]=v2_.x;  dst[6]=v2_.y;  dst[5]=v2_.z;  dst[4]=v2_.w;                     \
  dst[3]=v3_.x;  dst[2]=v3_.y;  dst[1]=v3_.z;  dst[0]=v3_.w; }

// K1 v4: block = 4 waves over SAME 64 pixels (lane=pixel). Wave ch owns a 64-row
// chunk of the 256 in_proj outputs; rows 4-at-a-time (s_load stream interleave).
__global__ __launch_bounds__(256) void k1_ln_inproj(
    const float* __restrict__ xmag, const float* __restrict__ xph,
    const float* __restrict__ n1w_, const float* __restrict__ n1b_,
    const float* __restrict__ ipw_, float* __restrict__ ws)
{
  const int i = blockIdx.y;
  const float* xin = i ? xph : xmag;
  const float* n1w = n1w_ + i*CC;
  const float* n1b = n1b_ + i*CC;
  const float* ipw = ipw_ + i*2*DI*CC;
  float* base = ws + (size_t)i*ISTRIDE;
  const int t = threadIdx.x, lane = t & 63;
  const int ch = __builtin_amdgcn_readfirstlane(t >> 6);
  const int p = blockIdx.x*64 + lane;
  const int b = p >> 12, l = p & (LL-1);
  float hn[CC];
  LD16(hn, xin + (size_t)p*CC);
  LD16((hn+16), xin + (size_t)p*CC + 16);
  LD16((hn+32), xin + (size_t)p*CC + 32);
  LD16((hn+48), xin + (size_t)p*CC + 48);
  float s1=0.f, s2=0.f;
  #pragma unroll
  for(int c=0;c<CC;++c){ s1 += hn[c]; s2 += hn[c]*hn[c]; }
  const float mu = s1*(1.f/CC);
  const float rs = rsqrtf(s2*(1.f/CC) - mu*mu + EPSF);
  #pragma unroll
  for(int c=0;c<CC;++c) hn[c] = (hn[c]-mu)*rs*n1w[c] + n1b[c];
  if(ch < 2){
    float* xcb = base + OFF_XCIN + (size_t)b*DI*LL + l;
    for(int jg=0;jg<16;++jg){
      const int j = ch*64 + jg*4;
      const float* w0 = ipw + (j+0)*CC;
      const float* w1 = ipw + (j+1)*CC;
      const float* w2 = ipw + (j+2)*CC;
      const float* w3 = ipw + (j+3)*CC;
      float a0=0.f,a1=0.f,a2=0.f,a3=0.f;
      #pragma unroll
      for(int c=0;c<CC;++c){
        const float h = hn[c];
        a0 += h*w0[c]; a1 += h*w1[c]; a2 += h*w2[c]; a3 += h*w3[c];
      }
      xcb[(size_t)(j+0)*LL] = a0;
      xcb[(size_t)(j+1)*LL] = a1;
      xcb[(size_t)(j+2)*LL] = a2;
      xcb[(size_t)(j+3)*LL] = a3;
    }
  } else {
    float* zT = base + OFF_Z;
    for(int jg=0;jg<16;++jg){
      const int d = (ch-2)*64 + jg*4;
      const float* w0 = ipw + (DI+d+0)*CC;
      const float* w1 = ipw + (DI+d+1)*CC;
      const float* w2 = ipw + (DI+d+2)*CC;
      const float* w3 = ipw + (DI+d+3)*CC;
      float a0=0.f,a1=0.f,a2=0.f,a3=0.f;
      #pragma unroll
      for(int c=0;c<CC;++c){
        const float h = hn[c];
        a0 += h*w0[c]; a1 += h*w1[c]; a2 += h*w2[c]; a3 += h*w3[c];
      }
      zT[(size_t)(d+0)*LB + p] = a0 * sigmoidf_(a0);
      zT[(size_t)(d+1)*LB + p] = a1 * sigmoidf_(a1);
      zT[(size_t)(d+2)*LB + p] = a2 * sigmoidf_(a2);
      zT[(size_t)(d+3)*LB + p] = a3 * sigmoidf_(a3);
    }
  }
}

// K2: depthwise 3x3 conv + silu; per (b,d) 64x64 tile via LDS; row-major + transposed out
__global__ __launch_bounds__(256) void k2_dwconv(
    const float* __restrict__ cw_, float* __restrict__ ws)
{
  const int i = blockIdx.y;
  const int bd = blockIdx.x;
  const int d = bd & (DI-1);
  const float* cw = cw_ + i*DI*9 + d*9;
  const float* xcin  = ws + (size_t)i*ISTRIDE + OFF_XCIN  + (size_t)bd*LL;
  float* xconv  = ws + (size_t)i*ISTRIDE + OFF_XCONV  + (size_t)bd*LL;
  float* xconvT = ws + (size_t)i*ISTRIDE + OFF_XCONVT + (size_t)bd*LL;
  __shared__ float tin[64*65];
  __shared__ float tout[64*65];
  const int t = threadIdx.x;
  float w9[9];
  #pragma unroll
  for(int q=0;q<9;++q) w9[q] = cw[q];
  for(int idx=t; idx<4096; idx+=256)
    tin[(idx>>6)*65 + (idx&63)] = xcin[idx];
  __syncthreads();
  const int w = t & 63, hb = (t>>6)*16;
  #pragma unroll
  for(int r=0;r<16;++r){
    const int h = hb + r;
    float acc = 0.f;
    #pragma unroll
    for(int dy=0;dy<3;++dy){
      const int hh = h + dy - 1;
      if(hh>=0 && hh<64){
        #pragma unroll
        for(int dx=0;dx<3;++dx){
          const int ww = w + dx - 1;
          if(ww>=0 && ww<64) acc += tin[hh*65+ww]*w9[dy*3+dx];
        }
      }
    }
    const float o = acc * sigmoidf_(acc);
    tout[h*65+w] = o;
    xconv[h*64+w] = o;
  }
  __syncthreads();
  const int hcol = t & 63, wb = (t>>6)*16;
  #pragma unroll
  for(int r=0;r<16;++r){
    const int wp = wb + r;
    xconvT[wp*64 + hcol] = tout[hcol*65 + wp];
  }
}

// K3a: x_dbl = x_proj(xs) -> (dts[4], Bs, Cs) per (b,k,scan-pos)
__global__ __launch_bounds__(256) void k3a_xproj(
    const float* __restrict__ xpw_, float* __restrict__ ws)
{
  const int i = blockIdx.z;
  const int b = blockIdx.y >> 2;
  const int k = blockIdx.y & 3;
  const int l = blockIdx.x*256 + threadIdx.x;
  const float* src = ws + (size_t)i*ISTRIDE + ((k&1)? OFF_XCONVT : OFF_XCONV) + (size_t)b*DI*LL;
  const int ridx = (k>=2) ? (LL-1-l) : l;
  const float* xpw = xpw_ + i*KK*6*DI + k*6*DI;
  float acc[6] = {0,0,0,0,0,0};
  for(int d=0; d<DI; ++d){
    const float xv = src[(size_t)d*LL + ridx];
    #pragma unroll
    for(int c=0;c<6;++c) acc[c] += xv * xpw[c*DI + d];
  }
  float* xdbl = ws + (size_t)i*ISTRIDE + OFF_XDBL + (size_t)(b*KK+k)*6*LL;
  #pragma unroll
  for(int c=0;c<6;++c) xdbl[(size_t)c*LL + l] = acc[c];
}

// K3b: paired fwd/bwd selective scan; phase-split regs + wave shuffle scan, 1 barrier.
__global__ __launch_bounds__(256,3) void k3b_scan(
    const float* __restrict__ dtw_, const float* __restrict__ dtb_,
    const float* __restrict__ alog_, const float* __restrict__ Ds_,
    float* __restrict__ ws)
{
  const int gid = blockIdx.x;           // b*256 + kp*128 + d
  const int i = blockIdx.y;
  const int d  = gid & (DI-1);
  const int kp = (gid >> 7) & 1;
  const int b  = gid >> 8;
  const int t = threadIdx.x, lane = t & 63, wv = t >> 6;
  float* base = ws + (size_t)i*ISTRIDE;
  const float* src = base + (kp? OFF_XCONVT : OFF_XCONV) + (size_t)(b*DI+d)*LL;
  float*       dst = base + (kp? OFF_YT    : OFF_Y    ) + (size_t)(b*DI+d)*LL;
  const float* xdF = base + OFF_XDBL + (size_t)(b*KK+kp  )*6*LL;
  const float* xdB = base + OFF_XDBL + (size_t)(b*KK+kp+2)*6*LL;
  const int kdF = kp*DI + d, kdB = (kp+2)*DI + d;
  const float4 wF = ((const float4*)dtw_)[i*KK*DI + kdF];
  const float4 wB = ((const float4*)dtw_)[i*KK*DI + kdB];
  const float biasF = dtb_[i*KK*DI + kdF], biasB = dtb_[i*KK*DI + kdB];
  const float AvF = -expf(alog_[i*KK*DI + kdF]);
  const float AvB = -expf(alog_[i*KK*DI + kdB]);
  const float Dsum = Ds_[i*KK*DI + kdF] + Ds_[i*KK*DI + kdB];
  const int l0 = t*16;
  const int s0 = LL - 16 - l0;

  float vX[16], aF[16], bF[16], aB[16], bB[16];
  float fA = 1.f, fB = 0.f, gA = 1.f, gB = 0.f;
  LD16(vX, src + l0);

  {
    float pre[16], r0[16];
    LD16(r0, xdF + 0*LL + l0);
    #pragma unroll
    for(int j=0;j<16;++j) pre[j] = biasF + wF.x*r0[j];
    LD16(r0, xdF + 1*LL + l0);
    #pragma unroll
    for(int j=0;j<16;++j) pre[j] += wF.y*r0[j];
    LD16(r0, xdF + 2*LL + l0);
    #pragma unroll
    for(int j=0;j<16;++j) pre[j] += wF.z*r0[j];
    LD16(r0, xdF + 3*LL + l0);
    #pragma unroll
    for(int j=0;j<16;++j) pre[j] += wF.w*r0[j];
    LD16(r0, xdF + 4*LL + l0);   // Bs
    #pragma unroll
    for(int j=0;j<16;++j){
      const float delta = softplusf_(pre[j]);
      aF[j] = expf(delta*AvF);
      bF[j] = delta*r0[j]*vX[j];
      fB = fB*aF[j] + bF[j];
      fA *= aF[j];
    }
  }
  {
    float pre[16], r0[16];
    LD16R(r0, xdB + 0*LL + s0);
    #pragma unroll
    for(int j=0;j<16;++j) pre[j] = biasB + wB.x*r0[j];
    LD16R(r0, xdB + 1*LL + s0);
    #pragma unroll
    for(int j=0;j<16;++j) pre[j] += wB.y*r0[j];
    LD16R(r0, xdB + 2*LL + s0);
    #pragma unroll
    for(int j=0;j<16;++j) pre[j] += wB.z*r0[j];
    LD16R(r0, xdB + 3*LL + s0);
    #pragma unroll
    for(int j=0;j<16;++j) pre[j] += wB.w*r0[j];
    LD16R(r0, xdB + 4*LL + s0);  // Bs reversed
    #pragma unroll
    for(int j=15;j>=0;--j){
      const float delta = softplusf_(pre[j]);
      aB[j] = expf(delta*AvB);
      bB[j] = delta*r0[j]*vX[j];
      gB = gB*aB[j] + bB[j];
      gA *= aB[j];
    }
  }

  #pragma unroll
  for(int off=1; off<64; off<<=1){
    const float aL = __shfl_up(fA, off);
    const float bL = __shfl_up(fB, off);
    if(lane >= off){ fB = bL*fA + fB; fA = aL*fA; }
  }
  float pA = __shfl_up(fA, 1), pB = __shfl_up(fB, 1);
  if(lane==0){ pA=1.f; pB=0.f; }
  #pragma unroll
  for(int off=1; off<64; off<<=1){
    const float aR = __shfl_down(gA, off);
    const float bR = __shfl_down(gB, off);
    if(lane + off < 64){ gB = gA*bR + gB; gA = gA*aR; }
  }
  float qA = __shfl_down(gA, 1), qB = __shfl_down(gB, 1);
  if(lane==63){ qA=1.f; qB=0.f; }

  __shared__ float wAg[4], wBg[4], vAg[4], vBg[4];
  if(lane==63){ wAg[wv]=fA; wBg[wv]=fB; }
  if(lane==0){ vAg[wv]=gA; vBg[wv]=gB; }
  __syncthreads();
  float eB=0.f;
  for(int u=0; u<wv; ++u){ eB = wAg[u]*eB + wBg[u]; }
  float rB=0.f;
  for(int u=3; u>wv; --u){ rB = vAg[u]*rB + vBg[u]; }

  float hf = pA*eB + pB;
  float hb = qA*rB + qB;

  float out[16], cc[16];
  LD16(cc, xdF + 5*LL + l0);
  #pragma unroll
  for(int j=0;j<16;++j){
    hf = aF[j]*hf + bF[j];
    out[j] = hf*cc[j] + Dsum*vX[j];
  }
  LD16R(cc, xdB + 5*LL + s0);
  #pragma unroll
  for(int j=15;j>=0;--j){
    hb = aB[j]*hb + bB[j];
    out[j] += hb*cc[j];
  }
  float4* d4 = (float4*)(dst + l0);
  d4[0] = make_float4(out[0],out[1],out[2],out[3]);
  d4[1] = make_float4(out[4],out[5],out[6],out[7]);
  d4[2] = make_float4(out[8],out[9],out[10],out[11]);
  d4[3] = make_float4(out[12],out[13],out[14],out[15]);
}

// K3c: combine y + transpose(yT) into d-major ycombT[d][b*LL+l].
__global__ __launch_bounds__(256) void k3c_combine(float* __restrict__ ws)
{
  const int i = blockIdx.y;
  const int b = blockIdx.x >> 4;
  const int tile = blockIdx.x & 15;
  const int h0 = (tile >> 2) * 16, w0 = (tile & 3) * 16;
  const int t = threadIdx.x;
  float* base = ws + (size_t)i*ISTRIDE;
  const float* y  = base + OFF_Y;
  const float* yT = base + OFF_YT;
  float* ycT = base + OFF_YCOMBT;
  __shared__ float ytile[16*16*16];
  __shared__ float ytT[16*16*17];
  const int r0 = t >> 4, c0 = t & 15;
  const int hi = t >> 4, wi = t & 15;
  const int l = (h0 + hi)*64 + (w0 + wi);
  for(int dc=0; dc<8; ++dc){
    #pragma unroll 4
    for(int dd=0; dd<16; ++dd){
      const int d = dc*16 + dd;
      const size_t rb = (size_t)(b*DI + d)*LL;
      ytile[dd*256 + t] = y[rb + (size_t)(h0 + r0)*64 + (w0 + c0)];
      ytT[dd*272 + r0*17 + c0] = yT[rb + (size_t)(w0 + r0)*64 + (h0 + c0)];
    }
    __syncthreads();
    #pragma unroll 4
    for(int dd=0; dd<16; ++dd){
      const int d = dc*16 + dd;
      ycT[(size_t)d*LB + b*LL + l] = ytile[dd*256 + t] + ytT[dd*272 + wi*17 + hi];
    }
    __syncthreads();
  }
}

// K4a: block = 4 waves = 2 pixel-groups x 2 K-chunks. lane = pixel.
__global__ __launch_bounds__(256) void k4a_proj(
    const float* __restrict__ xmag, const float* __restrict__ xph,
    const float* __restrict__ onw_, const float* __restrict__ onb_,
    const float* __restrict__ opw_, float* __restrict__ ws)
{
  const int i = blockIdx.y;
  const float* xin = i ? xph : xmag;
  const float* onw = onw_ + i*DI;
  const float* onb = onb_ + i*DI;
  const float* opw = opw_ + i*CC*DI;
  float* base = ws + (size_t)i*ISTRIDE;
  const float* ycT = base + OFF_YCOMBT;
  const float* zT  = base + OFF_Z;
  const int t = threadIdx.x, lane = t & 63, wv = t >> 6;
  const int g = wv >> 1;
  const int ch = __builtin_amdgcn_readfirstlane(wv & 1);
  const int p = blockIdx.x*128 + g*64 + lane;
  float yv[64];
  float s1=0.f, s2=0.f;
  #pragma unroll 8
  for(int c=0;c<64;++c){
    const float v = ycT[(size_t)(ch*64+c)*LB + p];
    yv[c]=v; s1+=v; s2+=v*v;
  }
  __shared__ float st[2][64][4];
  st[g][lane][ch*2]=s1; st[g][lane][ch*2+1]=s2;
  __syncthreads();
  const float S1 = st[g][lane][0]+st[g][lane][2];
  const float S2 = st[g][lane][1]+st[g][lane][3];
  const float mu = S1*(1.f/DI);
  const float rs = rsqrtf(S2*(1.f/DI) - mu*mu + EPSF);
  #pragma unroll 8
  for(int c=0;c<64;++c){
    const int d = ch*64+c;
    yv[c] = ((yv[c]-mu)*rs*onw[d] + onb[d]) * zT[(size_t)d*LB + p];
  }
  float acc[64];
  #pragma unroll 2
  for(int o=0;o<64;++o){
    const float* wr = opw + o*DI + ch*64;
    float a = 0.f;
    #pragma unroll
    for(int c=0;c<64;++c) a += yv[c]*wr[c];
    acc[o] = a;
  }
  __shared__ float ab[2][64*65];
  if(ch==0){
    #pragma unroll 8
    for(int o=0;o<64;++o) ab[g][lane*65+o] = acc[o];
  }
  __syncthreads();
  if(ch==1){
    #pragma unroll 8
    for(int o=0;o<64;++o) ab[g][lane*65+o] += acc[o];
  }
  __syncthreads();
  const int pxl = t >> 1, oh = (t & 1)*32;
  const int gg = pxl >> 6, ll = pxl & 63;
  const int pg = blockIdx.x*128 + pxl;
  float* xnew = base + OFF_XNEW + (size_t)pg*CC + oh;
  const float* xi = xin + (size_t)pg*CC + oh;
  #pragma unroll
  for(int q=0;q<8;++q){
    float4 v;
    v.x = ab[gg][ll*65+oh+4*q  ] + xi[4*q  ];
    v.y = ab[gg][ll*65+oh+4*q+1] + xi[4*q+1];
    v.z = ab[gg][ll*65+oh+4*q+2] + xi[4*q+2];
    v.w = ab[gg][ll*65+oh+4*q+3] + xi[4*q+3];
    ((float4*)xnew)[q] = v;
  }
}

// K4b v7 (MFMA): 64-pixel tile per block, 4 waves. LN per pixel (fp32) -> bf16
// H in LDS; per 128-j half: stage F1/F2 rows (bf16), fc1 via mfma 16x16x32
// (A: m=lane&15,k=quad*8+j; B from B^T rows: n=lane&15; C/D: col=lane&15,
// row=quad*4+reg), GELU on fp32 C-frags -> bf16 G in LDS (own-wave rows),
// fc2 mfma accumulates across halves. Epilogue adds f2b + residual.
__global__ __launch_bounds__(256) void k4b_mlp(
    const float* __restrict__ n2w_, const float* __restrict__ n2b_,
    const float* __restrict__ f1w_, const float* __restrict__ f1b_,
    const float* __restrict__ f2w_, const float* __restrict__ f2b_,
    float* __restrict__ ws)
{
  const int i = blockIdx.y;
  const float* n2w = n2w_ + i*CC;
  const float* n2b = n2b_ + i*CC;
  const float* f1w = f1w_ + i*256*64;    // [j][c]
  const float* f1b = f1b_ + i*256;
  const float* f2w = f2w_ + i*64*256;    // [o][j]
  const float* f2b = f2b_ + i*CC;
  float* base = ws + (size_t)i*ISTRIDE;
  const float* xnew = base + OFF_XNEW;
  const int t = threadIdx.x, lane = t & 63;
  const int wv = __builtin_amdgcn_readfirstlane(t >> 6);
  const int m = lane & 15, quad = lane >> 4;
  const int p0 = blockIdx.x*64;

  __shared__ short hlds[64*72];      //  9216 B : H bf16 [pixel][72]
  __shared__ short w1lds[128*72];    // 18432 B : F1 half rows [j][72]
  __shared__ short glds[64*136];     // 17408 B : G bf16 [pixel][136]
  __shared__ short w2lds[64*136];    // 17408 B : F2 half rows [o][136]

  // ---- LN per pixel (lane=pixel; redundant across waves; wave0 stores) ----
  {
    float h2[64];
    const float* xr = xnew + (size_t)(p0 + lane)*CC;
    LD16(h2, xr); LD16((h2+16), xr+16); LD16((h2+32), xr+32); LD16((h2+48), xr+48);
    float s1=0.f, s2=0.f;
    #pragma unroll
    for(int c=0;c<CC;++c){ s1 += h2[c]; s2 += h2[c]*h2[c]; }
    const float mu = s1*(1.f/CC);
    const float rs = rsqrtf(s2*(1.f/CC) - mu*mu + EPSF);
    if(wv==0){
      #pragma unroll
      for(int q=0;q<8;++q){
        v8s s;
        #pragma unroll
        for(int e=0;e<8;++e){
          const int c = q*8+e;
          s[e] = bf16_((h2[c]-mu)*rs*n2w[c] + n2b[c]);
        }
        *(v8s*)&hlds[lane*72 + q*8] = s;
      }
    }
  }

  v4f acc2[4];
  #pragma unroll
  for(int n=0;n<4;++n) acc2[n] = (v4f){0.f,0.f,0.f,0.f};

  for(int h=0; h<2; ++h){
    if(h) __syncthreads();             // prev fc2 done with w2lds before restage
    // stage F1 half (rows j-local = t>>1 of 128; 32 cols each)
    {
      const int jl = t >> 1, hc = (t & 1)*32;
      const float* src = f1w + (size_t)(h*128 + jl)*64 + hc;
      #pragma unroll
      for(int q=0;q<4;++q){
        const float4 fa = ((const float4*)src)[q*2];
        const float4 fb = ((const float4*)src)[q*2+1];
        v8s s;
        s[0]=bf16_(fa.x); s[1]=bf16_(fa.y); s[2]=bf16_(fa.z); s[3]=bf16_(fa.w);
        s[4]=bf16_(fb.x); s[5]=bf16_(fb.y); s[6]=bf16_(fb.z); s[7]=bf16_(fb.w);
        *(v8s*)&w1lds[jl*72 + hc + q*8] = s;
      }
    }
    // stage F2 half (rows o = t>>2 of 64; 32 j-cols each)
    {
      const int ol = t >> 2, seg = (t & 3)*32;
      const float* src = f2w + (size_t)ol*256 + h*128 + seg;
      #pragma unroll
      for(int q=0;q<4;++q){
        const float4 fa = ((const float4*)src)[q*2];
        const float4 fb = ((const float4*)src)[q*2+1];
        v8s s;
        s[0]=bf16_(fa.x); s[1]=bf16_(fa.y); s[2]=bf16_(fa.z); s[3]=bf16_(fa.w);
        s[4]=bf16_(fb.x); s[5]=bf16_(fb.y); s[6]=bf16_(fb.z); s[7]=bf16_(fb.w);
        *(v8s*)&w2lds[ol*136 + seg + q*8] = s;
      }
    }
    __syncthreads();
    // fc1: wave wv owns pixel rows [wv*16, +16); nt spans the half's 128 j
    #pragma unroll 2
    for(int nt=0; nt<8; ++nt){
      v4f acc = (v4f){0.f,0.f,0.f,0.f};
      #pragma unroll
      for(int ks=0; ks<2; ++ks){
        const v8s a = *(const v8s*)&hlds[(wv*16 + m)*72 + ks*32 + quad*8];
        const v8s b = *(const v8s*)&w1lds[(nt*16 + m)*72 + ks*32 + quad*8];
        acc = __builtin_amdgcn_mfma_f32_16x16x32_bf16(a, b, acc, 0, 0, 0);
      }
      const float bj = f1b[h*128 + nt*16 + m];
      #pragma unroll
      for(int r=0;r<4;++r){
        glds[(wv*16 + quad*4 + r)*136 + nt*16 + m] = bf16_(geluf_(acc[r] + bj));
      }
    }
    // fc2: reads only own-wave G rows (no barrier needed); accumulate across halves
    #pragma unroll
    for(int nt=0; nt<4; ++nt){
      v4f acc = acc2[nt];
      #pragma unroll
      for(int ks=0; ks<4; ++ks){
        const v8s a = *(const v8s*)&glds[(wv*16 + m)*136 + ks*32 + quad*8];
        const v8s b = *(const v8s*)&w2lds[(nt*16 + m)*136 + ks*32 + quad*8];
        acc = __builtin_amdgcn_mfma_f32_16x16x32_bf16(a, b, acc, 0, 0, 0);
      }
      acc2[nt] = acc;
    }
  }

  // epilogue: s = fc2 + f2b + xnew
  float* sb = base + OFF_SB;
  #pragma unroll
  for(int nt=0; nt<4; ++nt){
    const float bo = f2b[nt*16 + m];
    #pragma unroll
    for(int r=0;r<4;++r){
      const int p = p0 + wv*16 + quad*4 + r;
      const int o = nt*16 + m;
      sb[(size_t)p*CC + o] = acc2[nt][r] + bo + xnew[(size_t)p*CC + o];
    }
  }
}

// K5: s = inst0 + inst1; write to both output halves
__global__ __launch_bounds__(256) void k5_final(
    const float* __restrict__ ws, float* __restrict__ out)
{
  const int idx = blockIdx.x*256 + threadIdx.x;
  const float v = ws[OFF_SB + idx] + ws[ISTRIDE + OFF_SB + idx];
  out[idx] = v;
  out[NPIX + idx] = v;
}

extern "C" void kernel_launch(void* const* d_in, const int* in_sizes, int n_in,
                              void* d_out, int out_size, void* d_ws, size_t ws_size,
                              hipStream_t stream)
{
  const float* mag  = (const float*)d_in[0];
  const float* ph   = (const float*)d_in[1];
  const float* n1w  = (const float*)d_in[2];
  const float* n1b  = (const float*)d_in[3];
  const float* ipw  = (const float*)d_in[4];
  const float* cw   = (const float*)d_in[5];
  const float* xpw  = (const float*)d_in[6];
  const float* dtw  = (const float*)d_in[7];
  const float* dtb  = (const float*)d_in[8];
  const float* alog = (const float*)d_in[9];
  const float* Ds   = (const float*)d_in[10];
  const float* onw  = (const float*)d_in[11];
  const float* onb  = (const float*)d_in[12];
  const float* opw  = (const float*)d_in[13];
  const float* n2w  = (const float*)d_in[14];
  const float* n2b  = (const float*)d_in[15];
  const float* f1w  = (const float*)d_in[16];
  const float* f1b  = (const float*)d_in[17];
  const float* f2w  = (const float*)d_in[18];
  const float* f2b  = (const float*)d_in[19];
  float* ws = (float*)d_ws;
  float* out = (float*)d_out;

  k1_ln_inproj<<<dim3(512,2),  256, 0, stream>>>(mag, ph, n1w, n1b, ipw, ws);
  k2_dwconv   <<<dim3(1024,2), 256, 0, stream>>>(cw, ws);
  k3a_xproj   <<<dim3(16,32,2),256, 0, stream>>>(xpw, ws);
  k3b_scan    <<<dim3(2048,2), 256, 0, stream>>>(dtw, dtb, alog, Ds, ws);
  k3c_combine <<<dim3(128,2),  256, 0, stream>>>(ws);
  k4a_proj    <<<dim3(256,2),  256, 0, stream>>>(mag, ph, onw, onb, opw, ws);
  k4b_mlp     <<<dim3(512,2),  256, 0, stream>>>(n2w, n2b, f1w, f1b, f2w, f2b, ws);
  k5_final    <<<dim3(8192),   256, 0, stream>>>(ws, out);
}

// Round 12
// 462.427 us; speedup vs baseline: 1.9303x; 1.1530x over previous
//
#include <hip/hip_runtime.h>
#include <math.h>

// Problem constants
#define LL   4096      // H*W
#define DI   128       // 2*C
#define CC   64        // C
#define BB   8         // batch
#define KK   4         // scan directions
#define LB   32768     // pixels per instance
#define NPIX 2097152   // B*H*W*C elements of s
#define EPSF 1e-5f

// Workspace layout (floats, per instance)
#define OFF_XCIN   ((size_t)0)
#define OFF_XCONV  ((size_t)4194304)
#define OFF_XCONVT ((size_t)8388608)
#define OFF_Z      ((size_t)12582912)
#define OFF_Y      ((size_t)16777216)
#define OFF_YT     ((size_t)20971520)
#define OFF_XDBL   ((size_t)25165824)
#define ISTRIDE    ((size_t)25952256)   // floats per instance
// Aliases (lifetime-disjoint reuse):
#define OFF_YCOMBT OFF_XCIN             // xcin dead after k2; ycombT (d-major) by k3c
#define OFF_XNEW   OFF_YT               // yT dead after k3c; xnew (pixel-major) by k4a
#define OFF_SB     OFF_Y                // y dead after k3c; sbuf by k4b

typedef short v8s __attribute__((ext_vector_type(8)));
typedef float v4f __attribute__((ext_vector_type(4)));

// Fast transcendentals: native v_exp/v_log paths (error ~1e-7, threshold 0.144)
__device__ __forceinline__ float fexp_(float x){ return __expf(x); }
__device__ __forceinline__ float silu_(float x){ return __fdividef(x, 1.f+__expf(-x)); }
__device__ __forceinline__ float softplusf_(float x){
  return fmaxf(x,0.f) + __logf(1.f + __expf(-fabsf(x)));
}
__device__ __forceinline__ float geluf_(float x){ return 0.5f*x*(1.f+erff(x*0.70710678118f)); }
__device__ __forceinline__ short bf16_(float x){
  unsigned u = __float_as_uint(x);
  u += 0x7FFF + ((u>>16)&1);     // RNE
  return (short)(u>>16);
}

#define LD16(dst, ptr) { const float4* p4_=(const float4*)(ptr);                 \
  float4 v0_=p4_[0], v1_=p4_[1], v2_=p4_[2], v3_=p4_[3];                         \
  dst[0]=v0_.x; dst[1]=v0_.y; dst[2]=v0_.z; dst[3]=v0_.w;                        \
  dst[4]=v1_.x; dst[5]=v1_.y; dst[6]=v1_.z; dst[7]=v1_.w;                        \
  dst[8]=v2_.x; dst[9]=v2_.y; dst[10]=v2_.z; dst[11]=v2_.w;                      \
  dst[12]=v3_.x; dst[13]=v3_.y; dst[14]=v3_.z; dst[15]=v3_.w; }
#define LD16R(dst, ptr) { const float4* p4_=(const float4*)(ptr);                \
  float4 v0_=p4_[0], v1_=p4_[1], v2_=p4_[2], v3_=p4_[3];                         \
  dst[15]=v0_.x; dst[14]=v0_.y; dst[13]=v0_.z; dst[12]=v0_.w;                    \
  dst[11]=v1_.x; dst[10]=v1_.y; dst[9]=v1_.z;  dst[8]=v1_.w;                     \
  dst[7]=v2_.x;  dst[6]=v2_.y;  dst[5]=v2_.z;  dst[4]=v2_.w;                     \
  dst[3]=v3_.x;  dst[2]=v3_.y;  dst[1]=v3_.z;  dst[0]=v3_.w; }

// K1 v4: block = 4 waves over SAME 64 pixels (lane=pixel). Wave ch owns a 64-row
// chunk of the 256 in_proj outputs; rows 4-at-a-time (s_load stream interleave).
__global__ __launch_bounds__(256) void k1_ln_inproj(
    const float* __restrict__ xmag, const float* __restrict__ xph,
    const float* __restrict__ n1w_, const float* __restrict__ n1b_,
    const float* __restrict__ ipw_, float* __restrict__ ws)
{
  const int i = blockIdx.y;
  const float* xin = i ? xph : xmag;
  const float* n1w = n1w_ + i*CC;
  const float* n1b = n1b_ + i*CC;
  const float* ipw = ipw_ + i*2*DI*CC;
  float* base = ws + (size_t)i*ISTRIDE;
  const int t = threadIdx.x, lane = t & 63;
  const int ch = __builtin_amdgcn_readfirstlane(t >> 6);
  const int p = blockIdx.x*64 + lane;
  const int b = p >> 12, l = p & (LL-1);
  float hn[CC];
  LD16(hn, xin + (size_t)p*CC);
  LD16((hn+16), xin + (size_t)p*CC + 16);
  LD16((hn+32), xin + (size_t)p*CC + 32);
  LD16((hn+48), xin + (size_t)p*CC + 48);
  float s1=0.f, s2=0.f;
  #pragma unroll
  for(int c=0;c<CC;++c){ s1 += hn[c]; s2 += hn[c]*hn[c]; }
  const float mu = s1*(1.f/CC);
  const float rs = rsqrtf(s2*(1.f/CC) - mu*mu + EPSF);
  #pragma unroll
  for(int c=0;c<CC;++c) hn[c] = (hn[c]-mu)*rs*n1w[c] + n1b[c];
  if(ch < 2){
    float* xcb = base + OFF_XCIN + (size_t)b*DI*LL + l;
    for(int jg=0;jg<16;++jg){
      const int j = ch*64 + jg*4;
      const float* w0 = ipw + (j+0)*CC;
      const float* w1 = ipw + (j+1)*CC;
      const float* w2 = ipw + (j+2)*CC;
      const float* w3 = ipw + (j+3)*CC;
      float a0=0.f,a1=0.f,a2=0.f,a3=0.f;
      #pragma unroll
      for(int c=0;c<CC;++c){
        const float h = hn[c];
        a0 += h*w0[c]; a1 += h*w1[c]; a2 += h*w2[c]; a3 += h*w3[c];
      }
      xcb[(size_t)(j+0)*LL] = a0;
      xcb[(size_t)(j+1)*LL] = a1;
      xcb[(size_t)(j+2)*LL] = a2;
      xcb[(size_t)(j+3)*LL] = a3;
    }
  } else {
    float* zT = base + OFF_Z;
    for(int jg=0;jg<16;++jg){
      const int d = (ch-2)*64 + jg*4;
      const float* w0 = ipw + (DI+d+0)*CC;
      const float* w1 = ipw + (DI+d+1)*CC;
      const float* w2 = ipw + (DI+d+2)*CC;
      const float* w3 = ipw + (DI+d+3)*CC;
      float a0=0.f,a1=0.f,a2=0.f,a3=0.f;
      #pragma unroll
      for(int c=0;c<CC;++c){
        const float h = hn[c];
        a0 += h*w0[c]; a1 += h*w1[c]; a2 += h*w2[c]; a3 += h*w3[c];
      }
      zT[(size_t)(d+0)*LB + p] = silu_(a0);
      zT[(size_t)(d+1)*LB + p] = silu_(a1);
      zT[(size_t)(d+2)*LB + p] = silu_(a2);
      zT[(size_t)(d+3)*LB + p] = silu_(a3);
    }
  }
}

// K2: depthwise 3x3 conv + silu; per (b,d) 64x64 tile via LDS; row-major + transposed out
__global__ __launch_bounds__(256) void k2_dwconv(
    const float* __restrict__ cw_, float* __restrict__ ws)
{
  const int i = blockIdx.y;
  const int bd = blockIdx.x;
  const int d = bd & (DI-1);
  const float* cw = cw_ + i*DI*9 + d*9;
  const float* xcin  = ws + (size_t)i*ISTRIDE + OFF_XCIN  + (size_t)bd*LL;
  float* xconv  = ws + (size_t)i*ISTRIDE + OFF_XCONV  + (size_t)bd*LL;
  float* xconvT = ws + (size_t)i*ISTRIDE + OFF_XCONVT + (size_t)bd*LL;
  __shared__ float tin[64*65];
  __shared__ float tout[64*65];
  const int t = threadIdx.x;
  float w9[9];
  #pragma unroll
  for(int q=0;q<9;++q) w9[q] = cw[q];
  for(int idx=t; idx<4096; idx+=256)
    tin[(idx>>6)*65 + (idx&63)] = xcin[idx];
  __syncthreads();
  const int w = t & 63, hb = (t>>6)*16;
  #pragma unroll
  for(int r=0;r<16;++r){
    const int h = hb + r;
    float acc = 0.f;
    #pragma unroll
    for(int dy=0;dy<3;++dy){
      const int hh = h + dy - 1;
      if(hh>=0 && hh<64){
        #pragma unroll
        for(int dx=0;dx<3;++dx){
          const int ww = w + dx - 1;
          if(ww>=0 && ww<64) acc += tin[hh*65+ww]*w9[dy*3+dx];
        }
      }
    }
    const float o = silu_(acc);
    tout[h*65+w] = o;
    xconv[h*64+w] = o;
  }
  __syncthreads();
  const int hcol = t & 63, wb = (t>>6)*16;
  #pragma unroll
  for(int r=0;r<16;++r){
    const int wp = wb + r;
    xconvT[wp*64 + hcol] = tout[hcol*65 + wp];
  }
}

// K3a: x_dbl = x_proj(xs) -> (dts[4], Bs, Cs) per (b,k,scan-pos)
__global__ __launch_bounds__(256) void k3a_xproj(
    const float* __restrict__ xpw_, float* __restrict__ ws)
{
  const int i = blockIdx.z;
  const int b = blockIdx.y >> 2;
  const int k = blockIdx.y & 3;
  const int l = blockIdx.x*256 + threadIdx.x;
  const float* src = ws + (size_t)i*ISTRIDE + ((k&1)? OFF_XCONVT : OFF_XCONV) + (size_t)b*DI*LL;
  const int ridx = (k>=2) ? (LL-1-l) : l;
  const float* xpw = xpw_ + i*KK*6*DI + k*6*DI;
  float acc[6] = {0,0,0,0,0,0};
  for(int d=0; d<DI; ++d){
    const float xv = src[(size_t)d*LL + ridx];
    #pragma unroll
    for(int c=0;c<6;++c) acc[c] += xv * xpw[c*DI + d];
  }
  float* xdbl = ws + (size_t)i*ISTRIDE + OFF_XDBL + (size_t)(b*KK+k)*6*LL;
  #pragma unroll
  for(int c=0;c<6;++c) xdbl[(size_t)c*LL + l] = acc[c];
}

// K3b: paired fwd/bwd selective scan; phase-split regs + wave shuffle scan, 1 barrier.
__global__ __launch_bounds__(256,3) void k3b_scan(
    const float* __restrict__ dtw_, const float* __restrict__ dtb_,
    const float* __restrict__ alog_, const float* __restrict__ Ds_,
    float* __restrict__ ws)
{
  const int gid = blockIdx.x;           // b*256 + kp*128 + d
  const int i = blockIdx.y;
  const int d  = gid & (DI-1);
  const int kp = (gid >> 7) & 1;
  const int b  = gid >> 8;
  const int t = threadIdx.x, lane = t & 63, wv = t >> 6;
  float* base = ws + (size_t)i*ISTRIDE;
  const float* src = base + (kp? OFF_XCONVT : OFF_XCONV) + (size_t)(b*DI+d)*LL;
  float*       dst = base + (kp? OFF_YT    : OFF_Y    ) + (size_t)(b*DI+d)*LL;
  const float* xdF = base + OFF_XDBL + (size_t)(b*KK+kp  )*6*LL;
  const float* xdB = base + OFF_XDBL + (size_t)(b*KK+kp+2)*6*LL;
  const int kdF = kp*DI + d, kdB = (kp+2)*DI + d;
  const float4 wF = ((const float4*)dtw_)[i*KK*DI + kdF];
  const float4 wB = ((const float4*)dtw_)[i*KK*DI + kdB];
  const float biasF = dtb_[i*KK*DI + kdF], biasB = dtb_[i*KK*DI + kdB];
  const float AvF = -fexp_(alog_[i*KK*DI + kdF]);
  const float AvB = -fexp_(alog_[i*KK*DI + kdB]);
  const float Dsum = Ds_[i*KK*DI + kdF] + Ds_[i*KK*DI + kdB];
  const int l0 = t*16;
  const int s0 = LL - 16 - l0;

  float vX[16], aF[16], bF[16], aB[16], bB[16];
  float fA = 1.f, fB = 0.f, gA = 1.f, gB = 0.f;
  LD16(vX, src + l0);

  {
    float pre[16], r0[16];
    LD16(r0, xdF + 0*LL + l0);
    #pragma unroll
    for(int j=0;j<16;++j) pre[j] = biasF + wF.x*r0[j];
    LD16(r0, xdF + 1*LL + l0);
    #pragma unroll
    for(int j=0;j<16;++j) pre[j] += wF.y*r0[j];
    LD16(r0, xdF + 2*LL + l0);
    #pragma unroll
    for(int j=0;j<16;++j) pre[j] += wF.z*r0[j];
    LD16(r0, xdF + 3*LL + l0);
    #pragma unroll
    for(int j=0;j<16;++j) pre[j] += wF.w*r0[j];
    LD16(r0, xdF + 4*LL + l0);   // Bs
    #pragma unroll
    for(int j=0;j<16;++j){
      const float delta = softplusf_(pre[j]);
      aF[j] = fexp_(delta*AvF);
      bF[j] = delta*r0[j]*vX[j];
      fB = fB*aF[j] + bF[j];
      fA *= aF[j];
    }
  }
  {
    float pre[16], r0[16];
    LD16R(r0, xdB + 0*LL + s0);
    #pragma unroll
    for(int j=0;j<16;++j) pre[j] = biasB + wB.x*r0[j];
    LD16R(r0, xdB + 1*LL + s0);
    #pragma unroll
    for(int j=0;j<16;++j) pre[j] += wB.y*r0[j];
    LD16R(r0, xdB + 2*LL + s0);
    #pragma unroll
    for(int j=0;j<16;++j) pre[j] += wB.z*r0[j];
    LD16R(r0, xdB + 3*LL + s0);
    #pragma unroll
    for(int j=0;j<16;++j) pre[j] += wB.w*r0[j];
    LD16R(r0, xdB + 4*LL + s0);  // Bs reversed
    #pragma unroll
    for(int j=15;j>=0;--j){
      const float delta = softplusf_(pre[j]);
      aB[j] = fexp_(delta*AvB);
      bB[j] = delta*r0[j]*vX[j];
      gB = gB*aB[j] + bB[j];
      gA *= aB[j];
    }
  }

  #pragma unroll
  for(int off=1; off<64; off<<=1){
    const float aL = __shfl_up(fA, off);
    const float bL = __shfl_up(fB, off);
    if(lane >= off){ fB = bL*fA + fB; fA = aL*fA; }
  }
  float pA = __shfl_up(fA, 1), pB = __shfl_up(fB, 1);
  if(lane==0){ pA=1.f; pB=0.f; }
  #pragma unroll
  for(int off=1; off<64; off<<=1){
    const float aR = __shfl_down(gA, off);
    const float bR = __shfl_down(gB, off);
    if(lane + off < 64){ gB = gA*bR + gB; gA = gA*aR; }
  }
  float qA = __shfl_down(gA, 1), qB = __shfl_down(gB, 1);
  if(lane==63){ qA=1.f; qB=0.f; }

  __shared__ float wAg[4], wBg[4], vAg[4], vBg[4];
  if(lane==63){ wAg[wv]=fA; wBg[wv]=fB; }
  if(lane==0){ vAg[wv]=gA; vBg[wv]=gB; }
  __syncthreads();
  float eB=0.f;
  for(int u=0; u<wv; ++u){ eB = wAg[u]*eB + wBg[u]; }
  float rB=0.f;
  for(int u=3; u>wv; --u){ rB = vAg[u]*rB + vBg[u]; }

  float hf = pA*eB + pB;
  float hb = qA*rB + qB;

  float out[16], cc[16];
  LD16(cc, xdF + 5*LL + l0);
  #pragma unroll
  for(int j=0;j<16;++j){
    hf = aF[j]*hf + bF[j];
    out[j] = hf*cc[j] + Dsum*vX[j];
  }
  LD16R(cc, xdB + 5*LL + s0);
  #pragma unroll
  for(int j=15;j>=0;--j){
    hb = aB[j]*hb + bB[j];
    out[j] += hb*cc[j];
  }
  float4* d4 = (float4*)(dst + l0);
  d4[0] = make_float4(out[0],out[1],out[2],out[3]);
  d4[1] = make_float4(out[4],out[5],out[6],out[7]);
  d4[2] = make_float4(out[8],out[9],out[10],out[11]);
  d4[3] = make_float4(out[12],out[13],out[14],out[15]);
}

// K3c: combine y + transpose(yT) into d-major ycombT[d][b*LL+l].
__global__ __launch_bounds__(256) void k3c_combine(float* __restrict__ ws)
{
  const int i = blockIdx.y;
  const int b = blockIdx.x >> 4;
  const int tile = blockIdx.x & 15;
  const int h0 = (tile >> 2) * 16, w0 = (tile & 3) * 16;
  const int t = threadIdx.x;
  float* base = ws + (size_t)i*ISTRIDE;
  const float* y  = base + OFF_Y;
  const float* yT = base + OFF_YT;
  float* ycT = base + OFF_YCOMBT;
  __shared__ float ytile[16*16*16];
  __shared__ float ytT[16*16*17];
  const int r0 = t >> 4, c0 = t & 15;
  const int hi = t >> 4, wi = t & 15;
  const int l = (h0 + hi)*64 + (w0 + wi);
  for(int dc=0; dc<8; ++dc){
    #pragma unroll 4
    for(int dd=0; dd<16; ++dd){
      const int d = dc*16 + dd;
      const size_t rb = (size_t)(b*DI + d)*LL;
      ytile[dd*256 + t] = y[rb + (size_t)(h0 + r0)*64 + (w0 + c0)];
      ytT[dd*272 + r0*17 + c0] = yT[rb + (size_t)(w0 + r0)*64 + (h0 + c0)];
    }
    __syncthreads();
    #pragma unroll 4
    for(int dd=0; dd<16; ++dd){
      const int d = dc*16 + dd;
      ycT[(size_t)d*LB + b*LL + l] = ytile[dd*256 + t] + ytT[dd*272 + wi*17 + hi];
    }
    __syncthreads();
  }
}

// K4a: block = 4 waves = 2 pixel-groups x 2 K-chunks. lane = pixel.
__global__ __launch_bounds__(256) void k4a_proj(
    const float* __restrict__ xmag, const float* __restrict__ xph,
    const float* __restrict__ onw_, const float* __restrict__ onb_,
    const float* __restrict__ opw_, float* __restrict__ ws)
{
  const int i = blockIdx.y;
  const float* xin = i ? xph : xmag;
  const float* onw = onw_ + i*DI;
  const float* onb = onb_ + i*DI;
  const float* opw = opw_ + i*CC*DI;
  float* base = ws + (size_t)i*ISTRIDE;
  const float* ycT = base + OFF_YCOMBT;
  const float* zT  = base + OFF_Z;
  const int t = threadIdx.x, lane = t & 63, wv = t >> 6;
  const int g = wv >> 1;
  const int ch = __builtin_amdgcn_readfirstlane(wv & 1);
  const int p = blockIdx.x*128 + g*64 + lane;
  float yv[64];
  float s1=0.f, s2=0.f;
  #pragma unroll 8
  for(int c=0;c<64;++c){
    const float v = ycT[(size_t)(ch*64+c)*LB + p];
    yv[c]=v; s1+=v; s2+=v*v;
  }
  __shared__ float st[2][64][4];
  st[g][lane][ch*2]=s1; st[g][lane][ch*2+1]=s2;
  __syncthreads();
  const float S1 = st[g][lane][0]+st[g][lane][2];
  const float S2 = st[g][lane][1]+st[g][lane][3];
  const float mu = S1*(1.f/DI);
  const float rs = rsqrtf(S2*(1.f/DI) - mu*mu + EPSF);
  #pragma unroll 8
  for(int c=0;c<64;++c){
    const int d = ch*64+c;
    yv[c] = ((yv[c]-mu)*rs*onw[d] + onb[d]) * zT[(size_t)d*LB + p];
  }
  float acc[64];
  #pragma unroll 2
  for(int o=0;o<64;++o){
    const float* wr = opw + o*DI + ch*64;
    float a = 0.f;
    #pragma unroll
    for(int c=0;c<64;++c) a += yv[c]*wr[c];
    acc[o] = a;
  }
  __shared__ float ab[2][64*65];
  if(ch==0){
    #pragma unroll 8
    for(int o=0;o<64;++o) ab[g][lane*65+o] = acc[o];
  }
  __syncthreads();
  if(ch==1){
    #pragma unroll 8
    for(int o=0;o<64;++o) ab[g][lane*65+o] += acc[o];
  }
  __syncthreads();
  const int pxl = t >> 1, oh = (t & 1)*32;
  const int gg = pxl >> 6, ll = pxl & 63;
  const int pg = blockIdx.x*128 + pxl;
  float* xnew = base + OFF_XNEW + (size_t)pg*CC + oh;
  const float* xi = xin + (size_t)pg*CC + oh;
  #pragma unroll
  for(int q=0;q<8;++q){
    float4 v;
    v.x = ab[gg][ll*65+oh+4*q  ] + xi[4*q  ];
    v.y = ab[gg][ll*65+oh+4*q+1] + xi[4*q+1];
    v.z = ab[gg][ll*65+oh+4*q+2] + xi[4*q+2];
    v.w = ab[gg][ll*65+oh+4*q+3] + xi[4*q+3];
    ((float4*)xnew)[q] = v;
  }
}

// K4b v7 (MFMA): 64-pixel tile per block, 4 waves. LN (fp32) -> bf16 H in LDS;
// per 128-j half: stage F1/F2 bf16, fc1 mfma 16x16x32, GELU, fc2 mfma.
__global__ __launch_bounds__(256) void k4b_mlp(
    const float* __restrict__ n2w_, const float* __restrict__ n2b_,
    const float* __restrict__ f1w_, const float* __restrict__ f1b_,
    const float* __restrict__ f2w_, const float* __restrict__ f2b_,
    float* __restrict__ ws)
{
  const int i = blockIdx.y;
  const float* n2w = n2w_ + i*CC;
  const float* n2b = n2b_ + i*CC;
  const float* f1w = f1w_ + i*256*64;    // [j][c]
  const float* f1b = f1b_ + i*256;
  const float* f2w = f2w_ + i*64*256;    // [o][j]
  const float* f2b = f2b_ + i*CC;
  float* base = ws + (size_t)i*ISTRIDE;
  const float* xnew = base + OFF_XNEW;
  const int t = threadIdx.x, lane = t & 63;
  const int wv = __builtin_amdgcn_readfirstlane(t >> 6);
  const int m = lane & 15, quad = lane >> 4;
  const int p0 = blockIdx.x*64;

  __shared__ short hlds[64*72];
  __shared__ short w1lds[128*72];
  __shared__ short glds[64*136];
  __shared__ short w2lds[64*136];

  {
    float h2[64];
    const float* xr = xnew + (size_t)(p0 + lane)*CC;
    LD16(h2, xr); LD16((h2+16), xr+16); LD16((h2+32), xr+32); LD16((h2+48), xr+48);
    float s1=0.f, s2=0.f;
    #pragma unroll
    for(int c=0;c<CC;++c){ s1 += h2[c]; s2 += h2[c]*h2[c]; }
    const float mu = s1*(1.f/CC);
    const float rs = rsqrtf(s2*(1.f/CC) - mu*mu + EPSF);
    if(wv==0){
      #pragma unroll
      for(int q=0;q<8;++q){
        v8s s;
        #pragma unroll
        for(int e=0;e<8;++e){
          const int c = q*8+e;
          s[e] = bf16_((h2[c]-mu)*rs*n2w[c] + n2b[c]);
        }
        *(v8s*)&hlds[lane*72 + q*8] = s;
      }
    }
  }

  v4f acc2[4];
  #pragma unroll
  for(int n=0;n<4;++n) acc2[n] = (v4f){0.f,0.f,0.f,0.f};

  for(int h=0; h<2; ++h){
    if(h) __syncthreads();
    {
      const int jl = t >> 1, hc = (t & 1)*32;
      const float* src = f1w + (size_t)(h*128 + jl)*64 + hc;
      #pragma unroll
      for(int q=0;q<4;++q){
        const float4 fa = ((const float4*)src)[q*2];
        const float4 fb = ((const float4*)src)[q*2+1];
        v8s s;
        s[0]=bf16_(fa.x); s[1]=bf16_(fa.y); s[2]=bf16_(fa.z); s[3]=bf16_(fa.w);
        s[4]=bf16_(fb.x); s[5]=bf16_(fb.y); s[6]=bf16_(fb.z); s[7]=bf16_(fb.w);
        *(v8s*)&w1lds[jl*72 + hc + q*8] = s;
      }
    }
    {
      const int ol = t >> 2, seg = (t & 3)*32;
      const float* src = f2w + (size_t)ol*256 + h*128 + seg;
      #pragma unroll
      for(int q=0;q<4;++q){
        const float4 fa = ((const float4*)src)[q*2];
        const float4 fb = ((const float4*)src)[q*2+1];
        v8s s;
        s[0]=bf16_(fa.x); s[1]=bf16_(fa.y); s[2]=bf16_(fa.z); s[3]=bf16_(fa.w);
        s[4]=bf16_(fb.x); s[5]=bf16_(fb.y); s[6]=bf16_(fb.z); s[7]=bf16_(fb.w);
        *(v8s*)&w2lds[ol*136 + seg + q*8] = s;
      }
    }
    __syncthreads();
    #pragma unroll 2
    for(int nt=0; nt<8; ++nt){
      v4f acc = (v4f){0.f,0.f,0.f,0.f};
      #pragma unroll
      for(int ks=0; ks<2; ++ks){
        const v8s a = *(const v8s*)&hlds[(wv*16 + m)*72 + ks*32 + quad*8];
        const v8s b = *(const v8s*)&w1lds[(nt*16 + m)*72 + ks*32 + quad*8];
        acc = __builtin_amdgcn_mfma_f32_16x16x32_bf16(a, b, acc, 0, 0, 0);
      }
      const float bj = f1b[h*128 + nt*16 + m];
      #pragma unroll
      for(int r=0;r<4;++r){
        glds[(wv*16 + quad*4 + r)*136 + nt*16 + m] = bf16_(geluf_(acc[r] + bj));
      }
    }
    #pragma unroll
    for(int nt=0; nt<4; ++nt){
      v4f acc = acc2[nt];
      #pragma unroll
      for(int ks=0; ks<4; ++ks){
        const v8s a = *(const v8s*)&glds[(wv*16 + m)*136 + ks*32 + quad*8];
        const v8s b = *(const v8s*)&w2lds[(nt*16 + m)*136 + ks*32 + quad*8];
        acc = __builtin_amdgcn_mfma_f32_16x16x32_bf16(a, b, acc, 0, 0, 0);
      }
      acc2[nt] = acc;
    }
  }

  float* sb = base + OFF_SB;
  #pragma unroll
  for(int nt=0; nt<4; ++nt){
    const float bo = f2b[nt*16 + m];
    #pragma unroll
    for(int r=0;r<4;++r){
      const int p = p0 + wv*16 + quad*4 + r;
      const int o = nt*16 + m;
      sb[(size_t)p*CC + o] = acc2[nt][r] + bo + xnew[(size_t)p*CC + o];
    }
  }
}

// K5: s = inst0 + inst1; write to both output halves
__global__ __launch_bounds__(256) void k5_final(
    const float* __restrict__ ws, float* __restrict__ out)
{
  const int idx = blockIdx.x*256 + threadIdx.x;
  const float v = ws[OFF_SB + idx] + ws[ISTRIDE + OFF_SB + idx];
  out[idx] = v;
  out[NPIX + idx] = v;
}

extern "C" void kernel_launch(void* const* d_in, const int* in_sizes, int n_in,
                              void* d_out, int out_size, void* d_ws, size_t ws_size,
                              hipStream_t stream)
{
  const float* mag  = (const float*)d_in[0];
  const float* ph   = (const float*)d_in[1];
  const float* n1w  = (const float*)d_in[2];
  const float* n1b  = (const float*)d_in[3];
  const float* ipw  = (const float*)d_in[4];
  const float* cw   = (const float*)d_in[5];
  const float* xpw  = (const float*)d_in[6];
  const float* dtw  = (const float*)d_in[7];
  const float* dtb  = (const float*)d_in[8];
  const float* alog = (const float*)d_in[9];
  const float* Ds   = (const float*)d_in[10];
  const float* onw  = (const float*)d_in[11];
  const float* onb  = (const float*)d_in[12];
  const float* opw  = (const float*)d_in[13];
  const float* n2w  = (const float*)d_in[14];
  const float* n2b  = (const float*)d_in[15];
  const float* f1w  = (const float*)d_in[16];
  const float* f1b  = (const float*)d_in[17];
  const float* f2w  = (const float*)d_in[18];
  const float* f2b  = (const float*)d_in[19];
  float* ws = (float*)d_ws;
  float* out = (float*)d_out;

  k1_ln_inproj<<<dim3(512,2),  256, 0, stream>>>(mag, ph, n1w, n1b, ipw, ws);
  k2_dwconv   <<<dim3(1024,2), 256, 0, stream>>>(cw, ws);
  k3a_xproj   <<<dim3(16,32,2),256, 0, stream>>>(xpw, ws);
  k3b_scan    <<<dim3(2048,2), 256, 0, stream>>>(dtw, dtb, alog, Ds, ws);
  k3c_combine <<<dim3(128,2),  256, 0, stream>>>(ws);
  k4a_proj    <<<dim3(256,2),  256, 0, stream>>>(mag, ph, onw, onb, opw, ws);
  k4b_mlp     <<<dim3(512,2),  256, 0, stream>>>(n2w, n2b, f1w, f1b, f2w, f2b, ws);
  k5_final    <<<dim3(8192),   256, 0, stream>>>(ws, out);
}

// Round 13
// 386.922 us; speedup vs baseline: 2.3070x; 1.1951x over previous
//
#include <hip/hip_runtime.h>
#include <math.h>

// Problem constants
#define LL   4096      // H*W
#define DI   128       // 2*C
#define CC   64        // C
#define BB   8         // batch
#define KK   4         // scan directions
#define LB   32768     // pixels per instance
#define NPIX 2097152   // B*H*W*C elements of s
#define EPSF 1e-5f

// Workspace layout (floats, per instance)
#define OFF_XCIN   ((size_t)0)
#define OFF_XCONV  ((size_t)4194304)
#define OFF_XCONVT ((size_t)8388608)
#define OFF_Z      ((size_t)12582912)
#define OFF_Y      ((size_t)16777216)
#define OFF_YT     ((size_t)20971520)
#define OFF_XDBL   ((size_t)25165824)
#define ISTRIDE    ((size_t)25952256)   // floats per instance
// Aliases (lifetime-disjoint reuse):
#define OFF_YCOMBT OFF_XCIN             // xcin dead after k2; ycombT (d-major) by k3c
#define OFF_XNEW   OFF_YT               // yT dead after k3c; xnew (pixel-major) by k4a
#define OFF_SB     OFF_Y                // y dead after k3c; sbuf by k4b

typedef short v8s __attribute__((ext_vector_type(8)));
typedef float v4f __attribute__((ext_vector_type(4)));

// Fast transcendentals: native v_exp/v_log paths (error ~1e-7, threshold 0.144)
__device__ __forceinline__ float fexp_(float x){ return __expf(x); }
__device__ __forceinline__ float silu_(float x){ return __fdividef(x, 1.f+__expf(-x)); }
__device__ __forceinline__ float softplusf_(float x){
  return fmaxf(x,0.f) + __logf(1.f + __expf(-fabsf(x)));
}
__device__ __forceinline__ float geluf_(float x){ return 0.5f*x*(1.f+erff(x*0.70710678118f)); }
__device__ __forceinline__ short bf16_(float x){
  unsigned u = __float_as_uint(x);
  u += 0x7FFF + ((u>>16)&1);     // RNE
  return (short)(u>>16);
}

#define LD16(dst, ptr) { const float4* p4_=(const float4*)(ptr);                 \
  float4 v0_=p4_[0], v1_=p4_[1], v2_=p4_[2], v3_=p4_[3];                         \
  dst[0]=v0_.x; dst[1]=v0_.y; dst[2]=v0_.z; dst[3]=v0_.w;                        \
  dst[4]=v1_.x; dst[5]=v1_.y; dst[6]=v1_.z; dst[7]=v1_.w;                        \
  dst[8]=v2_.x; dst[9]=v2_.y; dst[10]=v2_.z; dst[11]=v2_.w;                      \
  dst[12]=v3_.x; dst[13]=v3_.y; dst[14]=v3_.z; dst[15]=v3_.w; }
#define LD16R(dst, ptr) { const float4* p4_=(const float4*)(ptr);                \
  float4 v0_=p4_[0], v1_=p4_[1], v2_=p4_[2], v3_=p4_[3];                         \
  dst[15]=v0_.x; dst[14]=v0_.y; dst[13]=v0_.z; dst[12]=v0_.w;                    \
  dst[11]=v1_.x; dst[10]=v1_.y; dst[9]=v1_.z;  dst[8]=v1_.w;                     \
  dst[7]=v2_.x;  dst[6]=v2_.y;  dst[5]=v2_.z;  dst[4]=v2_.w;                     \
  dst[3]=v3_.x;  dst[2]=v3_.y;  dst[1]=v3_.z;  dst[0]=v3_.w; }

// K1 v4: block = 4 waves over SAME 64 pixels (lane=pixel). Wave ch owns a 64-row
// chunk of the 256 in_proj outputs; rows 4-at-a-time (s_load stream interleave).
__global__ __launch_bounds__(256) void k1_ln_inproj(
    const float* __restrict__ xmag, const float* __restrict__ xph,
    const float* __restrict__ n1w_, const float* __restrict__ n1b_,
    const float* __restrict__ ipw_, float* __restrict__ ws)
{
  const int i = blockIdx.y;
  const float* xin = i ? xph : xmag;
  const float* n1w = n1w_ + i*CC;
  const float* n1b = n1b_ + i*CC;
  const float* ipw = ipw_ + i*2*DI*CC;
  float* base = ws + (size_t)i*ISTRIDE;
  const int t = threadIdx.x, lane = t & 63;
  const int ch = __builtin_amdgcn_readfirstlane(t >> 6);
  const int p = blockIdx.x*64 + lane;
  const int b = p >> 12, l = p & (LL-1);
  float hn[CC];
  LD16(hn, xin + (size_t)p*CC);
  LD16((hn+16), xin + (size_t)p*CC + 16);
  LD16((hn+32), xin + (size_t)p*CC + 32);
  LD16((hn+48), xin + (size_t)p*CC + 48);
  float s1=0.f, s2=0.f;
  #pragma unroll
  for(int c=0;c<CC;++c){ s1 += hn[c]; s2 += hn[c]*hn[c]; }
  const float mu = s1*(1.f/CC);
  const float rs = rsqrtf(s2*(1.f/CC) - mu*mu + EPSF);
  #pragma unroll
  for(int c=0;c<CC;++c) hn[c] = (hn[c]-mu)*rs*n1w[c] + n1b[c];
  if(ch < 2){
    float* xcb = base + OFF_XCIN + (size_t)b*DI*LL + l;
    for(int jg=0;jg<16;++jg){
      const int j = ch*64 + jg*4;
      const float* w0 = ipw + (j+0)*CC;
      const float* w1 = ipw + (j+1)*CC;
      const float* w2 = ipw + (j+2)*CC;
      const float* w3 = ipw + (j+3)*CC;
      float a0=0.f,a1=0.f,a2=0.f,a3=0.f;
      #pragma unroll
      for(int c=0;c<CC;++c){
        const float h = hn[c];
        a0 += h*w0[c]; a1 += h*w1[c]; a2 += h*w2[c]; a3 += h*w3[c];
      }
      xcb[(size_t)(j+0)*LL] = a0;
      xcb[(size_t)(j+1)*LL] = a1;
      xcb[(size_t)(j+2)*LL] = a2;
      xcb[(size_t)(j+3)*LL] = a3;
    }
  } else {
    float* zT = base + OFF_Z;
    for(int jg=0;jg<16;++jg){
      const int d = (ch-2)*64 + jg*4;
      const float* w0 = ipw + (DI+d+0)*CC;
      const float* w1 = ipw + (DI+d+1)*CC;
      const float* w2 = ipw + (DI+d+2)*CC;
      const float* w3 = ipw + (DI+d+3)*CC;
      float a0=0.f,a1=0.f,a2=0.f,a3=0.f;
      #pragma unroll
      for(int c=0;c<CC;++c){
        const float h = hn[c];
        a0 += h*w0[c]; a1 += h*w1[c]; a2 += h*w2[c]; a3 += h*w3[c];
      }
      zT[(size_t)(d+0)*LB + p] = silu_(a0);
      zT[(size_t)(d+1)*LB + p] = silu_(a1);
      zT[(size_t)(d+2)*LB + p] = silu_(a2);
      zT[(size_t)(d+3)*LB + p] = silu_(a3);
    }
  }
}

// K2: depthwise 3x3 conv + silu; per (b,d) 64x64 tile via LDS; row-major + transposed out
__global__ __launch_bounds__(256) void k2_dwconv(
    const float* __restrict__ cw_, float* __restrict__ ws)
{
  const int i = blockIdx.y;
  const int bd = blockIdx.x;
  const int d = bd & (DI-1);
  const float* cw = cw_ + i*DI*9 + d*9;
  const float* xcin  = ws + (size_t)i*ISTRIDE + OFF_XCIN  + (size_t)bd*LL;
  float* xconv  = ws + (size_t)i*ISTRIDE + OFF_XCONV  + (size_t)bd*LL;
  float* xconvT = ws + (size_t)i*ISTRIDE + OFF_XCONVT + (size_t)bd*LL;
  __shared__ float tin[64*65];
  __shared__ float tout[64*65];
  const int t = threadIdx.x;
  float w9[9];
  #pragma unroll
  for(int q=0;q<9;++q) w9[q] = cw[q];
  for(int idx=t; idx<4096; idx+=256)
    tin[(idx>>6)*65 + (idx&63)] = xcin[idx];
  __syncthreads();
  const int w = t & 63, hb = (t>>6)*16;
  #pragma unroll
  for(int r=0;r<16;++r){
    const int h = hb + r;
    float acc = 0.f;
    #pragma unroll
    for(int dy=0;dy<3;++dy){
      const int hh = h + dy - 1;
      if(hh>=0 && hh<64){
        #pragma unroll
        for(int dx=0;dx<3;++dx){
          const int ww = w + dx - 1;
          if(ww>=0 && ww<64) acc += tin[hh*65+ww]*w9[dy*3+dx];
        }
      }
    }
    const float o = silu_(acc);
    tout[h*65+w] = o;
    xconv[h*64+w] = o;
  }
  __syncthreads();
  const int hcol = t & 63, wb = (t>>6)*16;
  #pragma unroll
  for(int r=0;r<16;++r){
    const int wp = wb + r;
    xconvT[wp*64 + hcol] = tout[hcol*65 + wp];
  }
}

// K3a: x_dbl = x_proj(xs) -> (dts[4], Bs, Cs) per (b,k,scan-pos)
__global__ __launch_bounds__(256) void k3a_xproj(
    const float* __restrict__ xpw_, float* __restrict__ ws)
{
  const int i = blockIdx.z;
  const int b = blockIdx.y >> 2;
  const int k = blockIdx.y & 3;
  const int l = blockIdx.x*256 + threadIdx.x;
  const float* src = ws + (size_t)i*ISTRIDE + ((k&1)? OFF_XCONVT : OFF_XCONV) + (size_t)b*DI*LL;
  const int ridx = (k>=2) ? (LL-1-l) : l;
  const float* xpw = xpw_ + i*KK*6*DI + k*6*DI;
  float acc[6] = {0,0,0,0,0,0};
  for(int d=0; d<DI; ++d){
    const float xv = src[(size_t)d*LL + ridx];
    #pragma unroll
    for(int c=0;c<6;++c) acc[c] += xv * xpw[c*DI + d];
  }
  float* xdbl = ws + (size_t)i*ISTRIDE + OFF_XDBL + (size_t)(b*KK+k)*6*LL;
  #pragma unroll
  for(int c=0;c<6;++c) xdbl[(size_t)c*LL + l] = acc[c];
}

// K3b: paired fwd/bwd selective scan; phase-split regs + wave shuffle scan, 1 barrier.
__global__ __launch_bounds__(256,3) void k3b_scan(
    const float* __restrict__ dtw_, const float* __restrict__ dtb_,
    const float* __restrict__ alog_, const float* __restrict__ Ds_,
    float* __restrict__ ws)
{
  const int gid = blockIdx.x;           // b*256 + kp*128 + d
  const int i = blockIdx.y;
  const int d  = gid & (DI-1);
  const int kp = (gid >> 7) & 1;
  const int b  = gid >> 8;
  const int t = threadIdx.x, lane = t & 63, wv = t >> 6;
  float* base = ws + (size_t)i*ISTRIDE;
  const float* src = base + (kp? OFF_XCONVT : OFF_XCONV) + (size_t)(b*DI+d)*LL;
  float*       dst = base + (kp? OFF_YT    : OFF_Y    ) + (size_t)(b*DI+d)*LL;
  const float* xdF = base + OFF_XDBL + (size_t)(b*KK+kp  )*6*LL;
  const float* xdB = base + OFF_XDBL + (size_t)(b*KK+kp+2)*6*LL;
  const int kdF = kp*DI + d, kdB = (kp+2)*DI + d;
  const float4 wF = ((const float4*)dtw_)[i*KK*DI + kdF];
  const float4 wB = ((const float4*)dtw_)[i*KK*DI + kdB];
  const float biasF = dtb_[i*KK*DI + kdF], biasB = dtb_[i*KK*DI + kdB];
  const float AvF = -fexp_(alog_[i*KK*DI + kdF]);
  const float AvB = -fexp_(alog_[i*KK*DI + kdB]);
  const float Dsum = Ds_[i*KK*DI + kdF] + Ds_[i*KK*DI + kdB];
  const int l0 = t*16;
  const int s0 = LL - 16 - l0;

  float vX[16], aF[16], bF[16], aB[16], bB[16];
  float fA = 1.f, fB = 0.f, gA = 1.f, gB = 0.f;
  LD16(vX, src + l0);

  {
    float pre[16], r0[16];
    LD16(r0, xdF + 0*LL + l0);
    #pragma unroll
    for(int j=0;j<16;++j) pre[j] = biasF + wF.x*r0[j];
    LD16(r0, xdF + 1*LL + l0);
    #pragma unroll
    for(int j=0;j<16;++j) pre[j] += wF.y*r0[j];
    LD16(r0, xdF + 2*LL + l0);
    #pragma unroll
    for(int j=0;j<16;++j) pre[j] += wF.z*r0[j];
    LD16(r0, xdF + 3*LL + l0);
    #pragma unroll
    for(int j=0;j<16;++j) pre[j] += wF.w*r0[j];
    LD16(r0, xdF + 4*LL + l0);   // Bs
    #pragma unroll
    for(int j=0;j<16;++j){
      const float delta = softplusf_(pre[j]);
      aF[j] = fexp_(delta*AvF);
      bF[j] = delta*r0[j]*vX[j];
      fB = fB*aF[j] + bF[j];
      fA *= aF[j];
    }
  }
  {
    float pre[16], r0[16];
    LD16R(r0, xdB + 0*LL + s0);
    #pragma unroll
    for(int j=0;j<16;++j) pre[j] = biasB + wB.x*r0[j];
    LD16R(r0, xdB + 1*LL + s0);
    #pragma unroll
    for(int j=0;j<16;++j) pre[j] += wB.y*r0[j];
    LD16R(r0, xdB + 2*LL + s0);
    #pragma unroll
    for(int j=0;j<16;++j) pre[j] += wB.z*r0[j];
    LD16R(r0, xdB + 3*LL + s0);
    #pragma unroll
    for(int j=0;j<16;++j) pre[j] += wB.w*r0[j];
    LD16R(r0, xdB + 4*LL + s0);  // Bs reversed
    #pragma unroll
    for(int j=15;j>=0;--j){
      const float delta = softplusf_(pre[j]);
      aB[j] = fexp_(delta*AvB);
      bB[j] = delta*r0[j]*vX[j];
      gB = gB*aB[j] + bB[j];
      gA *= aB[j];
    }
  }

  #pragma unroll
  for(int off=1; off<64; off<<=1){
    const float aL = __shfl_up(fA, off);
    const float bL = __shfl_up(fB, off);
    if(lane >= off){ fB = bL*fA + fB; fA = aL*fA; }
  }
  float pA = __shfl_up(fA, 1), pB = __shfl_up(fB, 1);
  if(lane==0){ pA=1.f; pB=0.f; }
  #pragma unroll
  for(int off=1; off<64; off<<=1){
    const float aR = __shfl_down(gA, off);
    const float bR = __shfl_down(gB, off);
    if(lane + off < 64){ gB = gA*bR + gB; gA = gA*aR; }
  }
  float qA = __shfl_down(gA, 1), qB = __shfl_down(gB, 1);
  if(lane==63){ qA=1.f; qB=0.f; }

  __shared__ float wAg[4], wBg[4], vAg[4], vBg[4];
  if(lane==63){ wAg[wv]=fA; wBg[wv]=fB; }
  if(lane==0){ vAg[wv]=gA; vBg[wv]=gB; }
  __syncthreads();
  float eB=0.f;
  for(int u=0; u<wv; ++u){ eB = wAg[u]*eB + wBg[u]; }
  float rB=0.f;
  for(int u=3; u>wv; --u){ rB = vAg[u]*rB + vBg[u]; }

  float hf = pA*eB + pB;
  float hb = qA*rB + qB;

  float out[16], cc[16];
  LD16(cc, xdF + 5*LL + l0);
  #pragma unroll
  for(int j=0;j<16;++j){
    hf = aF[j]*hf + bF[j];
    out[j] = hf*cc[j] + Dsum*vX[j];
  }
  LD16R(cc, xdB + 5*LL + s0);
  #pragma unroll
  for(int j=15;j>=0;--j){
    hb = aB[j]*hb + bB[j];
    out[j] += hb*cc[j];
  }
  float4* d4 = (float4*)(dst + l0);
  d4[0] = make_float4(out[0],out[1],out[2],out[3]);
  d4[1] = make_float4(out[4],out[5],out[6],out[7]);
  d4[2] = make_float4(out[8],out[9],out[10],out[11]);
  d4[3] = make_float4(out[12],out[13],out[14],out[15]);
}

// K3c: combine y + transpose(yT) into d-major ycombT[d][b*LL+l].
__global__ __launch_bounds__(256) void k3c_combine(float* __restrict__ ws)
{
  const int i = blockIdx.y;
  const int b = blockIdx.x >> 4;
  const int tile = blockIdx.x & 15;
  const int h0 = (tile >> 2) * 16, w0 = (tile & 3) * 16;
  const int t = threadIdx.x;
  float* base = ws + (size_t)i*ISTRIDE;
  const float* y  = base + OFF_Y;
  const float* yT = base + OFF_YT;
  float* ycT = base + OFF_YCOMBT;
  __shared__ float ytile[16*16*16];
  __shared__ float ytT[16*16*17];
  const int r0 = t >> 4, c0 = t & 15;
  const int hi = t >> 4, wi = t & 15;
  const int l = (h0 + hi)*64 + (w0 + wi);
  for(int dc=0; dc<8; ++dc){
    #pragma unroll 4
    for(int dd=0; dd<16; ++dd){
      const int d = dc*16 + dd;
      const size_t rb = (size_t)(b*DI + d)*LL;
      ytile[dd*256 + t] = y[rb + (size_t)(h0 + r0)*64 + (w0 + c0)];
      ytT[dd*272 + r0*17 + c0] = yT[rb + (size_t)(w0 + r0)*64 + (h0 + c0)];
    }
    __syncthreads();
    #pragma unroll 4
    for(int dd=0; dd<16; ++dd){
      const int d = dc*16 + dd;
      ycT[(size_t)d*LB + b*LL + l] = ytile[dd*256 + t] + ytT[dd*272 + wi*17 + hi];
    }
    __syncthreads();
  }
}

// K4a v3 (MFMA): block = 64 pixels, 4 waves. Wave wv loads d-chunk [wv*32,+32)
// (lane=pixel, coalesced), LN stats via padded LDS, normalize*z -> bf16
// ynlds[px][136]; stage opw rows -> bf16 wlds[o][136]; out_proj via
// mfma_f32_16x16x32_bf16 (wave owns pixel rows [wv*16,+16)); +xin -> xnew.
__global__ __launch_bounds__(256) void k4a_proj(
    const float* __restrict__ xmag, const float* __restrict__ xph,
    const float* __restrict__ onw_, const float* __restrict__ onb_,
    const float* __restrict__ opw_, float* __restrict__ ws)
{
  const int i = blockIdx.y;
  const float* xin = i ? xph : xmag;
  const float* onw = onw_ + i*DI;
  const float* onb = onb_ + i*DI;
  const float* opw = opw_ + i*CC*DI;     // [o][d] = [64][128]
  float* base = ws + (size_t)i*ISTRIDE;
  const float* ycT = base + OFF_YCOMBT;
  const float* zT  = base + OFF_Z;
  const int t = threadIdx.x, lane = t & 63;
  const int wv = __builtin_amdgcn_readfirstlane(t >> 6);
  const int m = lane & 15, quad = lane >> 4;
  const int p0 = blockIdx.x*64;
  const int p = p0 + lane;

  __shared__ short ynlds[64*136];   // [px][d+pad] bf16
  __shared__ short wlds[64*136];    // [o][d+pad] bf16
  __shared__ float st[64][9];       // per-pixel partial stats (pad 9: conflict-free)

  // wave wv: d-chunk [wv*32, +32), lane = pixel
  float yv[32];
  float s1=0.f, s2=0.f;
  #pragma unroll 8
  for(int c=0;c<32;++c){
    const float v = ycT[(size_t)(wv*32+c)*LB + p];
    yv[c]=v; s1+=v; s2+=v*v;
  }
  st[lane][wv*2]=s1; st[lane][wv*2+1]=s2;
  __syncthreads();
  const float S1 = st[lane][0]+st[lane][2]+st[lane][4]+st[lane][6];
  const float S2 = st[lane][1]+st[lane][3]+st[lane][5]+st[lane][7];
  const float mu = S1*(1.f/DI);
  const float rs = rsqrtf(S2*(1.f/DI) - mu*mu + EPSF);
  #pragma unroll
  for(int cq=0;cq<8;++cq){
    short4 s4;
    #pragma unroll
    for(int e=0;e<4;++e){
      const int c = cq*4+e;
      const int d = wv*32 + c;
      ((short*)&s4)[e] = bf16_(((yv[c]-mu)*rs*onw[d] + onb[d]) * zT[(size_t)d*LB + p]);
    }
    *(short4*)&ynlds[lane*136 + wv*32 + cq*4] = s4;
  }
  // stage opw: thread t -> row o = t>>2, seg (t&3)*32
  {
    const int ol = t >> 2, seg = (t & 3)*32;
    const float* src = opw + (size_t)ol*DI + seg;
    #pragma unroll
    for(int q=0;q<4;++q){
      const float4 fa = ((const float4*)src)[q*2];
      const float4 fb = ((const float4*)src)[q*2+1];
      v8s s;
      s[0]=bf16_(fa.x); s[1]=bf16_(fa.y); s[2]=bf16_(fa.z); s[3]=bf16_(fa.w);
      s[4]=bf16_(fb.x); s[5]=bf16_(fb.y); s[6]=bf16_(fb.z); s[7]=bf16_(fb.w);
      *(v8s*)&wlds[ol*136 + seg + q*8] = s;
    }
  }
  __syncthreads();

  // MFMA: wave wv owns pixel rows [wv*16,+16); 4 n-tiles x 4 k-steps
  v4f accs[4];
  #pragma unroll
  for(int nt=0; nt<4; ++nt){
    v4f acc = (v4f){0.f,0.f,0.f,0.f};
    #pragma unroll
    for(int ks=0; ks<4; ++ks){
      const v8s a = *(const v8s*)&ynlds[(wv*16 + m)*136 + ks*32 + quad*8];
      const v8s b = *(const v8s*)&wlds[(nt*16 + m)*136 + ks*32 + quad*8];
      acc = __builtin_amdgcn_mfma_f32_16x16x32_bf16(a, b, acc, 0, 0, 0);
    }
    accs[nt] = acc;
  }
  // epilogue: xnew = out_proj + xin  (C/D: col o = nt*16+m, row px = quad*4+r)
  float* xnew = base + OFF_XNEW;
  #pragma unroll
  for(int nt=0; nt<4; ++nt){
    #pragma unroll
    for(int r=0;r<4;++r){
      const int pp = p0 + wv*16 + quad*4 + r;
      const int o = nt*16 + m;
      xnew[(size_t)pp*CC + o] = accs[nt][r] + xin[(size_t)pp*CC + o];
    }
  }
}

// K4b v7 (MFMA): 64-pixel tile per block, 4 waves. LN (fp32) -> bf16 H in LDS;
// per 128-j half: stage F1/F2 bf16, fc1 mfma 16x16x32, GELU, fc2 mfma.
__global__ __launch_bounds__(256) void k4b_mlp(
    const float* __restrict__ n2w_, const float* __restrict__ n2b_,
    const float* __restrict__ f1w_, const float* __restrict__ f1b_,
    const float* __restrict__ f2w_, const float* __restrict__ f2b_,
    float* __restrict__ ws)
{
  const int i = blockIdx.y;
  const float* n2w = n2w_ + i*CC;
  const float* n2b = n2b_ + i*CC;
  const float* f1w = f1w_ + i*256*64;    // [j][c]
  const float* f1b = f1b_ + i*256;
  const float* f2w = f2w_ + i*64*256;    // [o][j]
  const float* f2b = f2b_ + i*CC;
  float* base = ws + (size_t)i*ISTRIDE;
  const float* xnew = base + OFF_XNEW;
  const int t = threadIdx.x, lane = t & 63;
  const int wv = __builtin_amdgcn_readfirstlane(t >> 6);
  const int m = lane & 15, quad = lane >> 4;
  const int p0 = blockIdx.x*64;

  __shared__ short hlds[64*72];
  __shared__ short w1lds[128*72];
  __shared__ short glds[64*136];
  __shared__ short w2lds[64*136];

  {
    float h2[64];
    const float* xr = xnew + (size_t)(p0 + lane)*CC;
    LD16(h2, xr); LD16((h2+16), xr+16); LD16((h2+32), xr+32); LD16((h2+48), xr+48);
    float s1=0.f, s2=0.f;
    #pragma unroll
    for(int c=0;c<CC;++c){ s1 += h2[c]; s2 += h2[c]*h2[c]; }
    const float mu = s1*(1.f/CC);
    const float rs = rsqrtf(s2*(1.f/CC) - mu*mu + EPSF);
    if(wv==0){
      #pragma unroll
      for(int q=0;q<8;++q){
        v8s s;
        #pragma unroll
        for(int e=0;e<8;++e){
          const int c = q*8+e;
          s[e] = bf16_((h2[c]-mu)*rs*n2w[c] + n2b[c]);
        }
        *(v8s*)&hlds[lane*72 + q*8] = s;
      }
    }
  }

  v4f acc2[4];
  #pragma unroll
  for(int n=0;n<4;++n) acc2[n] = (v4f){0.f,0.f,0.f,0.f};

  for(int h=0; h<2; ++h){
    if(h) __syncthreads();
    {
      const int jl = t >> 1, hc = (t & 1)*32;
      const float* src = f1w + (size_t)(h*128 + jl)*64 + hc;
      #pragma unroll
      for(int q=0;q<4;++q){
        const float4 fa = ((const float4*)src)[q*2];
        const float4 fb = ((const float4*)src)[q*2+1];
        v8s s;
        s[0]=bf16_(fa.x); s[1]=bf16_(fa.y); s[2]=bf16_(fa.z); s[3]=bf16_(fa.w);
        s[4]=bf16_(fb.x); s[5]=bf16_(fb.y); s[6]=bf16_(fb.z); s[7]=bf16_(fb.w);
        *(v8s*)&w1lds[jl*72 + hc + q*8] = s;
      }
    }
    {
      const int ol = t >> 2, seg = (t & 3)*32;
      const float* src = f2w + (size_t)ol*256 + h*128 + seg;
      #pragma unroll
      for(int q=0;q<4;++q){
        const float4 fa = ((const float4*)src)[q*2];
        const float4 fb = ((const float4*)src)[q*2+1];
        v8s s;
        s[0]=bf16_(fa.x); s[1]=bf16_(fa.y); s[2]=bf16_(fa.z); s[3]=bf16_(fa.w);
        s[4]=bf16_(fb.x); s[5]=bf16_(fb.y); s[6]=bf16_(fb.z); s[7]=bf16_(fb.w);
        *(v8s*)&w2lds[ol*136 + seg + q*8] = s;
      }
    }
    __syncthreads();
    #pragma unroll 2
    for(int nt=0; nt<8; ++nt){
      v4f acc = (v4f){0.f,0.f,0.f,0.f};
      #pragma unroll
      for(int ks=0; ks<2; ++ks){
        const v8s a = *(const v8s*)&hlds[(wv*16 + m)*72 + ks*32 + quad*8];
        const v8s b = *(const v8s*)&w1lds[(nt*16 + m)*72 + ks*32 + quad*8];
        acc = __builtin_amdgcn_mfma_f32_16x16x32_bf16(a, b, acc, 0, 0, 0);
      }
      const float bj = f1b[h*128 + nt*16 + m];
      #pragma unroll
      for(int r=0;r<4;++r){
        glds[(wv*16 + quad*4 + r)*136 + nt*16 + m] = bf16_(geluf_(acc[r] + bj));
      }
    }
    #pragma unroll
    for(int nt=0; nt<4; ++nt){
      v4f acc = acc2[nt];
      #pragma unroll
      for(int ks=0; ks<4; ++ks){
        const v8s a = *(const v8s*)&glds[(wv*16 + m)*136 + ks*32 + quad*8];
        const v8s b = *(const v8s*)&w2lds[(nt*16 + m)*136 + ks*32 + quad*8];
        acc = __builtin_amdgcn_mfma_f32_16x16x32_bf16(a, b, acc, 0, 0, 0);
      }
      acc2[nt] = acc;
    }
  }

  float* sb = base + OFF_SB;
  #pragma unroll
  for(int nt=0; nt<4; ++nt){
    const float bo = f2b[nt*16 + m];
    #pragma unroll
    for(int r=0;r<4;++r){
      const int p = p0 + wv*16 + quad*4 + r;
      const int o = nt*16 + m;
      sb[(size_t)p*CC + o] = acc2[nt][r] + bo + xnew[(size_t)p*CC + o];
    }
  }
}

// K5: s = inst0 + inst1; write to both output halves
__global__ __launch_bounds__(256) void k5_final(
    const float* __restrict__ ws, float* __restrict__ out)
{
  const int idx = blockIdx.x*256 + threadIdx.x;
  const float v = ws[OFF_SB + idx] + ws[ISTRIDE + OFF_SB + idx];
  out[idx] = v;
  out[NPIX + idx] = v;
}

extern "C" void kernel_launch(void* const* d_in, const int* in_sizes, int n_in,
                              void* d_out, int out_size, void* d_ws, size_t ws_size,
                              hipStream_t stream)
{
  const float* mag  = (const float*)d_in[0];
  const float* ph   = (const float*)d_in[1];
  const float* n1w  = (const float*)d_in[2];
  const float* n1b  = (const float*)d_in[3];
  const float* ipw  = (const float*)d_in[4];
  const float* cw   = (const float*)d_in[5];
  const float* xpw  = (const float*)d_in[6];
  const float* dtw  = (const float*)d_in[7];
  const float* dtb  = (const float*)d_in[8];
  const float* alog = (const float*)d_in[9];
  const float* Ds   = (const float*)d_in[10];
  const float* onw  = (const float*)d_in[11];
  const float* onb  = (const float*)d_in[12];
  const float* opw  = (const float*)d_in[13];
  const float* n2w  = (const float*)d_in[14];
  const float* n2b  = (const float*)d_in[15];
  const float* f1w  = (const float*)d_in[16];
  const float* f1b  = (const float*)d_in[17];
  const float* f2w  = (const float*)d_in[18];
  const float* f2b  = (const float*)d_in[19];
  float* ws = (float*)d_ws;
  float* out = (float*)d_out;

  k1_ln_inproj<<<dim3(512,2),  256, 0, stream>>>(mag, ph, n1w, n1b, ipw, ws);
  k2_dwconv   <<<dim3(1024,2), 256, 0, stream>>>(cw, ws);
  k3a_xproj   <<<dim3(16,32,2),256, 0, stream>>>(xpw, ws);
  k3b_scan    <<<dim3(2048,2), 256, 0, stream>>>(dtw, dtb, alog, Ds, ws);
  k3c_combine <<<dim3(128,2),  256, 0, stream>>>(ws);
  k4a_proj    <<<dim3(512,2),  256, 0, stream>>>(mag, ph, onw, onb, opw, ws);
  k4b_mlp     <<<dim3(512,2),  256, 0, stream>>>(n2w, n2b, f1w, f1b, f2w, f2b, ws);
  k5_final    <<<dim3(8192),   256, 0, stream>>>(ws, out);
}

// Round 14
// 364.605 us; speedup vs baseline: 2.4482x; 1.0612x over previous
//
#include <hip/hip_runtime.h>
#include <math.h>

// Problem constants
#define LL   4096      // H*W
#define DI   128       // 2*C
#define CC   64        // C
#define BB   8         // batch
#define KK   4         // scan directions
#define LB   32768     // pixels per instance
#define NPIX 2097152   // B*H*W*C elements of s
#define EPSF 1e-5f

// Workspace layout (floats, per instance)
#define OFF_XCIN   ((size_t)0)
#define OFF_XCONV  ((size_t)4194304)
#define OFF_XCONVT ((size_t)8388608)
#define OFF_Z      ((size_t)12582912)
#define OFF_Y      ((size_t)16777216)
#define OFF_YT     ((size_t)20971520)
#define OFF_XDBL   ((size_t)25165824)
#define ISTRIDE    ((size_t)25952256)   // floats per instance
// Aliases (lifetime-disjoint reuse):
#define OFF_YCOMBT OFF_XCIN             // xcin dead after k2; ycombT (d-major) by k3c
#define OFF_XNEW   OFF_YT               // yT dead after k3c; xnew (pixel-major) by k4a
#define OFF_SB     OFF_Y                // y dead after k3c; sbuf by k4b

typedef short v8s __attribute__((ext_vector_type(8)));
typedef float v4f __attribute__((ext_vector_type(4)));

// Fast transcendentals: native v_exp/v_log paths (error ~1e-7, threshold 0.144)
__device__ __forceinline__ float fexp_(float x){ return __expf(x); }
__device__ __forceinline__ float silu_(float x){ return __fdividef(x, 1.f+__expf(-x)); }
__device__ __forceinline__ float softplusf_(float x){
  return fmaxf(x,0.f) + __logf(1.f + __expf(-fabsf(x)));
}
__device__ __forceinline__ float geluf_(float x){ return 0.5f*x*(1.f+erff(x*0.70710678118f)); }
__device__ __forceinline__ short bf16_(float x){
  unsigned u = __float_as_uint(x);
  u += 0x7FFF + ((u>>16)&1);     // RNE
  return (short)(u>>16);
}

#define LD16(dst, ptr) { const float4* p4_=(const float4*)(ptr);                 \
  float4 v0_=p4_[0], v1_=p4_[1], v2_=p4_[2], v3_=p4_[3];                         \
  dst[0]=v0_.x; dst[1]=v0_.y; dst[2]=v0_.z; dst[3]=v0_.w;                        \
  dst[4]=v1_.x; dst[5]=v1_.y; dst[6]=v1_.z; dst[7]=v1_.w;                        \
  dst[8]=v2_.x; dst[9]=v2_.y; dst[10]=v2_.z; dst[11]=v2_.w;                      \
  dst[12]=v3_.x; dst[13]=v3_.y; dst[14]=v3_.z; dst[15]=v3_.w; }
#define LD16R(dst, ptr) { const float4* p4_=(const float4*)(ptr);                \
  float4 v0_=p4_[0], v1_=p4_[1], v2_=p4_[2], v3_=p4_[3];                         \
  dst[15]=v0_.x; dst[14]=v0_.y; dst[13]=v0_.z; dst[12]=v0_.w;                    \
  dst[11]=v1_.x; dst[10]=v1_.y; dst[9]=v1_.z;  dst[8]=v1_.w;                     \
  dst[7]=v2_.x;  dst[6]=v2_.y;  dst[5]=v2_.z;  dst[4]=v2_.w;                     \
  dst[3]=v3_.x;  dst[2]=v3_.y;  dst[1]=v3_.z;  dst[0]=v3_.w; }

// K1 v5 (MFMA): block = 64 pixels, 4 waves. LN (fp32) -> bf16 hlds; per 128-row
// half of ipw: stage w1lds (B^T rows), 8 n-tiles x 2 k-steps of
// mfma_f32_16x16x32_bf16, C-frags -> fp32 outs[j][68] -> coalesced stores:
// h=0 rows -> xc (b,d,l layout), h=1 rows -> silu -> zT (d-major).
__global__ __launch_bounds__(256) void k1_ln_inproj(
    const float* __restrict__ xmag, const float* __restrict__ xph,
    const float* __restrict__ n1w_, const float* __restrict__ n1b_,
    const float* __restrict__ ipw_, float* __restrict__ ws)
{
  const int i = blockIdx.y;
  const float* xin = i ? xph : xmag;
  const float* n1w = n1w_ + i*CC;
  const float* n1b = n1b_ + i*CC;
  const float* ipw = ipw_ + i*2*DI*CC;   // [256][64]
  float* base = ws + (size_t)i*ISTRIDE;
  const int t = threadIdx.x, lane = t & 63;
  const int wv = __builtin_amdgcn_readfirstlane(t >> 6);
  const int m = lane & 15, quad = lane >> 4;
  const int p0 = blockIdx.x*64;
  const int b = p0 >> 12, l0 = p0 & (LL-1);

  __shared__ short hlds[64*72];     //  9216 B
  __shared__ short w1lds[128*72];   // 18432 B
  __shared__ float outs[128*68];    // 34816 B

  // LN per pixel (lane=pixel; redundant per wave; wave0 stores bf16)
  {
    float hn[CC];
    const float* xr = xin + (size_t)(p0 + lane)*CC;
    LD16(hn, xr); LD16((hn+16), xr+16); LD16((hn+32), xr+32); LD16((hn+48), xr+48);
    float s1=0.f, s2=0.f;
    #pragma unroll
    for(int c=0;c<CC;++c){ s1 += hn[c]; s2 += hn[c]*hn[c]; }
    const float mu = s1*(1.f/CC);
    const float rs = rsqrtf(s2*(1.f/CC) - mu*mu + EPSF);
    if(wv==0){
      #pragma unroll
      for(int q=0;q<8;++q){
        v8s s;
        #pragma unroll
        for(int e=0;e<8;++e){
          const int c = q*8+e;
          s[e] = bf16_((hn[c]-mu)*rs*n1w[c] + n1b[c]);
        }
        *(v8s*)&hlds[lane*72 + q*8] = s;
      }
    }
  }

  for(int h=0; h<2; ++h){
    if(h) __syncthreads();           // h=0 outs readers done before restage/rewrite
    // stage ipw rows [h*128, +128): thread -> row jl=t>>1, 32-col half
    {
      const int jl = t >> 1, hc = (t & 1)*32;
      const float* src = ipw + (size_t)(h*128 + jl)*64 + hc;
      #pragma unroll
      for(int q=0;q<4;++q){
        const float4 fa = ((const float4*)src)[q*2];
        const float4 fb = ((const float4*)src)[q*2+1];
        v8s s;
        s[0]=bf16_(fa.x); s[1]=bf16_(fa.y); s[2]=bf16_(fa.z); s[3]=bf16_(fa.w);
        s[4]=bf16_(fb.x); s[5]=bf16_(fb.y); s[6]=bf16_(fb.z); s[7]=bf16_(fb.w);
        *(v8s*)&w1lds[jl*72 + hc + q*8] = s;
      }
    }
    __syncthreads();
    // MFMA: wave wv owns pixel rows [wv*16,+16); nt spans the half's 128 j
    #pragma unroll 2
    for(int nt=0; nt<8; ++nt){
      v4f acc = (v4f){0.f,0.f,0.f,0.f};
      #pragma unroll
      for(int ks=0; ks<2; ++ks){
        const v8s a = *(const v8s*)&hlds[(wv*16 + m)*72 + ks*32 + quad*8];
        const v8s bb = *(const v8s*)&w1lds[(nt*16 + m)*72 + ks*32 + quad*8];
        acc = __builtin_amdgcn_mfma_f32_16x16x32_bf16(a, bb, acc, 0, 0, 0);
      }
      // C/D: col j = nt*16+m, rows px = wv*16+quad*4+r (4 consecutive px)
      *(float4*)&outs[(nt*16 + m)*68 + wv*16 + quad*4] =
          make_float4(acc[0], acc[1], acc[2], acc[3]);
    }
    __syncthreads();
    // store: thread -> j-row jl=t>>1, 32-px half
    const int jl = t >> 1, hc = (t & 1)*32;
    if(h==0){
      float* xcb = base + OFF_XCIN + (size_t)b*DI*LL + (size_t)jl*LL + l0 + hc;
      #pragma unroll
      for(int q=0;q<8;++q)
        ((float4*)xcb)[q] = *(const float4*)&outs[jl*68 + hc + q*4];
    } else {
      float* zr = base + OFF_Z + (size_t)jl*LB + p0 + hc;
      #pragma unroll
      for(int q=0;q<8;++q){
        const float4 v = *(const float4*)&outs[jl*68 + hc + q*4];
        ((float4*)zr)[q] = make_float4(silu_(v.x), silu_(v.y), silu_(v.z), silu_(v.w));
      }
    }
  }
}

// K2: depthwise 3x3 conv + silu; per (b,d) 64x64 tile via LDS; row-major + transposed out
__global__ __launch_bounds__(256) void k2_dwconv(
    const float* __restrict__ cw_, float* __restrict__ ws)
{
  const int i = blockIdx.y;
  const int bd = blockIdx.x;
  const int d = bd & (DI-1);
  const float* cw = cw_ + i*DI*9 + d*9;
  const float* xcin  = ws + (size_t)i*ISTRIDE + OFF_XCIN  + (size_t)bd*LL;
  float* xconv  = ws + (size_t)i*ISTRIDE + OFF_XCONV  + (size_t)bd*LL;
  float* xconvT = ws + (size_t)i*ISTRIDE + OFF_XCONVT + (size_t)bd*LL;
  __shared__ float tin[64*65];
  __shared__ float tout[64*65];
  const int t = threadIdx.x;
  float w9[9];
  #pragma unroll
  for(int q=0;q<9;++q) w9[q] = cw[q];
  for(int idx=t; idx<4096; idx+=256)
    tin[(idx>>6)*65 + (idx&63)] = xcin[idx];
  __syncthreads();
  const int w = t & 63, hb = (t>>6)*16;
  #pragma unroll
  for(int r=0;r<16;++r){
    const int h = hb + r;
    float acc = 0.f;
    #pragma unroll
    for(int dy=0;dy<3;++dy){
      const int hh = h + dy - 1;
      if(hh>=0 && hh<64){
        #pragma unroll
        for(int dx=0;dx<3;++dx){
          const int ww = w + dx - 1;
          if(ww>=0 && ww<64) acc += tin[hh*65+ww]*w9[dy*3+dx];
        }
      }
    }
    const float o = silu_(acc);
    tout[h*65+w] = o;
    xconv[h*64+w] = o;
  }
  __syncthreads();
  const int hcol = t & 63, wb = (t>>6)*16;
  #pragma unroll
  for(int r=0;r<16;++r){
    const int wp = wb + r;
    xconvT[wp*64 + hcol] = tout[hcol*65 + wp];
  }
}

// K3a: x_dbl = x_proj(xs) -> (dts[4], Bs, Cs) per (b,k,scan-pos)
__global__ __launch_bounds__(256) void k3a_xproj(
    const float* __restrict__ xpw_, float* __restrict__ ws)
{
  const int i = blockIdx.z;
  const int b = blockIdx.y >> 2;
  const int k = blockIdx.y & 3;
  const int l = blockIdx.x*256 + threadIdx.x;
  const float* src = ws + (size_t)i*ISTRIDE + ((k&1)? OFF_XCONVT : OFF_XCONV) + (size_t)b*DI*LL;
  const int ridx = (k>=2) ? (LL-1-l) : l;
  const float* xpw = xpw_ + i*KK*6*DI + k*6*DI;
  float acc[6] = {0,0,0,0,0,0};
  for(int d=0; d<DI; ++d){
    const float xv = src[(size_t)d*LL + ridx];
    #pragma unroll
    for(int c=0;c<6;++c) acc[c] += xv * xpw[c*DI + d];
  }
  float* xdbl = ws + (size_t)i*ISTRIDE + OFF_XDBL + (size_t)(b*KK+k)*6*LL;
  #pragma unroll
  for(int c=0;c<6;++c) xdbl[(size_t)c*LL + l] = acc[c];
}

// K3b v4: paired fwd/bwd scan. Each phase loads its 5 x_dbl rows into DISTINCT
// register arrays before consumption (5 concurrent HBM streams -> MLP), then
// wave shuffle scan + 1-barrier cross-wave exchange.
__global__ __launch_bounds__(256,3) void k3b_scan(
    const float* __restrict__ dtw_, const float* __restrict__ dtb_,
    const float* __restrict__ alog_, const float* __restrict__ Ds_,
    float* __restrict__ ws)
{
  const int gid = blockIdx.x;           // b*256 + kp*128 + d
  const int i = blockIdx.y;
  const int d  = gid & (DI-1);
  const int kp = (gid >> 7) & 1;
  const int b  = gid >> 8;
  const int t = threadIdx.x, lane = t & 63, wv = t >> 6;
  float* base = ws + (size_t)i*ISTRIDE;
  const float* src = base + (kp? OFF_XCONVT : OFF_XCONV) + (size_t)(b*DI+d)*LL;
  float*       dst = base + (kp? OFF_YT    : OFF_Y    ) + (size_t)(b*DI+d)*LL;
  const float* xdF = base + OFF_XDBL + (size_t)(b*KK+kp  )*6*LL;
  const float* xdB = base + OFF_XDBL + (size_t)(b*KK+kp+2)*6*LL;
  const int kdF = kp*DI + d, kdB = (kp+2)*DI + d;
  const float4 wF = ((const float4*)dtw_)[i*KK*DI + kdF];
  const float4 wB = ((const float4*)dtw_)[i*KK*DI + kdB];
  const float biasF = dtb_[i*KK*DI + kdF], biasB = dtb_[i*KK*DI + kdB];
  const float AvF = -fexp_(alog_[i*KK*DI + kdF]);
  const float AvB = -fexp_(alog_[i*KK*DI + kdB]);
  const float Dsum = Ds_[i*KK*DI + kdF] + Ds_[i*KK*DI + kdB];
  const int l0 = t*16;
  const int s0 = LL - 16 - l0;

  float vX[16], aF[16], bF[16], aB[16], bB[16];
  float fA = 1.f, fB = 0.f, gA = 1.f, gB = 0.f;
  LD16(vX, src + l0);

  { // fwd: 5 concurrent row streams
    float q0[16], q1[16], q2[16], q3[16], q4[16];
    LD16(q0, xdF + 0*LL + l0);
    LD16(q1, xdF + 1*LL + l0);
    LD16(q2, xdF + 2*LL + l0);
    LD16(q3, xdF + 3*LL + l0);
    LD16(q4, xdF + 4*LL + l0);   // Bs
    #pragma unroll
    for(int j=0;j<16;++j){
      const float pre = biasF + wF.x*q0[j] + wF.y*q1[j] + wF.z*q2[j] + wF.w*q3[j];
      const float delta = softplusf_(pre);
      aF[j] = fexp_(delta*AvF);
      bF[j] = delta*q4[j]*vX[j];
      fB = fB*aF[j] + bF[j];
      fA *= aF[j];
    }
  }
  { // bwd: 5 concurrent row streams (reversed)
    float q0[16], q1[16], q2[16], q3[16], q4[16];
    LD16R(q0, xdB + 0*LL + s0);
    LD16R(q1, xdB + 1*LL + s0);
    LD16R(q2, xdB + 2*LL + s0);
    LD16R(q3, xdB + 3*LL + s0);
    LD16R(q4, xdB + 4*LL + s0);  // Bs reversed
    #pragma unroll
    for(int j=15;j>=0;--j){
      const float pre = biasB + wB.x*q0[j] + wB.y*q1[j] + wB.z*q2[j] + wB.w*q3[j];
      const float delta = softplusf_(pre);
      aB[j] = fexp_(delta*AvB);
      bB[j] = delta*q4[j]*vX[j];
      gB = gB*aB[j] + bB[j];
      gA *= aB[j];
    }
  }

  #pragma unroll
  for(int off=1; off<64; off<<=1){
    const float aL = __shfl_up(fA, off);
    const float bL = __shfl_up(fB, off);
    if(lane >= off){ fB = bL*fA + fB; fA = aL*fA; }
  }
  float pA = __shfl_up(fA, 1), pB = __shfl_up(fB, 1);
  if(lane==0){ pA=1.f; pB=0.f; }
  #pragma unroll
  for(int off=1; off<64; off<<=1){
    const float aR = __shfl_down(gA, off);
    const float bR = __shfl_down(gB, off);
    if(lane + off < 64){ gB = gA*bR + gB; gA = gA*aR; }
  }
  float qA = __shfl_down(gA, 1), qB = __shfl_down(gB, 1);
  if(lane==63){ qA=1.f; qB=0.f; }

  __shared__ float wAg[4], wBg[4], vAg[4], vBg[4];
  if(lane==63){ wAg[wv]=fA; wBg[wv]=fB; }
  if(lane==0){ vAg[wv]=gA; vBg[wv]=gB; }
  __syncthreads();
  float eB=0.f;
  for(int u=0; u<wv; ++u){ eB = wAg[u]*eB + wBg[u]; }
  float rB=0.f;
  for(int u=3; u>wv; --u){ rB = vAg[u]*rB + vBg[u]; }

  float hf = pA*eB + pB;
  float hb = qA*rB + qB;

  float out[16], cc[16];
  LD16(cc, xdF + 5*LL + l0);
  #pragma unroll
  for(int j=0;j<16;++j){
    hf = aF[j]*hf + bF[j];
    out[j] = hf*cc[j] + Dsum*vX[j];
  }
  LD16R(cc, xdB + 5*LL + s0);
  #pragma unroll
  for(int j=15;j>=0;--j){
    hb = aB[j]*hb + bB[j];
    out[j] += hb*cc[j];
  }
  float4* d4 = (float4*)(dst + l0);
  d4[0] = make_float4(out[0],out[1],out[2],out[3]);
  d4[1] = make_float4(out[4],out[5],out[6],out[7]);
  d4[2] = make_float4(out[8],out[9],out[10],out[11]);
  d4[3] = make_float4(out[12],out[13],out[14],out[15]);
}

// K3c: combine y + transpose(yT) into d-major ycombT[d][b*LL+l].
__global__ __launch_bounds__(256) void k3c_combine(float* __restrict__ ws)
{
  const int i = blockIdx.y;
  const int b = blockIdx.x >> 4;
  const int tile = blockIdx.x & 15;
  const int h0 = (tile >> 2) * 16, w0 = (tile & 3) * 16;
  const int t = threadIdx.x;
  float* base = ws + (size_t)i*ISTRIDE;
  const float* y  = base + OFF_Y;
  const float* yT = base + OFF_YT;
  float* ycT = base + OFF_YCOMBT;
  __shared__ float ytile[16*16*16];
  __shared__ float ytT[16*16*17];
  const int r0 = t >> 4, c0 = t & 15;
  const int hi = t >> 4, wi = t & 15;
  const int l = (h0 + hi)*64 + (w0 + wi);
  for(int dc=0; dc<8; ++dc){
    #pragma unroll 4
    for(int dd=0; dd<16; ++dd){
      const int d = dc*16 + dd;
      const size_t rb = (size_t)(b*DI + d)*LL;
      ytile[dd*256 + t] = y[rb + (size_t)(h0 + r0)*64 + (w0 + c0)];
      ytT[dd*272 + r0*17 + c0] = yT[rb + (size_t)(w0 + r0)*64 + (h0 + c0)];
    }
    __syncthreads();
    #pragma unroll 4
    for(int dd=0; dd<16; ++dd){
      const int d = dc*16 + dd;
      ycT[(size_t)d*LB + b*LL + l] = ytile[dd*256 + t] + ytT[dd*272 + wi*17 + hi];
    }
    __syncthreads();
  }
}

// K4a v3 (MFMA): block = 64 pixels, 4 waves; LN via padded LDS stats; out_proj
// via mfma_f32_16x16x32_bf16; +xin -> xnew.
__global__ __launch_bounds__(256) void k4a_proj(
    const float* __restrict__ xmag, const float* __restrict__ xph,
    const float* __restrict__ onw_, const float* __restrict__ onb_,
    const float* __restrict__ opw_, float* __restrict__ ws)
{
  const int i = blockIdx.y;
  const float* xin = i ? xph : xmag;
  const float* onw = onw_ + i*DI;
  const float* onb = onb_ + i*DI;
  const float* opw = opw_ + i*CC*DI;     // [o][d] = [64][128]
  float* base = ws + (size_t)i*ISTRIDE;
  const float* ycT = base + OFF_YCOMBT;
  const float* zT  = base + OFF_Z;
  const int t = threadIdx.x, lane = t & 63;
  const int wv = __builtin_amdgcn_readfirstlane(t >> 6);
  const int m = lane & 15, quad = lane >> 4;
  const int p0 = blockIdx.x*64;
  const int p = p0 + lane;

  __shared__ short ynlds[64*136];
  __shared__ short wlds[64*136];
  __shared__ float st[64][9];

  float yv[32];
  float s1=0.f, s2=0.f;
  #pragma unroll 8
  for(int c=0;c<32;++c){
    const float v = ycT[(size_t)(wv*32+c)*LB + p];
    yv[c]=v; s1+=v; s2+=v*v;
  }
  st[lane][wv*2]=s1; st[lane][wv*2+1]=s2;
  __syncthreads();
  const float S1 = st[lane][0]+st[lane][2]+st[lane][4]+st[lane][6];
  const float S2 = st[lane][1]+st[lane][3]+st[lane][5]+st[lane][7];
  const float mu = S1*(1.f/DI);
  const float rs = rsqrtf(S2*(1.f/DI) - mu*mu + EPSF);
  #pragma unroll
  for(int cq=0;cq<8;++cq){
    short4 s4;
    #pragma unroll
    for(int e=0;e<4;++e){
      const int c = cq*4+e;
      const int d = wv*32 + c;
      ((short*)&s4)[e] = bf16_(((yv[c]-mu)*rs*onw[d] + onb[d]) * zT[(size_t)d*LB + p]);
    }
    *(short4*)&ynlds[lane*136 + wv*32 + cq*4] = s4;
  }
  {
    const int ol = t >> 2, seg = (t & 3)*32;
    const float* src = opw + (size_t)ol*DI + seg;
    #pragma unroll
    for(int q=0;q<4;++q){
      const float4 fa = ((const float4*)src)[q*2];
      const float4 fb = ((const float4*)src)[q*2+1];
      v8s s;
      s[0]=bf16_(fa.x); s[1]=bf16_(fa.y); s[2]=bf16_(fa.z); s[3]=bf16_(fa.w);
      s[4]=bf16_(fb.x); s[5]=bf16_(fb.y); s[6]=bf16_(fb.z); s[7]=bf16_(fb.w);
      *(v8s*)&wlds[ol*136 + seg + q*8] = s;
    }
  }
  __syncthreads();

  v4f accs[4];
  #pragma unroll
  for(int nt=0; nt<4; ++nt){
    v4f acc = (v4f){0.f,0.f,0.f,0.f};
    #pragma unroll
    for(int ks=0; ks<4; ++ks){
      const v8s a = *(const v8s*)&ynlds[(wv*16 + m)*136 + ks*32 + quad*8];
      const v8s b = *(const v8s*)&wlds[(nt*16 + m)*136 + ks*32 + quad*8];
      acc = __builtin_amdgcn_mfma_f32_16x16x32_bf16(a, b, acc, 0, 0, 0);
    }
    accs[nt] = acc;
  }
  float* xnew = base + OFF_XNEW;
  #pragma unroll
  for(int nt=0; nt<4; ++nt){
    #pragma unroll
    for(int r=0;r<4;++r){
      const int pp = p0 + wv*16 + quad*4 + r;
      const int o = nt*16 + m;
      xnew[(size_t)pp*CC + o] = accs[nt][r] + xin[(size_t)pp*CC + o];
    }
  }
}

// K4b v7 (MFMA): 64-pixel tile per block, 4 waves. LN (fp32) -> bf16 H in LDS;
// per 128-j half: stage F1/F2 bf16, fc1 mfma 16x16x32, GELU, fc2 mfma.
__global__ __launch_bounds__(256) void k4b_mlp(
    const float* __restrict__ n2w_, const float* __restrict__ n2b_,
    const float* __restrict__ f1w_, const float* __restrict__ f1b_,
    const float* __restrict__ f2w_, const float* __restrict__ f2b_,
    float* __restrict__ ws)
{
  const int i = blockIdx.y;
  const float* n2w = n2w_ + i*CC;
  const float* n2b = n2b_ + i*CC;
  const float* f1w = f1w_ + i*256*64;    // [j][c]
  const float* f1b = f1b_ + i*256;
  const float* f2w = f2w_ + i*64*256;    // [o][j]
  const float* f2b = f2b_ + i*CC;
  float* base = ws + (size_t)i*ISTRIDE;
  const float* xnew = base + OFF_XNEW;
  const int t = threadIdx.x, lane = t & 63;
  const int wv = __builtin_amdgcn_readfirstlane(t >> 6);
  const int m = lane & 15, quad = lane >> 4;
  const int p0 = blockIdx.x*64;

  __shared__ short hlds[64*72];
  __shared__ short w1lds[128*72];
  __shared__ short glds[64*136];
  __shared__ short w2lds[64*136];

  {
    float h2[64];
    const float* xr = xnew + (size_t)(p0 + lane)*CC;
    LD16(h2, xr); LD16((h2+16), xr+16); LD16((h2+32), xr+32); LD16((h2+48), xr+48);
    float s1=0.f, s2=0.f;
    #pragma unroll
    for(int c=0;c<CC;++c){ s1 += h2[c]; s2 += h2[c]*h2[c]; }
    const float mu = s1*(1.f/CC);
    const float rs = rsqrtf(s2*(1.f/CC) - mu*mu + EPSF);
    if(wv==0){
      #pragma unroll
      for(int q=0;q<8;++q){
        v8s s;
        #pragma unroll
        for(int e=0;e<8;++e){
          const int c = q*8+e;
          s[e] = bf16_((h2[c]-mu)*rs*n2w[c] + n2b[c]);
        }
        *(v8s*)&hlds[lane*72 + q*8] = s;
      }
    }
  }

  v4f acc2[4];
  #pragma unroll
  for(int n=0;n<4;++n) acc2[n] = (v4f){0.f,0.f,0.f,0.f};

  for(int h=0; h<2; ++h){
    if(h) __syncthreads();
    {
      const int jl = t >> 1, hc = (t & 1)*32;
      const float* src = f1w + (size_t)(h*128 + jl)*64 + hc;
      #pragma unroll
      for(int q=0;q<4;++q){
        const float4 fa = ((const float4*)src)[q*2];
        const float4 fb = ((const float4*)src)[q*2+1];
        v8s s;
        s[0]=bf16_(fa.x); s[1]=bf16_(fa.y); s[2]=bf16_(fa.z); s[3]=bf16_(fa.w);
        s[4]=bf16_(fb.x); s[5]=bf16_(fb.y); s[6]=bf16_(fb.z); s[7]=bf16_(fb.w);
        *(v8s*)&w1lds[jl*72 + hc + q*8] = s;
      }
    }
    {
      const int ol = t >> 2, seg = (t & 3)*32;
      const float* src = f2w + (size_t)ol*256 + h*128 + seg;
      #pragma unroll
      for(int q=0;q<4;++q){
        const float4 fa = ((const float4*)src)[q*2];
        const float4 fb = ((const float4*)src)[q*2+1];
        v8s s;
        s[0]=bf16_(fa.x); s[1]=bf16_(fa.y); s[2]=bf16_(fa.z); s[3]=bf16_(fa.w);
        s[4]=bf16_(fb.x); s[5]=bf16_(fb.y); s[6]=bf16_(fb.z); s[7]=bf16_(fb.w);
        *(v8s*)&w2lds[ol*136 + seg + q*8] = s;
      }
    }
    __syncthreads();
    #pragma unroll 2
    for(int nt=0; nt<8; ++nt){
      v4f acc = (v4f){0.f,0.f,0.f,0.f};
      #pragma unroll
      for(int ks=0; ks<2; ++ks){
        const v8s a = *(const v8s*)&hlds[(wv*16 + m)*72 + ks*32 + quad*8];
        const v8s b = *(const v8s*)&w1lds[(nt*16 + m)*72 + ks*32 + quad*8];
        acc = __builtin_amdgcn_mfma_f32_16x16x32_bf16(a, b, acc, 0, 0, 0);
      }
      const float bj = f1b[h*128 + nt*16 + m];
      #pragma unroll
      for(int r=0;r<4;++r){
        glds[(wv*16 + quad*4 + r)*136 + nt*16 + m] = bf16_(geluf_(acc[r] + bj));
      }
    }
    #pragma unroll
    for(int nt=0; nt<4; ++nt){
      v4f acc = acc2[nt];
      #pragma unroll
      for(int ks=0; ks<4; ++ks){
        const v8s a = *(const v8s*)&glds[(wv*16 + m)*136 + ks*32 + quad*8];
        const v8s b = *(const v8s*)&w2lds[(nt*16 + m)*136 + ks*32 + quad*8];
        acc = __builtin_amdgcn_mfma_f32_16x16x32_bf16(a, b, acc, 0, 0, 0);
      }
      acc2[nt] = acc;
    }
  }

  float* sb = base + OFF_SB;
  #pragma unroll
  for(int nt=0; nt<4; ++nt){
    const float bo = f2b[nt*16 + m];
    #pragma unroll
    for(int r=0;r<4;++r){
      const int p = p0 + wv*16 + quad*4 + r;
      const int o = nt*16 + m;
      sb[(size_t)p*CC + o] = acc2[nt][r] + bo + xnew[(size_t)p*CC + o];
    }
  }
}

// K5: s = inst0 + inst1; write to both output halves
__global__ __launch_bounds__(256) void k5_final(
    const float* __restrict__ ws, float* __restrict__ out)
{
  const int idx = blockIdx.x*256 + threadIdx.x;
  const float v = ws[OFF_SB + idx] + ws[ISTRIDE + OFF_SB + idx];
  out[idx] = v;
  out[NPIX + idx] = v;
}

extern "C" void kernel_launch(void* const* d_in, const int* in_sizes, int n_in,
                              void* d_out, int out_size, void* d_ws, size_t ws_size,
                              hipStream_t stream)
{
  const float* mag  = (const float*)d_in[0];
  const float* ph   = (const float*)d_in[1];
  const float* n1w  = (const float*)d_in[2];
  const float* n1b  = (const float*)d_in[3];
  const float* ipw  = (const float*)d_in[4];
  const float* cw   = (const float*)d_in[5];
  const float* xpw  = (const float*)d_in[6];
  const float* dtw  = (const float*)d_in[7];
  const float* dtb  = (const float*)d_in[8];
  const float* alog = (const float*)d_in[9];
  const float* Ds   = (const float*)d_in[10];
  const float* onw  = (const float*)d_in[11];
  const float* onb  = (const float*)d_in[12];
  const float* opw  = (const float*)d_in[13];
  const float* n2w  = (const float*)d_in[14];
  const float* n2b  = (const float*)d_in[15];
  const float* f1w  = (const float*)d_in[16];
  const float* f1b  = (const float*)d_in[17];
  const float* f2w  = (const float*)d_in[18];
  const float* f2b  = (const float*)d_in[19];
  float* ws = (float*)d_ws;
  float* out = (float*)d_out;

  k1_ln_inproj<<<dim3(512,2),  256, 0, stream>>>(mag, ph, n1w, n1b, ipw, ws);
  k2_dwconv   <<<dim3(1024,2), 256, 0, stream>>>(cw, ws);
  k3a_xproj   <<<dim3(16,32,2),256, 0, stream>>>(xpw, ws);
  k3b_scan    <<<dim3(2048,2), 256, 0, stream>>>(dtw, dtb, alog, Ds, ws);
  k3c_combine <<<dim3(128,2),  256, 0, stream>>>(ws);
  k4a_proj    <<<dim3(512,2),  256, 0, stream>>>(mag, ph, onw, onb, opw, ws);
  k4b_mlp     <<<dim3(512,2),  256, 0, stream>>>(n2w, n2b, f1w, f1b, f2w, f2b, ws);
  k5_final    <<<dim3(8192),   256, 0, stream>>>(ws, out);
}

// Round 15
// 362.671 us; speedup vs baseline: 2.4612x; 1.0053x over previous
//
#include <hip/hip_runtime.h>
#include <math.h>

// Problem constants
#define LL   4096      // H*W
#define DI   128       // 2*C
#define CC   64        // C
#define BB   8         // batch
#define KK   4         // scan directions
#define LB   32768     // pixels per instance
#define NPIX 2097152   // B*H*W*C elements of s
#define EPSF 1e-5f

// Workspace layout (floats, per instance)
#define OFF_XCIN   ((size_t)0)
#define OFF_XCONV  ((size_t)4194304)
#define OFF_XCONVT ((size_t)8388608)
#define OFF_Z      ((size_t)12582912)
#define OFF_Y      ((size_t)16777216)
#define OFF_YT     ((size_t)20971520)
#define OFF_XDBL   ((size_t)25165824)
#define ISTRIDE    ((size_t)25952256)   // floats per instance
// Aliases (lifetime-disjoint reuse):
#define OFF_YCOMBT OFF_XCIN             // xcin dead after k2; ycombT (d-major) by k3c
#define OFF_XNEW   OFF_YT               // yT dead after k3c; xnew (pixel-major) by k4a
#define OFF_SB     OFF_Y                // y dead after k3c; sbuf by k4b

typedef short v8s __attribute__((ext_vector_type(8)));
typedef float v4f __attribute__((ext_vector_type(4)));

// Fast transcendentals: native v_exp/v_log paths (error ~1e-7, threshold 0.144)
__device__ __forceinline__ float fexp_(float x){ return __expf(x); }
__device__ __forceinline__ float silu_(float x){ return __fdividef(x, 1.f+__expf(-x)); }
__device__ __forceinline__ float softplusf_(float x){
  return fmaxf(x,0.f) + __logf(1.f + __expf(-fabsf(x)));
}
__device__ __forceinline__ float geluf_(float x){ return 0.5f*x*(1.f+erff(x*0.70710678118f)); }
__device__ __forceinline__ short bf16_(float x){
  unsigned u = __float_as_uint(x);
  u += 0x7FFF + ((u>>16)&1);     // RNE
  return (short)(u>>16);
}

#define LD16(dst, ptr) { const float4* p4_=(const float4*)(ptr);                 \
  float4 v0_=p4_[0], v1_=p4_[1], v2_=p4_[2], v3_=p4_[3];                         \
  dst[0]=v0_.x; dst[1]=v0_.y; dst[2]=v0_.z; dst[3]=v0_.w;                        \
  dst[4]=v1_.x; dst[5]=v1_.y; dst[6]=v1_.z; dst[7]=v1_.w;                        \
  dst[8]=v2_.x; dst[9]=v2_.y; dst[10]=v2_.z; dst[11]=v2_.w;                      \
  dst[12]=v3_.x; dst[13]=v3_.y; dst[14]=v3_.z; dst[15]=v3_.w; }
#define LD16R(dst, ptr) { const float4* p4_=(const float4*)(ptr);                \
  float4 v0_=p4_[0], v1_=p4_[1], v2_=p4_[2], v3_=p4_[3];                         \
  dst[15]=v0_.x; dst[14]=v0_.y; dst[13]=v0_.z; dst[12]=v0_.w;                    \
  dst[11]=v1_.x; dst[10]=v1_.y; dst[9]=v1_.z;  dst[8]=v1_.w;                     \
  dst[7]=v2_.x;  dst[6]=v2_.y;  dst[5]=v2_.z;  dst[4]=v2_.w;                     \
  dst[3]=v3_.x;  dst[2]=v3_.y;  dst[1]=v3_.z;  dst[0]=v3_.w; }

// K1 v5 (MFMA): block = 64 pixels, 4 waves. LN (fp32) -> bf16 hlds; per 128-row
// half of ipw: stage w1lds, 8 n-tiles x 2 k-steps mfma, outs -> coalesced stores.
__global__ __launch_bounds__(256) void k1_ln_inproj(
    const float* __restrict__ xmag, const float* __restrict__ xph,
    const float* __restrict__ n1w_, const float* __restrict__ n1b_,
    const float* __restrict__ ipw_, float* __restrict__ ws)
{
  const int i = blockIdx.y;
  const float* xin = i ? xph : xmag;
  const float* n1w = n1w_ + i*CC;
  const float* n1b = n1b_ + i*CC;
  const float* ipw = ipw_ + i*2*DI*CC;   // [256][64]
  float* base = ws + (size_t)i*ISTRIDE;
  const int t = threadIdx.x, lane = t & 63;
  const int wv = __builtin_amdgcn_readfirstlane(t >> 6);
  const int m = lane & 15, quad = lane >> 4;
  const int p0 = blockIdx.x*64;
  const int b = p0 >> 12, l0 = p0 & (LL-1);

  __shared__ short hlds[64*72];
  __shared__ short w1lds[128*72];
  __shared__ float outs[128*68];

  {
    float hn[CC];
    const float* xr = xin + (size_t)(p0 + lane)*CC;
    LD16(hn, xr); LD16((hn+16), xr+16); LD16((hn+32), xr+32); LD16((hn+48), xr+48);
    float s1=0.f, s2=0.f;
    #pragma unroll
    for(int c=0;c<CC;++c){ s1 += hn[c]; s2 += hn[c]*hn[c]; }
    const float mu = s1*(1.f/CC);
    const float rs = rsqrtf(s2*(1.f/CC) - mu*mu + EPSF);
    if(wv==0){
      #pragma unroll
      for(int q=0;q<8;++q){
        v8s s;
        #pragma unroll
        for(int e=0;e<8;++e){
          const int c = q*8+e;
          s[e] = bf16_((hn[c]-mu)*rs*n1w[c] + n1b[c]);
        }
        *(v8s*)&hlds[lane*72 + q*8] = s;
      }
    }
  }

  for(int h=0; h<2; ++h){
    if(h) __syncthreads();
    {
      const int jl = t >> 1, hc = (t & 1)*32;
      const float* src = ipw + (size_t)(h*128 + jl)*64 + hc;
      #pragma unroll
      for(int q=0;q<4;++q){
        const float4 fa = ((const float4*)src)[q*2];
        const float4 fb = ((const float4*)src)[q*2+1];
        v8s s;
        s[0]=bf16_(fa.x); s[1]=bf16_(fa.y); s[2]=bf16_(fa.z); s[3]=bf16_(fa.w);
        s[4]=bf16_(fb.x); s[5]=bf16_(fb.y); s[6]=bf16_(fb.z); s[7]=bf16_(fb.w);
        *(v8s*)&w1lds[jl*72 + hc + q*8] = s;
      }
    }
    __syncthreads();
    #pragma unroll 2
    for(int nt=0; nt<8; ++nt){
      v4f acc = (v4f){0.f,0.f,0.f,0.f};
      #pragma unroll
      for(int ks=0; ks<2; ++ks){
        const v8s a = *(const v8s*)&hlds[(wv*16 + m)*72 + ks*32 + quad*8];
        const v8s bb = *(const v8s*)&w1lds[(nt*16 + m)*72 + ks*32 + quad*8];
        acc = __builtin_amdgcn_mfma_f32_16x16x32_bf16(a, bb, acc, 0, 0, 0);
      }
      *(float4*)&outs[(nt*16 + m)*68 + wv*16 + quad*4] =
          make_float4(acc[0], acc[1], acc[2], acc[3]);
    }
    __syncthreads();
    const int jl = t >> 1, hc = (t & 1)*32;
    if(h==0){
      float* xcb = base + OFF_XCIN + (size_t)b*DI*LL + (size_t)jl*LL + l0 + hc;
      #pragma unroll
      for(int q=0;q<8;++q)
        ((float4*)xcb)[q] = *(const float4*)&outs[jl*68 + hc + q*4];
    } else {
      float* zr = base + OFF_Z + (size_t)jl*LB + p0 + hc;
      #pragma unroll
      for(int q=0;q<8;++q){
        const float4 v = *(const float4*)&outs[jl*68 + hc + q*4];
        ((float4*)zr)[q] = make_float4(silu_(v.x), silu_(v.y), silu_(v.z), silu_(v.w));
      }
    }
  }
}

// K2: depthwise 3x3 conv + silu; per (b,d) 64x64 tile via LDS; row-major + transposed out
__global__ __launch_bounds__(256) void k2_dwconv(
    const float* __restrict__ cw_, float* __restrict__ ws)
{
  const int i = blockIdx.y;
  const int bd = blockIdx.x;
  const int d = bd & (DI-1);
  const float* cw = cw_ + i*DI*9 + d*9;
  const float* xcin  = ws + (size_t)i*ISTRIDE + OFF_XCIN  + (size_t)bd*LL;
  float* xconv  = ws + (size_t)i*ISTRIDE + OFF_XCONV  + (size_t)bd*LL;
  float* xconvT = ws + (size_t)i*ISTRIDE + OFF_XCONVT + (size_t)bd*LL;
  __shared__ float tin[64*65];
  __shared__ float tout[64*65];
  const int t = threadIdx.x;
  float w9[9];
  #pragma unroll
  for(int q=0;q<9;++q) w9[q] = cw[q];
  for(int idx=t; idx<4096; idx+=256)
    tin[(idx>>6)*65 + (idx&63)] = xcin[idx];
  __syncthreads();
  const int w = t & 63, hb = (t>>6)*16;
  #pragma unroll
  for(int r=0;r<16;++r){
    const int h = hb + r;
    float acc = 0.f;
    #pragma unroll
    for(int dy=0;dy<3;++dy){
      const int hh = h + dy - 1;
      if(hh>=0 && hh<64){
        #pragma unroll
        for(int dx=0;dx<3;++dx){
          const int ww = w + dx - 1;
          if(ww>=0 && ww<64) acc += tin[hh*65+ww]*w9[dy*3+dx];
        }
      }
    }
    const float o = silu_(acc);
    tout[h*65+w] = o;
    xconv[h*64+w] = o;
  }
  __syncthreads();
  const int hcol = t & 63, wb = (t>>6)*16;
  #pragma unroll
  for(int r=0;r<16;++r){
    const int wp = wb + r;
    xconvT[wp*64 + hcol] = tout[hcol*65 + wp];
  }
}

// K3a: x_dbl = x_proj(xs) -> (dts[4], Bs, Cs) per (b,k,scan-pos)
__global__ __launch_bounds__(256) void k3a_xproj(
    const float* __restrict__ xpw_, float* __restrict__ ws)
{
  const int i = blockIdx.z;
  const int b = blockIdx.y >> 2;
  const int k = blockIdx.y & 3;
  const int l = blockIdx.x*256 + threadIdx.x;
  const float* src = ws + (size_t)i*ISTRIDE + ((k&1)? OFF_XCONVT : OFF_XCONV) + (size_t)b*DI*LL;
  const int ridx = (k>=2) ? (LL-1-l) : l;
  const float* xpw = xpw_ + i*KK*6*DI + k*6*DI;
  float acc[6] = {0,0,0,0,0,0};
  for(int d=0; d<DI; ++d){
    const float xv = src[(size_t)d*LL + ridx];
    #pragma unroll
    for(int c=0;c<6;++c) acc[c] += xv * xpw[c*DI + d];
  }
  float* xdbl = ws + (size_t)i*ISTRIDE + OFF_XDBL + (size_t)(b*KK+k)*6*LL;
  #pragma unroll
  for(int c=0;c<6;++c) xdbl[(size_t)c*LL + l] = acc[c];
}

// K3b (round-13 body, occupancy knob): paired fwd/bwd scan; wave shuffle scan,
// 1 barrier. launch_bounds(256,4) -> <=64 VGPR, min 4 waves/SIMD.
__global__ __launch_bounds__(256,4) void k3b_scan(
    const float* __restrict__ dtw_, const float* __restrict__ dtb_,
    const float* __restrict__ alog_, const float* __restrict__ Ds_,
    float* __restrict__ ws)
{
  const int gid = blockIdx.x;           // b*256 + kp*128 + d
  const int i = blockIdx.y;
  const int d  = gid & (DI-1);
  const int kp = (gid >> 7) & 1;
  const int b  = gid >> 8;
  const int t = threadIdx.x, lane = t & 63, wv = t >> 6;
  float* base = ws + (size_t)i*ISTRIDE;
  const float* src = base + (kp? OFF_XCONVT : OFF_XCONV) + (size_t)(b*DI+d)*LL;
  float*       dst = base + (kp? OFF_YT    : OFF_Y    ) + (size_t)(b*DI+d)*LL;
  const float* xdF = base + OFF_XDBL + (size_t)(b*KK+kp  )*6*LL;
  const float* xdB = base + OFF_XDBL + (size_t)(b*KK+kp+2)*6*LL;
  const int kdF = kp*DI + d, kdB = (kp+2)*DI + d;
  const float4 wF = ((const float4*)dtw_)[i*KK*DI + kdF];
  const float4 wB = ((const float4*)dtw_)[i*KK*DI + kdB];
  const float biasF = dtb_[i*KK*DI + kdF], biasB = dtb_[i*KK*DI + kdB];
  const float AvF = -fexp_(alog_[i*KK*DI + kdF]);
  const float AvB = -fexp_(alog_[i*KK*DI + kdB]);
  const float Dsum = Ds_[i*KK*DI + kdF] + Ds_[i*KK*DI + kdB];
  const int l0 = t*16;
  const int s0 = LL - 16 - l0;

  float vX[16], aF[16], bF[16], aB[16], bB[16];
  float fA = 1.f, fB = 0.f, gA = 1.f, gB = 0.f;
  LD16(vX, src + l0);

  {
    float pre[16], r0[16];
    LD16(r0, xdF + 0*LL + l0);
    #pragma unroll
    for(int j=0;j<16;++j) pre[j] = biasF + wF.x*r0[j];
    LD16(r0, xdF + 1*LL + l0);
    #pragma unroll
    for(int j=0;j<16;++j) pre[j] += wF.y*r0[j];
    LD16(r0, xdF + 2*LL + l0);
    #pragma unroll
    for(int j=0;j<16;++j) pre[j] += wF.z*r0[j];
    LD16(r0, xdF + 3*LL + l0);
    #pragma unroll
    for(int j=0;j<16;++j) pre[j] += wF.w*r0[j];
    LD16(r0, xdF + 4*LL + l0);   // Bs
    #pragma unroll
    for(int j=0;j<16;++j){
      const float delta = softplusf_(pre[j]);
      aF[j] = fexp_(delta*AvF);
      bF[j] = delta*r0[j]*vX[j];
      fB = fB*aF[j] + bF[j];
      fA *= aF[j];
    }
  }
  {
    float pre[16], r0[16];
    LD16R(r0, xdB + 0*LL + s0);
    #pragma unroll
    for(int j=0;j<16;++j) pre[j] = biasB + wB.x*r0[j];
    LD16R(r0, xdB + 1*LL + s0);
    #pragma unroll
    for(int j=0;j<16;++j) pre[j] += wB.y*r0[j];
    LD16R(r0, xdB + 2*LL + s0);
    #pragma unroll
    for(int j=0;j<16;++j) pre[j] += wB.z*r0[j];
    LD16R(r0, xdB + 3*LL + s0);
    #pragma unroll
    for(int j=0;j<16;++j) pre[j] += wB.w*r0[j];
    LD16R(r0, xdB + 4*LL + s0);  // Bs reversed
    #pragma unroll
    for(int j=15;j>=0;--j){
      const float delta = softplusf_(pre[j]);
      aB[j] = fexp_(delta*AvB);
      bB[j] = delta*r0[j]*vX[j];
      gB = gB*aB[j] + bB[j];
      gA *= aB[j];
    }
  }

  #pragma unroll
  for(int off=1; off<64; off<<=1){
    const float aL = __shfl_up(fA, off);
    const float bL = __shfl_up(fB, off);
    if(lane >= off){ fB = bL*fA + fB; fA = aL*fA; }
  }
  float pA = __shfl_up(fA, 1), pB = __shfl_up(fB, 1);
  if(lane==0){ pA=1.f; pB=0.f; }
  #pragma unroll
  for(int off=1; off<64; off<<=1){
    const float aR = __shfl_down(gA, off);
    const float bR = __shfl_down(gB, off);
    if(lane + off < 64){ gB = gA*bR + gB; gA = gA*aR; }
  }
  float qA = __shfl_down(gA, 1), qB = __shfl_down(gB, 1);
  if(lane==63){ qA=1.f; qB=0.f; }

  __shared__ float wAg[4], wBg[4], vAg[4], vBg[4];
  if(lane==63){ wAg[wv]=fA; wBg[wv]=fB; }
  if(lane==0){ vAg[wv]=gA; vBg[wv]=gB; }
  __syncthreads();
  float eB=0.f;
  for(int u=0; u<wv; ++u){ eB = wAg[u]*eB + wBg[u]; }
  float rB=0.f;
  for(int u=3; u>wv; --u){ rB = vAg[u]*rB + vBg[u]; }

  float hf = pA*eB + pB;
  float hb = qA*rB + qB;

  float out[16], cc[16];
  LD16(cc, xdF + 5*LL + l0);
  #pragma unroll
  for(int j=0;j<16;++j){
    hf = aF[j]*hf + bF[j];
    out[j] = hf*cc[j] + Dsum*vX[j];
  }
  LD16R(cc, xdB + 5*LL + s0);
  #pragma unroll
  for(int j=15;j>=0;--j){
    hb = aB[j]*hb + bB[j];
    out[j] += hb*cc[j];
  }
  float4* d4 = (float4*)(dst + l0);
  d4[0] = make_float4(out[0],out[1],out[2],out[3]);
  d4[1] = make_float4(out[4],out[5],out[6],out[7]);
  d4[2] = make_float4(out[8],out[9],out[10],out[11]);
  d4[3] = make_float4(out[12],out[13],out[14],out[15]);
}

// K3c: combine y + transpose(yT) into d-major ycombT[d][b*LL+l].
__global__ __launch_bounds__(256) void k3c_combine(float* __restrict__ ws)
{
  const int i = blockIdx.y;
  const int b = blockIdx.x >> 4;
  const int tile = blockIdx.x & 15;
  const int h0 = (tile >> 2) * 16, w0 = (tile & 3) * 16;
  const int t = threadIdx.x;
  float* base = ws + (size_t)i*ISTRIDE;
  const float* y  = base + OFF_Y;
  const float* yT = base + OFF_YT;
  float* ycT = base + OFF_YCOMBT;
  __shared__ float ytile[16*16*16];
  __shared__ float ytT[16*16*17];
  const int r0 = t >> 4, c0 = t & 15;
  const int hi = t >> 4, wi = t & 15;
  const int l = (h0 + hi)*64 + (w0 + wi);
  for(int dc=0; dc<8; ++dc){
    #pragma unroll 4
    for(int dd=0; dd<16; ++dd){
      const int d = dc*16 + dd;
      const size_t rb = (size_t)(b*DI + d)*LL;
      ytile[dd*256 + t] = y[rb + (size_t)(h0 + r0)*64 + (w0 + c0)];
      ytT[dd*272 + r0*17 + c0] = yT[rb + (size_t)(w0 + r0)*64 + (h0 + c0)];
    }
    __syncthreads();
    #pragma unroll 4
    for(int dd=0; dd<16; ++dd){
      const int d = dc*16 + dd;
      ycT[(size_t)d*LB + b*LL + l] = ytile[dd*256 + t] + ytT[dd*272 + wi*17 + hi];
    }
    __syncthreads();
  }
}

// K4a v3 (MFMA): block = 64 pixels, 4 waves; LN via padded LDS stats; out_proj
// via mfma_f32_16x16x32_bf16; +xin -> xnew.
__global__ __launch_bounds__(256) void k4a_proj(
    const float* __restrict__ xmag, const float* __restrict__ xph,
    const float* __restrict__ onw_, const float* __restrict__ onb_,
    const float* __restrict__ opw_, float* __restrict__ ws)
{
  const int i = blockIdx.y;
  const float* xin = i ? xph : xmag;
  const float* onw = onw_ + i*DI;
  const float* onb = onb_ + i*DI;
  const float* opw = opw_ + i*CC*DI;     // [o][d] = [64][128]
  float* base = ws + (size_t)i*ISTRIDE;
  const float* ycT = base + OFF_YCOMBT;
  const float* zT  = base + OFF_Z;
  const int t = threadIdx.x, lane = t & 63;
  const int wv = __builtin_amdgcn_readfirstlane(t >> 6);
  const int m = lane & 15, quad = lane >> 4;
  const int p0 = blockIdx.x*64;
  const int p = p0 + lane;

  __shared__ short ynlds[64*136];
  __shared__ short wlds[64*136];
  __shared__ float st[64][9];

  float yv[32];
  float s1=0.f, s2=0.f;
  #pragma unroll 8
  for(int c=0;c<32;++c){
    const float v = ycT[(size_t)(wv*32+c)*LB + p];
    yv[c]=v; s1+=v; s2+=v*v;
  }
  st[lane][wv*2]=s1; st[lane][wv*2+1]=s2;
  __syncthreads();
  const float S1 = st[lane][0]+st[lane][2]+st[lane][4]+st[lane][6];
  const float S2 = st[lane][1]+st[lane][3]+st[lane][5]+st[lane][7];
  const float mu = S1*(1.f/DI);
  const float rs = rsqrtf(S2*(1.f/DI) - mu*mu + EPSF);
  #pragma unroll
  for(int cq=0;cq<8;++cq){
    short4 s4;
    #pragma unroll
    for(int e=0;e<4;++e){
      const int c = cq*4+e;
      const int d = wv*32 + c;
      ((short*)&s4)[e] = bf16_(((yv[c]-mu)*rs*onw[d] + onb[d]) * zT[(size_t)d*LB + p]);
    }
    *(short4*)&ynlds[lane*136 + wv*32 + cq*4] = s4;
  }
  {
    const int ol = t >> 2, seg = (t & 3)*32;
    const float* src = opw + (size_t)ol*DI + seg;
    #pragma unroll
    for(int q=0;q<4;++q){
      const float4 fa = ((const float4*)src)[q*2];
      const float4 fb = ((const float4*)src)[q*2+1];
      v8s s;
      s[0]=bf16_(fa.x); s[1]=bf16_(fa.y); s[2]=bf16_(fa.z); s[3]=bf16_(fa.w);
      s[4]=bf16_(fb.x); s[5]=bf16_(fb.y); s[6]=bf16_(fb.z); s[7]=bf16_(fb.w);
      *(v8s*)&wlds[ol*136 + seg + q*8] = s;
    }
  }
  __syncthreads();

  v4f accs[4];
  #pragma unroll
  for(int nt=0; nt<4; ++nt){
    v4f acc = (v4f){0.f,0.f,0.f,0.f};
    #pragma unroll
    for(int ks=0; ks<4; ++ks){
      const v8s a = *(const v8s*)&ynlds[(wv*16 + m)*136 + ks*32 + quad*8];
      const v8s b = *(const v8s*)&wlds[(nt*16 + m)*136 + ks*32 + quad*8];
      acc = __builtin_amdgcn_mfma_f32_16x16x32_bf16(a, b, acc, 0, 0, 0);
    }
    accs[nt] = acc;
  }
  float* xnew = base + OFF_XNEW;
  #pragma unroll
  for(int nt=0; nt<4; ++nt){
    #pragma unroll
    for(int r=0;r<4;++r){
      const int pp = p0 + wv*16 + quad*4 + r;
      const int o = nt*16 + m;
      xnew[(size_t)pp*CC + o] = accs[nt][r] + xin[(size_t)pp*CC + o];
    }
  }
}

// K4b v7 (MFMA): 64-pixel tile per block, 4 waves. LN (fp32) -> bf16 H in LDS;
// per 128-j half: stage F1/F2 bf16, fc1 mfma 16x16x32, GELU, fc2 mfma.
__global__ __launch_bounds__(256) void k4b_mlp(
    const float* __restrict__ n2w_, const float* __restrict__ n2b_,
    const float* __restrict__ f1w_, const float* __restrict__ f1b_,
    const float* __restrict__ f2w_, const float* __restrict__ f2b_,
    float* __restrict__ ws)
{
  const int i = blockIdx.y;
  const float* n2w = n2w_ + i*CC;
  const float* n2b = n2b_ + i*CC;
  const float* f1w = f1w_ + i*256*64;    // [j][c]
  const float* f1b = f1b_ + i*256;
  const float* f2w = f2w_ + i*64*256;    // [o][j]
  const float* f2b = f2b_ + i*CC;
  float* base = ws + (size_t)i*ISTRIDE;
  const float* xnew = base + OFF_XNEW;
  const int t = threadIdx.x, lane = t & 63;
  const int wv = __builtin_amdgcn_readfirstlane(t >> 6);
  const int m = lane & 15, quad = lane >> 4;
  const int p0 = blockIdx.x*64;

  __shared__ short hlds[64*72];
  __shared__ short w1lds[128*72];
  __shared__ short glds[64*136];
  __shared__ short w2lds[64*136];

  {
    float h2[64];
    const float* xr = xnew + (size_t)(p0 + lane)*CC;
    LD16(h2, xr); LD16((h2+16), xr+16); LD16((h2+32), xr+32); LD16((h2+48), xr+48);
    float s1=0.f, s2=0.f;
    #pragma unroll
    for(int c=0;c<CC;++c){ s1 += h2[c]; s2 += h2[c]*h2[c]; }
    const float mu = s1*(1.f/CC);
    const float rs = rsqrtf(s2*(1.f/CC) - mu*mu + EPSF);
    if(wv==0){
      #pragma unroll
      for(int q=0;q<8;++q){
        v8s s;
        #pragma unroll
        for(int e=0;e<8;++e){
          const int c = q*8+e;
          s[e] = bf16_((h2[c]-mu)*rs*n2w[c] + n2b[c]);
        }
        *(v8s*)&hlds[lane*72 + q*8] = s;
      }
    }
  }

  v4f acc2[4];
  #pragma unroll
  for(int n=0;n<4;++n) acc2[n] = (v4f){0.f,0.f,0.f,0.f};

  for(int h=0; h<2; ++h){
    if(h) __syncthreads();
    {
      const int jl = t >> 1, hc = (t & 1)*32;
      const float* src = f1w + (size_t)(h*128 + jl)*64 + hc;
      #pragma unroll
      for(int q=0;q<4;++q){
        const float4 fa = ((const float4*)src)[q*2];
        const float4 fb = ((const float4*)src)[q*2+1];
        v8s s;
        s[0]=bf16_(fa.x); s[1]=bf16_(fa.y); s[2]=bf16_(fa.z); s[3]=bf16_(fa.w);
        s[4]=bf16_(fb.x); s[5]=bf16_(fb.y); s[6]=bf16_(fb.z); s[7]=bf16_(fb.w);
        *(v8s*)&w1lds[jl*72 + hc + q*8] = s;
      }
    }
    {
      const int ol = t >> 2, seg = (t & 3)*32;
      const float* src = f2w + (size_t)ol*256 + h*128 + seg;
      #pragma unroll
      for(int q=0;q<4;++q){
        const float4 fa = ((const float4*)src)[q*2];
        const float4 fb = ((const float4*)src)[q*2+1];
        v8s s;
        s[0]=bf16_(fa.x); s[1]=bf16_(fa.y); s[2]=bf16_(fa.z); s[3]=bf16_(fa.w);
        s[4]=bf16_(fb.x); s[5]=bf16_(fb.y); s[6]=bf16_(fb.z); s[7]=bf16_(fb.w);
        *(v8s*)&w2lds[ol*136 + seg + q*8] = s;
      }
    }
    __syncthreads();
    #pragma unroll 2
    for(int nt=0; nt<8; ++nt){
      v4f acc = (v4f){0.f,0.f,0.f,0.f};
      #pragma unroll
      for(int ks=0; ks<2; ++ks){
        const v8s a = *(const v8s*)&hlds[(wv*16 + m)*72 + ks*32 + quad*8];
        const v8s b = *(const v8s*)&w1lds[(nt*16 + m)*72 + ks*32 + quad*8];
        acc = __builtin_amdgcn_mfma_f32_16x16x32_bf16(a, b, acc, 0, 0, 0);
      }
      const float bj = f1b[h*128 + nt*16 + m];
      #pragma unroll
      for(int r=0;r<4;++r){
        glds[(wv*16 + quad*4 + r)*136 + nt*16 + m] = bf16_(geluf_(acc[r] + bj));
      }
    }
    #pragma unroll
    for(int nt=0; nt<4; ++nt){
      v4f acc = acc2[nt];
      #pragma unroll
      for(int ks=0; ks<4; ++ks){
        const v8s a = *(const v8s*)&glds[(wv*16 + m)*136 + ks*32 + quad*8];
        const v8s b = *(const v8s*)&w2lds[(nt*16 + m)*136 + ks*32 + quad*8];
        acc = __builtin_amdgcn_mfma_f32_16x16x32_bf16(a, b, acc, 0, 0, 0);
      }
      acc2[nt] = acc;
    }
  }

  float* sb = base + OFF_SB;
  #pragma unroll
  for(int nt=0; nt<4; ++nt){
    const float bo = f2b[nt*16 + m];
    #pragma unroll
    for(int r=0;r<4;++r){
      const int p = p0 + wv*16 + quad*4 + r;
      const int o = nt*16 + m;
      sb[(size_t)p*CC + o] = acc2[nt][r] + bo + xnew[(size_t)p*CC + o];
    }
  }
}

// K5: s = inst0 + inst1; float4-vectorized; write both output halves
__global__ __launch_bounds__(256) void k5_final(
    const float* __restrict__ ws, float* __restrict__ out)
{
  const int idx = blockIdx.x*256 + threadIdx.x;   // float4 index
  const float4 a = ((const float4*)(ws + OFF_SB))[idx];
  const float4 b = ((const float4*)(ws + ISTRIDE + OFF_SB))[idx];
  const float4 v = make_float4(a.x+b.x, a.y+b.y, a.z+b.z, a.w+b.w);
  ((float4*)out)[idx] = v;
  ((float4*)out)[NPIX/4 + idx] = v;
}

extern "C" void kernel_launch(void* const* d_in, const int* in_sizes, int n_in,
                              void* d_out, int out_size, void* d_ws, size_t ws_size,
                              hipStream_t stream)
{
  const float* mag  = (const float*)d_in[0];
  const float* ph   = (const float*)d_in[1];
  const float* n1w  = (const float*)d_in[2];
  const float* n1b  = (const float*)d_in[3];
  const float* ipw  = (const float*)d_in[4];
  const float* cw   = (const float*)d_in[5];
  const float* xpw  = (const float*)d_in[6];
  const float* dtw  = (const float*)d_in[7];
  const float* dtb  = (const float*)d_in[8];
  const float* alog = (const float*)d_in[9];
  const float* Ds   = (const float*)d_in[10];
  const float* onw  = (const float*)d_in[11];
  const float* onb  = (const float*)d_in[12];
  const float* opw  = (const float*)d_in[13];
  const float* n2w  = (const float*)d_in[14];
  const float* n2b  = (const float*)d_in[15];
  const float* f1w  = (const float*)d_in[16];
  const float* f1b  = (const float*)d_in[17];
  const float* f2w  = (const float*)d_in[18];
  const float* f2b  = (const float*)d_in[19];
  float* ws = (float*)d_ws;
  float* out = (float*)d_out;

  k1_ln_inproj<<<dim3(512,2),  256, 0, stream>>>(mag, ph, n1w, n1b, ipw, ws);
  k2_dwconv   <<<dim3(1024,2), 256, 0, stream>>>(cw, ws);
  k3a_xproj   <<<dim3(16,32,2),256, 0, stream>>>(xpw, ws);
  k3b_scan    <<<dim3(2048,2), 256, 0, stream>>>(dtw, dtb, alog, Ds, ws);
  k3c_combine <<<dim3(128,2),  256, 0, stream>>>(ws);
  k4a_proj    <<<dim3(512,2),  256, 0, stream>>>(mag, ph, onw, onb, opw, ws);
  k4b_mlp     <<<dim3(512,2),  256, 0, stream>>>(n2w, n2b, f1w, f1b, f2w, f2b, ws);
  k5_final    <<<dim3(2048),   256, 0, stream>>>(ws, out);
}

// Round 16
// 361.806 us; speedup vs baseline: 2.4671x; 1.0024x over previous
//
#include <hip/hip_runtime.h>
#include <math.h>

// Problem constants
#define LL   4096      // H*W
#define DI   128       // 2*C
#define CC   64        // C
#define BB   8         // batch
#define KK   4         // scan directions
#define LB   32768     // pixels per instance
#define NPIX 2097152   // B*H*W*C elements of s
#define EPSF 1e-5f

// Workspace layout (floats, per instance)
#define OFF_XCIN   ((size_t)0)
#define OFF_XCONV  ((size_t)4194304)
#define OFF_XCONVT ((size_t)8388608)
#define OFF_Z      ((size_t)12582912)
#define OFF_Y      ((size_t)16777216)
#define OFF_YT     ((size_t)20971520)
#define OFF_XDBL   ((size_t)25165824)
#define ISTRIDE    ((size_t)25952256)   // floats per instance
// Aliases (lifetime-disjoint reuse):
#define OFF_YCOMBT OFF_XCIN             // xcin dead after k2; ycombT (d-major) by k3c
#define OFF_XNEW   OFF_YT               // yT dead after k3c; xnew (pixel-major) by k4a
#define OFF_SB     OFF_Y                // y dead after k3c; sbuf by k4b

typedef short v8s __attribute__((ext_vector_type(8)));
typedef float v4f __attribute__((ext_vector_type(4)));

// Fast transcendentals: native v_exp/v_log paths (error ~1e-7, threshold 0.144)
__device__ __forceinline__ float fexp_(float x){ return __expf(x); }
__device__ __forceinline__ float silu_(float x){ return __fdividef(x, 1.f+__expf(-x)); }
__device__ __forceinline__ float softplusf_(float x){
  return fmaxf(x,0.f) + __logf(1.f + __expf(-fabsf(x)));
}
__device__ __forceinline__ float geluf_(float x){ return 0.5f*x*(1.f+erff(x*0.70710678118f)); }
__device__ __forceinline__ short bf16_(float x){
  unsigned u = __float_as_uint(x);
  u += 0x7FFF + ((u>>16)&1);     // RNE
  return (short)(u>>16);
}

#define LD16(dst, ptr) { const float4* p4_=(const float4*)(ptr);                 \
  float4 v0_=p4_[0], v1_=p4_[1], v2_=p4_[2], v3_=p4_[3];                         \
  dst[0]=v0_.x; dst[1]=v0_.y; dst[2]=v0_.z; dst[3]=v0_.w;                        \
  dst[4]=v1_.x; dst[5]=v1_.y; dst[6]=v1_.z; dst[7]=v1_.w;                        \
  dst[8]=v2_.x; dst[9]=v2_.y; dst[10]=v2_.z; dst[11]=v2_.w;                      \
  dst[12]=v3_.x; dst[13]=v3_.y; dst[14]=v3_.z; dst[15]=v3_.w; }
#define LD16R(dst, ptr) { const float4* p4_=(const float4*)(ptr);                \
  float4 v0_=p4_[0], v1_=p4_[1], v2_=p4_[2], v3_=p4_[3];                         \
  dst[15]=v0_.x; dst[14]=v0_.y; dst[13]=v0_.z; dst[12]=v0_.w;                    \
  dst[11]=v1_.x; dst[10]=v1_.y; dst[9]=v1_.z;  dst[8]=v1_.w;                     \
  dst[7]=v2_.x;  dst[6]=v2_.y;  dst[5]=v2_.z;  dst[4]=v2_.w;                     \
  dst[3]=v3_.x;  dst[2]=v3_.y;  dst[1]=v3_.z;  dst[0]=v3_.w; }

// K1 v5 (MFMA): block = 64 pixels, 4 waves. LN (fp32) -> bf16 hlds; per 128-row
// half of ipw: stage w1lds, 8 n-tiles x 2 k-steps mfma, outs -> coalesced stores.
__global__ __launch_bounds__(256) void k1_ln_inproj(
    const float* __restrict__ xmag, const float* __restrict__ xph,
    const float* __restrict__ n1w_, const float* __restrict__ n1b_,
    const float* __restrict__ ipw_, float* __restrict__ ws)
{
  const int i = blockIdx.y;
  const float* xin = i ? xph : xmag;
  const float* n1w = n1w_ + i*CC;
  const float* n1b = n1b_ + i*CC;
  const float* ipw = ipw_ + i*2*DI*CC;   // [256][64]
  float* base = ws + (size_t)i*ISTRIDE;
  const int t = threadIdx.x, lane = t & 63;
  const int wv = __builtin_amdgcn_readfirstlane(t >> 6);
  const int m = lane & 15, quad = lane >> 4;
  const int p0 = blockIdx.x*64;
  const int b = p0 >> 12, l0 = p0 & (LL-1);

  __shared__ short hlds[64*72];
  __shared__ short w1lds[128*72];
  __shared__ float outs[128*68];

  {
    float hn[CC];
    const float* xr = xin + (size_t)(p0 + lane)*CC;
    LD16(hn, xr); LD16((hn+16), xr+16); LD16((hn+32), xr+32); LD16((hn+48), xr+48);
    float s1=0.f, s2=0.f;
    #pragma unroll
    for(int c=0;c<CC;++c){ s1 += hn[c]; s2 += hn[c]*hn[c]; }
    const float mu = s1*(1.f/CC);
    const float rs = rsqrtf(s2*(1.f/CC) - mu*mu + EPSF);
    if(wv==0){
      #pragma unroll
      for(int q=0;q<8;++q){
        v8s s;
        #pragma unroll
        for(int e=0;e<8;++e){
          const int c = q*8+e;
          s[e] = bf16_((hn[c]-mu)*rs*n1w[c] + n1b[c]);
        }
        *(v8s*)&hlds[lane*72 + q*8] = s;
      }
    }
  }

  for(int h=0; h<2; ++h){
    if(h) __syncthreads();
    {
      const int jl = t >> 1, hc = (t & 1)*32;
      const float* src = ipw + (size_t)(h*128 + jl)*64 + hc;
      #pragma unroll
      for(int q=0;q<4;++q){
        const float4 fa = ((const float4*)src)[q*2];
        const float4 fb = ((const float4*)src)[q*2+1];
        v8s s;
        s[0]=bf16_(fa.x); s[1]=bf16_(fa.y); s[2]=bf16_(fa.z); s[3]=bf16_(fa.w);
        s[4]=bf16_(fb.x); s[5]=bf16_(fb.y); s[6]=bf16_(fb.z); s[7]=bf16_(fb.w);
        *(v8s*)&w1lds[jl*72 + hc + q*8] = s;
      }
    }
    __syncthreads();
    #pragma unroll 2
    for(int nt=0; nt<8; ++nt){
      v4f acc = (v4f){0.f,0.f,0.f,0.f};
      #pragma unroll
      for(int ks=0; ks<2; ++ks){
        const v8s a = *(const v8s*)&hlds[(wv*16 + m)*72 + ks*32 + quad*8];
        const v8s bb = *(const v8s*)&w1lds[(nt*16 + m)*72 + ks*32 + quad*8];
        acc = __builtin_amdgcn_mfma_f32_16x16x32_bf16(a, bb, acc, 0, 0, 0);
      }
      *(float4*)&outs[(nt*16 + m)*68 + wv*16 + quad*4] =
          make_float4(acc[0], acc[1], acc[2], acc[3]);
    }
    __syncthreads();
    const int jl = t >> 1, hc = (t & 1)*32;
    if(h==0){
      float* xcb = base + OFF_XCIN + (size_t)b*DI*LL + (size_t)jl*LL + l0 + hc;
      #pragma unroll
      for(int q=0;q<8;++q)
        ((float4*)xcb)[q] = *(const float4*)&outs[jl*68 + hc + q*4];
    } else {
      float* zr = base + OFF_Z + (size_t)jl*LB + p0 + hc;
      #pragma unroll
      for(int q=0;q<8;++q){
        const float4 v = *(const float4*)&outs[jl*68 + hc + q*4];
        ((float4*)zr)[q] = make_float4(silu_(v.x), silu_(v.y), silu_(v.z), silu_(v.w));
      }
    }
  }
}

// K2: depthwise 3x3 conv + silu; per (b,d) 64x64 tile via LDS; row-major + transposed out
__global__ __launch_bounds__(256) void k2_dwconv(
    const float* __restrict__ cw_, float* __restrict__ ws)
{
  const int i = blockIdx.y;
  const int bd = blockIdx.x;
  const int d = bd & (DI-1);
  const float* cw = cw_ + i*DI*9 + d*9;
  const float* xcin  = ws + (size_t)i*ISTRIDE + OFF_XCIN  + (size_t)bd*LL;
  float* xconv  = ws + (size_t)i*ISTRIDE + OFF_XCONV  + (size_t)bd*LL;
  float* xconvT = ws + (size_t)i*ISTRIDE + OFF_XCONVT + (size_t)bd*LL;
  __shared__ float tin[64*65];
  __shared__ float tout[64*65];
  const int t = threadIdx.x;
  float w9[9];
  #pragma unroll
  for(int q=0;q<9;++q) w9[q] = cw[q];
  for(int idx=t; idx<4096; idx+=256)
    tin[(idx>>6)*65 + (idx&63)] = xcin[idx];
  __syncthreads();
  const int w = t & 63, hb = (t>>6)*16;
  #pragma unroll
  for(int r=0;r<16;++r){
    const int h = hb + r;
    float acc = 0.f;
    #pragma unroll
    for(int dy=0;dy<3;++dy){
      const int hh = h + dy - 1;
      if(hh>=0 && hh<64){
        #pragma unroll
        for(int dx=0;dx<3;++dx){
          const int ww = w + dx - 1;
          if(ww>=0 && ww<64) acc += tin[hh*65+ww]*w9[dy*3+dx];
        }
      }
    }
    const float o = silu_(acc);
    tout[h*65+w] = o;
    xconv[h*64+w] = o;
  }
  __syncthreads();
  const int hcol = t & 63, wb = (t>>6)*16;
  #pragma unroll
  for(int r=0;r<16;++r){
    const int wp = wb + r;
    xconvT[wp*64 + hcol] = tout[hcol*65 + wp];
  }
}

// K3a v2: paired-direction x_proj. Directions k=kp and k=kp+2 read the SAME
// source data (the latter scan-reversed), so one block computes both: 12 FMAs
// per load, half the read traffic. Reversed store is still a contiguous
// 64-lane segment (coalesced).
__global__ __launch_bounds__(256) void k3a_xproj(
    const float* __restrict__ xpw_, float* __restrict__ ws)
{
  const int i = blockIdx.z;
  const int b = blockIdx.y >> 1;
  const int kp = blockIdx.y & 1;
  const int l = blockIdx.x*256 + threadIdx.x;   // source index
  const float* src = ws + (size_t)i*ISTRIDE + (kp? OFF_XCONVT : OFF_XCONV) + (size_t)b*DI*LL;
  const float* xpwF = xpw_ + i*KK*6*DI + kp*6*DI;
  const float* xpwB = xpw_ + i*KK*6*DI + (kp+2)*6*DI;
  float accF[6] = {0,0,0,0,0,0};
  float accB[6] = {0,0,0,0,0,0};
  for(int d=0; d<DI; ++d){
    const float xv = src[(size_t)d*LL + l];
    #pragma unroll
    for(int c=0;c<6;++c){
      accF[c] += xv * xpwF[c*DI + d];
      accB[c] += xv * xpwB[c*DI + d];
    }
  }
  float* xdF = ws + (size_t)i*ISTRIDE + OFF_XDBL + (size_t)(b*KK+kp  )*6*LL;
  float* xdB = ws + (size_t)i*ISTRIDE + OFF_XDBL + (size_t)(b*KK+kp+2)*6*LL;
  #pragma unroll
  for(int c=0;c<6;++c) xdF[(size_t)c*LL + l] = accF[c];
  #pragma unroll
  for(int c=0;c<6;++c) xdB[(size_t)c*LL + (LL-1-l)] = accB[c];
}

// K3b (round-13 body): paired fwd/bwd scan; wave shuffle scan, 1 barrier.
// (256,3): 68 VGPR + AGPR overflow, no scratch spills — measured optimum.
__global__ __launch_bounds__(256,3) void k3b_scan(
    const float* __restrict__ dtw_, const float* __restrict__ dtb_,
    const float* __restrict__ alog_, const float* __restrict__ Ds_,
    float* __restrict__ ws)
{
  const int gid = blockIdx.x;           // b*256 + kp*128 + d
  const int i = blockIdx.y;
  const int d  = gid & (DI-1);
  const int kp = (gid >> 7) & 1;
  const int b  = gid >> 8;
  const int t = threadIdx.x, lane = t & 63, wv = t >> 6;
  float* base = ws + (size_t)i*ISTRIDE;
  const float* src = base + (kp? OFF_XCONVT : OFF_XCONV) + (size_t)(b*DI+d)*LL;
  float*       dst = base + (kp? OFF_YT    : OFF_Y    ) + (size_t)(b*DI+d)*LL;
  const float* xdF = base + OFF_XDBL + (size_t)(b*KK+kp  )*6*LL;
  const float* xdB = base + OFF_XDBL + (size_t)(b*KK+kp+2)*6*LL;
  const int kdF = kp*DI + d, kdB = (kp+2)*DI + d;
  const float4 wF = ((const float4*)dtw_)[i*KK*DI + kdF];
  const float4 wB = ((const float4*)dtw_)[i*KK*DI + kdB];
  const float biasF = dtb_[i*KK*DI + kdF], biasB = dtb_[i*KK*DI + kdB];
  const float AvF = -fexp_(alog_[i*KK*DI + kdF]);
  const float AvB = -fexp_(alog_[i*KK*DI + kdB]);
  const float Dsum = Ds_[i*KK*DI + kdF] + Ds_[i*KK*DI + kdB];
  const int l0 = t*16;
  const int s0 = LL - 16 - l0;

  float vX[16], aF[16], bF[16], aB[16], bB[16];
  float fA = 1.f, fB = 0.f, gA = 1.f, gB = 0.f;
  LD16(vX, src + l0);

  {
    float pre[16], r0[16];
    LD16(r0, xdF + 0*LL + l0);
    #pragma unroll
    for(int j=0;j<16;++j) pre[j] = biasF + wF.x*r0[j];
    LD16(r0, xdF + 1*LL + l0);
    #pragma unroll
    for(int j=0;j<16;++j) pre[j] += wF.y*r0[j];
    LD16(r0, xdF + 2*LL + l0);
    #pragma unroll
    for(int j=0;j<16;++j) pre[j] += wF.z*r0[j];
    LD16(r0, xdF + 3*LL + l0);
    #pragma unroll
    for(int j=0;j<16;++j) pre[j] += wF.w*r0[j];
    LD16(r0, xdF + 4*LL + l0);   // Bs
    #pragma unroll
    for(int j=0;j<16;++j){
      const float delta = softplusf_(pre[j]);
      aF[j] = fexp_(delta*AvF);
      bF[j] = delta*r0[j]*vX[j];
      fB = fB*aF[j] + bF[j];
      fA *= aF[j];
    }
  }
  {
    float pre[16], r0[16];
    LD16R(r0, xdB + 0*LL + s0);
    #pragma unroll
    for(int j=0;j<16;++j) pre[j] = biasB + wB.x*r0[j];
    LD16R(r0, xdB + 1*LL + s0);
    #pragma unroll
    for(int j=0;j<16;++j) pre[j] += wB.y*r0[j];
    LD16R(r0, xdB + 2*LL + s0);
    #pragma unroll
    for(int j=0;j<16;++j) pre[j] += wB.z*r0[j];
    LD16R(r0, xdB + 3*LL + s0);
    #pragma unroll
    for(int j=0;j<16;++j) pre[j] += wB.w*r0[j];
    LD16R(r0, xdB + 4*LL + s0);  // Bs reversed
    #pragma unroll
    for(int j=15;j>=0;--j){
      const float delta = softplusf_(pre[j]);
      aB[j] = fexp_(delta*AvB);
      bB[j] = delta*r0[j]*vX[j];
      gB = gB*aB[j] + bB[j];
      gA *= aB[j];
    }
  }

  #pragma unroll
  for(int off=1; off<64; off<<=1){
    const float aL = __shfl_up(fA, off);
    const float bL = __shfl_up(fB, off);
    if(lane >= off){ fB = bL*fA + fB; fA = aL*fA; }
  }
  float pA = __shfl_up(fA, 1), pB = __shfl_up(fB, 1);
  if(lane==0){ pA=1.f; pB=0.f; }
  #pragma unroll
  for(int off=1; off<64; off<<=1){
    const float aR = __shfl_down(gA, off);
    const float bR = __shfl_down(gB, off);
    if(lane + off < 64){ gB = gA*bR + gB; gA = gA*aR; }
  }
  float qA = __shfl_down(gA, 1), qB = __shfl_down(gB, 1);
  if(lane==63){ qA=1.f; qB=0.f; }

  __shared__ float wAg[4], wBg[4], vAg[4], vBg[4];
  if(lane==63){ wAg[wv]=fA; wBg[wv]=fB; }
  if(lane==0){ vAg[wv]=gA; vBg[wv]=gB; }
  __syncthreads();
  float eB=0.f;
  for(int u=0; u<wv; ++u){ eB = wAg[u]*eB + wBg[u]; }
  float rB=0.f;
  for(int u=3; u>wv; --u){ rB = vAg[u]*rB + vBg[u]; }

  float hf = pA*eB + pB;
  float hb = qA*rB + qB;

  float out[16], cc[16];
  LD16(cc, xdF + 5*LL + l0);
  #pragma unroll
  for(int j=0;j<16;++j){
    hf = aF[j]*hf + bF[j];
    out[j] = hf*cc[j] + Dsum*vX[j];
  }
  LD16R(cc, xdB + 5*LL + s0);
  #pragma unroll
  for(int j=15;j>=0;--j){
    hb = aB[j]*hb + bB[j];
    out[j] += hb*cc[j];
  }
  float4* d4 = (float4*)(dst + l0);
  d4[0] = make_float4(out[0],out[1],out[2],out[3]);
  d4[1] = make_float4(out[4],out[5],out[6],out[7]);
  d4[2] = make_float4(out[8],out[9],out[10],out[11]);
  d4[3] = make_float4(out[12],out[13],out[14],out[15]);
}

// K3c: combine y + transpose(yT) into d-major ycombT[d][b*LL+l].
__global__ __launch_bounds__(256) void k3c_combine(float* __restrict__ ws)
{
  const int i = blockIdx.y;
  const int b = blockIdx.x >> 4;
  const int tile = blockIdx.x & 15;
  const int h0 = (tile >> 2) * 16, w0 = (tile & 3) * 16;
  const int t = threadIdx.x;
  float* base = ws + (size_t)i*ISTRIDE;
  const float* y  = base + OFF_Y;
  const float* yT = base + OFF_YT;
  float* ycT = base + OFF_YCOMBT;
  __shared__ float ytile[16*16*16];
  __shared__ float ytT[16*16*17];
  const int r0 = t >> 4, c0 = t & 15;
  const int hi = t >> 4, wi = t & 15;
  const int l = (h0 + hi)*64 + (w0 + wi);
  for(int dc=0; dc<8; ++dc){
    #pragma unroll 4
    for(int dd=0; dd<16; ++dd){
      const int d = dc*16 + dd;
      const size_t rb = (size_t)(b*DI + d)*LL;
      ytile[dd*256 + t] = y[rb + (size_t)(h0 + r0)*64 + (w0 + c0)];
      ytT[dd*272 + r0*17 + c0] = yT[rb + (size_t)(w0 + r0)*64 + (h0 + c0)];
    }
    __syncthreads();
    #pragma unroll 4
    for(int dd=0; dd<16; ++dd){
      const int d = dc*16 + dd;
      ycT[(size_t)d*LB + b*LL + l] = ytile[dd*256 + t] + ytT[dd*272 + wi*17 + hi];
    }
    __syncthreads();
  }
}

// K4a v3 (MFMA): block = 64 pixels, 4 waves; LN via padded LDS stats; out_proj
// via mfma_f32_16x16x32_bf16; +xin -> xnew.
__global__ __launch_bounds__(256) void k4a_proj(
    const float* __restrict__ xmag, const float* __restrict__ xph,
    const float* __restrict__ onw_, const float* __restrict__ onb_,
    const float* __restrict__ opw_, float* __restrict__ ws)
{
  const int i = blockIdx.y;
  const float* xin = i ? xph : xmag;
  const float* onw = onw_ + i*DI;
  const float* onb = onb_ + i*DI;
  const float* opw = opw_ + i*CC*DI;     // [o][d] = [64][128]
  float* base = ws + (size_t)i*ISTRIDE;
  const float* ycT = base + OFF_YCOMBT;
  const float* zT  = base + OFF_Z;
  const int t = threadIdx.x, lane = t & 63;
  const int wv = __builtin_amdgcn_readfirstlane(t >> 6);
  const int m = lane & 15, quad = lane >> 4;
  const int p0 = blockIdx.x*64;
  const int p = p0 + lane;

  __shared__ short ynlds[64*136];
  __shared__ short wlds[64*136];
  __shared__ float st[64][9];

  float yv[32];
  float s1=0.f, s2=0.f;
  #pragma unroll 8
  for(int c=0;c<32;++c){
    const float v = ycT[(size_t)(wv*32+c)*LB + p];
    yv[c]=v; s1+=v; s2+=v*v;
  }
  st[lane][wv*2]=s1; st[lane][wv*2+1]=s2;
  __syncthreads();
  const float S1 = st[lane][0]+st[lane][2]+st[lane][4]+st[lane][6];
  const float S2 = st[lane][1]+st[lane][3]+st[lane][5]+st[lane][7];
  const float mu = S1*(1.f/DI);
  const float rs = rsqrtf(S2*(1.f/DI) - mu*mu + EPSF);
  #pragma unroll
  for(int cq=0;cq<8;++cq){
    short4 s4;
    #pragma unroll
    for(int e=0;e<4;++e){
      const int c = cq*4+e;
      const int d = wv*32 + c;
      ((short*)&s4)[e] = bf16_(((yv[c]-mu)*rs*onw[d] + onb[d]) * zT[(size_t)d*LB + p]);
    }
    *(short4*)&ynlds[lane*136 + wv*32 + cq*4] = s4;
  }
  {
    const int ol = t >> 2, seg = (t & 3)*32;
    const float* src = opw + (size_t)ol*DI + seg;
    #pragma unroll
    for(int q=0;q<4;++q){
      const float4 fa = ((const float4*)src)[q*2];
      const float4 fb = ((const float4*)src)[q*2+1];
      v8s s;
      s[0]=bf16_(fa.x); s[1]=bf16_(fa.y); s[2]=bf16_(fa.z); s[3]=bf16_(fa.w);
      s[4]=bf16_(fb.x); s[5]=bf16_(fb.y); s[6]=bf16_(fb.z); s[7]=bf16_(fb.w);
      *(v8s*)&wlds[ol*136 + seg + q*8] = s;
    }
  }
  __syncthreads();

  v4f accs[4];
  #pragma unroll
  for(int nt=0; nt<4; ++nt){
    v4f acc = (v4f){0.f,0.f,0.f,0.f};
    #pragma unroll
    for(int ks=0; ks<4; ++ks){
      const v8s a = *(const v8s*)&ynlds[(wv*16 + m)*136 + ks*32 + quad*8];
      const v8s b = *(const v8s*)&wlds[(nt*16 + m)*136 + ks*32 + quad*8];
      acc = __builtin_amdgcn_mfma_f32_16x16x32_bf16(a, b, acc, 0, 0, 0);
    }
    accs[nt] = acc;
  }
  float* xnew = base + OFF_XNEW;
  #pragma unroll
  for(int nt=0; nt<4; ++nt){
    #pragma unroll
    for(int r=0;r<4;++r){
      const int pp = p0 + wv*16 + quad*4 + r;
      const int o = nt*16 + m;
      xnew[(size_t)pp*CC + o] = accs[nt][r] + xin[(size_t)pp*CC + o];
    }
  }
}

// K4b v7 (MFMA): 64-pixel tile per block, 4 waves. LN (fp32) -> bf16 H in LDS;
// per 128-j half: stage F1/F2 bf16, fc1 mfma 16x16x32, GELU, fc2 mfma.
__global__ __launch_bounds__(256) void k4b_mlp(
    const float* __restrict__ n2w_, const float* __restrict__ n2b_,
    const float* __restrict__ f1w_, const float* __restrict__ f1b_,
    const float* __restrict__ f2w_, const float* __restrict__ f2b_,
    float* __restrict__ ws)
{
  const int i = blockIdx.y;
  const float* n2w = n2w_ + i*CC;
  const float* n2b = n2b_ + i*CC;
  const float* f1w = f1w_ + i*256*64;    // [j][c]
  const float* f1b = f1b_ + i*256;
  const float* f2w = f2w_ + i*64*256;    // [o][j]
  const float* f2b = f2b_ + i*CC;
  float* base = ws + (size_t)i*ISTRIDE;
  const float* xnew = base + OFF_XNEW;
  const int t = threadIdx.x, lane = t & 63;
  const int wv = __builtin_amdgcn_readfirstlane(t >> 6);
  const int m = lane & 15, quad = lane >> 4;
  const int p0 = blockIdx.x*64;

  __shared__ short hlds[64*72];
  __shared__ short w1lds[128*72];
  __shared__ short glds[64*136];
  __shared__ short w2lds[64*136];

  {
    float h2[64];
    const float* xr = xnew + (size_t)(p0 + lane)*CC;
    LD16(h2, xr); LD16((h2+16), xr+16); LD16((h2+32), xr+32); LD16((h2+48), xr+48);
    float s1=0.f, s2=0.f;
    #pragma unroll
    for(int c=0;c<CC;++c){ s1 += h2[c]; s2 += h2[c]*h2[c]; }
    const float mu = s1*(1.f/CC);
    const float rs = rsqrtf(s2*(1.f/CC) - mu*mu + EPSF);
    if(wv==0){
      #pragma unroll
      for(int q=0;q<8;++q){
        v8s s;
        #pragma unroll
        for(int e=0;e<8;++e){
          const int c = q*8+e;
          s[e] = bf16_((h2[c]-mu)*rs*n2w[c] + n2b[c]);
        }
        *(v8s*)&hlds[lane*72 + q*8] = s;
      }
    }
  }

  v4f acc2[4];
  #pragma unroll
  for(int n=0;n<4;++n) acc2[n] = (v4f){0.f,0.f,0.f,0.f};

  for(int h=0; h<2; ++h){
    if(h) __syncthreads();
    {
      const int jl = t >> 1, hc = (t & 1)*32;
      const float* src = f1w + (size_t)(h*128 + jl)*64 + hc;
      #pragma unroll
      for(int q=0;q<4;++q){
        const float4 fa = ((const float4*)src)[q*2];
        const float4 fb = ((const float4*)src)[q*2+1];
        v8s s;
        s[0]=bf16_(fa.x); s[1]=bf16_(fa.y); s[2]=bf16_(fa.z); s[3]=bf16_(fa.w);
        s[4]=bf16_(fb.x); s[5]=bf16_(fb.y); s[6]=bf16_(fb.z); s[7]=bf16_(fb.w);
        *(v8s*)&w1lds[jl*72 + hc + q*8] = s;
      }
    }
    {
      const int ol = t >> 2, seg = (t & 3)*32;
      const float* src = f2w + (size_t)ol*256 + h*128 + seg;
      #pragma unroll
      for(int q=0;q<4;++q){
        const float4 fa = ((const float4*)src)[q*2];
        const float4 fb = ((const float4*)src)[q*2+1];
        v8s s;
        s[0]=bf16_(fa.x); s[1]=bf16_(fa.y); s[2]=bf16_(fa.z); s[3]=bf16_(fa.w);
        s[4]=bf16_(fb.x); s[5]=bf16_(fb.y); s[6]=bf16_(fb.z); s[7]=bf16_(fb.w);
        *(v8s*)&w2lds[ol*136 + seg + q*8] = s;
      }
    }
    __syncthreads();
    #pragma unroll 2
    for(int nt=0; nt<8; ++nt){
      v4f acc = (v4f){0.f,0.f,0.f,0.f};
      #pragma unroll
      for(int ks=0; ks<2; ++ks){
        const v8s a = *(const v8s*)&hlds[(wv*16 + m)*72 + ks*32 + quad*8];
        const v8s b = *(const v8s*)&w1lds[(nt*16 + m)*72 + ks*32 + quad*8];
        acc = __builtin_amdgcn_mfma_f32_16x16x32_bf16(a, b, acc, 0, 0, 0);
      }
      const float bj = f1b[h*128 + nt*16 + m];
      #pragma unroll
      for(int r=0;r<4;++r){
        glds[(wv*16 + quad*4 + r)*136 + nt*16 + m] = bf16_(geluf_(acc[r] + bj));
      }
    }
    #pragma unroll
    for(int nt=0; nt<4; ++nt){
      v4f acc = acc2[nt];
      #pragma unroll
      for(int ks=0; ks<4; ++ks){
        const v8s a = *(const v8s*)&glds[(wv*16 + m)*136 + ks*32 + quad*8];
        const v8s b = *(const v8s*)&w2lds[(nt*16 + m)*136 + ks*32 + quad*8];
        acc = __builtin_amdgcn_mfma_f32_16x16x32_bf16(a, b, acc, 0, 0, 0);
      }
      acc2[nt] = acc;
    }
  }

  float* sb = base + OFF_SB;
  #pragma unroll
  for(int nt=0; nt<4; ++nt){
    const float bo = f2b[nt*16 + m];
    #pragma unroll
    for(int r=0;r<4;++r){
      const int p = p0 + wv*16 + quad*4 + r;
      const int o = nt*16 + m;
      sb[(size_t)p*CC + o] = acc2[nt][r] + bo + xnew[(size_t)p*CC + o];
    }
  }
}

// K5: s = inst0 + inst1; float4-vectorized; write both output halves
__global__ __launch_bounds__(256) void k5_final(
    const float* __restrict__ ws, float* __restrict__ out)
{
  const int idx = blockIdx.x*256 + threadIdx.x;   // float4 index
  const float4 a = ((const float4*)(ws + OFF_SB))[idx];
  const float4 b = ((const float4*)(ws + ISTRIDE + OFF_SB))[idx];
  const float4 v = make_float4(a.x+b.x, a.y+b.y, a.z+b.z, a.w+b.w);
  ((float4*)out)[idx] = v;
  ((float4*)out)[NPIX/4 + idx] = v;
}

extern "C" void kernel_launch(void* const* d_in, const int* in_sizes, int n_in,
                              void* d_out, int out_size, void* d_ws, size_t ws_size,
                              hipStream_t stream)
{
  const float* mag  = (const float*)d_in[0];
  const float* ph   = (const float*)d_in[1];
  const float* n1w  = (const float*)d_in[2];
  const float* n1b  = (const float*)d_in[3];
  const float* ipw  = (const float*)d_in[4];
  const float* cw   = (const float*)d_in[5];
  const float* xpw  = (const float*)d_in[6];
  const float* dtw  = (const float*)d_in[7];
  const float* dtb  = (const float*)d_in[8];
  const float* alog = (const float*)d_in[9];
  const float* Ds   = (const float*)d_in[10];
  const float* onw  = (const float*)d_in[11];
  const float* onb  = (const float*)d_in[12];
  const float* opw  = (const float*)d_in[13];
  const float* n2w  = (const float*)d_in[14];
  const float* n2b  = (const float*)d_in[15];
  const float* f1w  = (const float*)d_in[16];
  const float* f1b  = (const float*)d_in[17];
  const float* f2w  = (const float*)d_in[18];
  const float* f2b  = (const float*)d_in[19];
  float* ws = (float*)d_ws;
  float* out = (float*)d_out;

  k1_ln_inproj<<<dim3(512,2),  256, 0, stream>>>(mag, ph, n1w, n1b, ipw, ws);
  k2_dwconv   <<<dim3(1024,2), 256, 0, stream>>>(cw, ws);
  k3a_xproj   <<<dim3(16,16,2),256, 0, stream>>>(xpw, ws);
  k3b_scan    <<<dim3(2048,2), 256, 0, stream>>>(dtw, dtb, alog, Ds, ws);
  k3c_combine <<<dim3(128,2),  256, 0, stream>>>(ws);
  k4a_proj    <<<dim3(512,2),  256, 0, stream>>>(mag, ph, onw, onb, opw, ws);
  k4b_mlp     <<<dim3(512,2),  256, 0, stream>>>(n2w, n2b, f1w, f1b, f2w, f2b, ws);
  k5_final    <<<dim3(2048),   256, 0, stream>>>(ws, out);
}

// Round 17
// 354.995 us; speedup vs baseline: 2.5144x; 1.0192x over previous
//
#include <hip/hip_runtime.h>
#include <math.h>

// Problem constants
#define LL   4096      // H*W
#define DI   128       // 2*C
#define CC   64        // C
#define BB   8         // batch
#define KK   4         // scan directions
#define LB   32768     // pixels per instance
#define NPIX 2097152   // B*H*W*C elements of s
#define EPSF 1e-5f

// Workspace layout (floats, per instance). XCONV/XCONVT regions now hold bf16
// (half-occupied; offsets unchanged for simplicity).
#define OFF_XCIN   ((size_t)0)
#define OFF_XCONV  ((size_t)4194304)
#define OFF_XCONVT ((size_t)8388608)
#define OFF_Z      ((size_t)12582912)
#define OFF_Y      ((size_t)16777216)
#define OFF_YT     ((size_t)20971520)
#define OFF_XDBL   ((size_t)25165824)
#define ISTRIDE    ((size_t)25952256)   // floats per instance
// Aliases (lifetime-disjoint reuse):
#define OFF_YCOMBT OFF_XCIN             // xcin dead after k2; ycombT (d-major) by k3c
#define OFF_XNEW   OFF_YT               // yT dead after k3c; xnew (pixel-major) by k4a
#define OFF_SB     OFF_Y                // y dead after k3c; sbuf by k4b

typedef short v8s __attribute__((ext_vector_type(8)));
typedef float v4f __attribute__((ext_vector_type(4)));

// Fast transcendentals: native v_exp/v_log paths (error ~1e-7, threshold 0.144)
__device__ __forceinline__ float fexp_(float x){ return __expf(x); }
__device__ __forceinline__ float silu_(float x){ return __fdividef(x, 1.f+__expf(-x)); }
__device__ __forceinline__ float softplusf_(float x){
  return fmaxf(x,0.f) + __logf(1.f + __expf(-fabsf(x)));
}
__device__ __forceinline__ float geluf_(float x){ return 0.5f*x*(1.f+erff(x*0.70710678118f)); }
__device__ __forceinline__ short bf16_(float x){
  unsigned u = __float_as_uint(x);
  u += 0x7FFF + ((u>>16)&1);     // RNE
  return (short)(u>>16);
}
__device__ __forceinline__ float bf2f_(short s){
  return __uint_as_float(((unsigned)(unsigned short)s)<<16);
}

#define LD16(dst, ptr) { const float4* p4_=(const float4*)(ptr);                 \
  float4 v0_=p4_[0], v1_=p4_[1], v2_=p4_[2], v3_=p4_[3];                         \
  dst[0]=v0_.x; dst[1]=v0_.y; dst[2]=v0_.z; dst[3]=v0_.w;                        \
  dst[4]=v1_.x; dst[5]=v1_.y; dst[6]=v1_.z; dst[7]=v1_.w;                        \
  dst[8]=v2_.x; dst[9]=v2_.y; dst[10]=v2_.z; dst[11]=v2_.w;                      \
  dst[12]=v3_.x; dst[13]=v3_.y; dst[14]=v3_.z; dst[15]=v3_.w; }
#define LD16R(dst, ptr) { const float4* p4_=(const float4*)(ptr);                \
  float4 v0_=p4_[0], v1_=p4_[1], v2_=p4_[2], v3_=p4_[3];                         \
  dst[15]=v0_.x; dst[14]=v0_.y; dst[13]=v0_.z; dst[12]=v0_.w;                    \
  dst[11]=v1_.x; dst[10]=v1_.y; dst[9]=v1_.z;  dst[8]=v1_.w;                     \
  dst[7]=v2_.x;  dst[6]=v2_.y;  dst[5]=v2_.z;  dst[4]=v2_.w;                     \
  dst[3]=v3_.x;  dst[2]=v3_.y;  dst[1]=v3_.z;  dst[0]=v3_.w; }
// 16 bf16 (32B) -> 16 floats
#define LD16H(dst, ptr) { const v8s* p8_=(const v8s*)(ptr);                      \
  v8s a0_=p8_[0], a1_=p8_[1];                                                    \
  _Pragma("unroll") for(int e_=0;e_<8;++e_){ dst[e_]=bf2f_(a0_[e_]);             \
                                             dst[8+e_]=bf2f_(a1_[e_]); } }

// K1 v5 (MFMA): block = 64 pixels, 4 waves. LN (fp32) -> bf16 hlds; per 128-row
// half of ipw: stage w1lds, 8 n-tiles x 2 k-steps mfma, outs -> coalesced stores.
__global__ __launch_bounds__(256) void k1_ln_inproj(
    const float* __restrict__ xmag, const float* __restrict__ xph,
    const float* __restrict__ n1w_, const float* __restrict__ n1b_,
    const float* __restrict__ ipw_, float* __restrict__ ws)
{
  const int i = blockIdx.y;
  const float* xin = i ? xph : xmag;
  const float* n1w = n1w_ + i*CC;
  const float* n1b = n1b_ + i*CC;
  const float* ipw = ipw_ + i*2*DI*CC;   // [256][64]
  float* base = ws + (size_t)i*ISTRIDE;
  const int t = threadIdx.x, lane = t & 63;
  const int wv = __builtin_amdgcn_readfirstlane(t >> 6);
  const int m = lane & 15, quad = lane >> 4;
  const int p0 = blockIdx.x*64;
  const int b = p0 >> 12, l0 = p0 & (LL-1);

  __shared__ short hlds[64*72];
  __shared__ short w1lds[128*72];
  __shared__ float outs[128*68];

  {
    float hn[CC];
    const float* xr = xin + (size_t)(p0 + lane)*CC;
    LD16(hn, xr); LD16((hn+16), xr+16); LD16((hn+32), xr+32); LD16((hn+48), xr+48);
    float s1=0.f, s2=0.f;
    #pragma unroll
    for(int c=0;c<CC;++c){ s1 += hn[c]; s2 += hn[c]*hn[c]; }
    const float mu = s1*(1.f/CC);
    const float rs = rsqrtf(s2*(1.f/CC) - mu*mu + EPSF);
    if(wv==0){
      #pragma unroll
      for(int q=0;q<8;++q){
        v8s s;
        #pragma unroll
        for(int e=0;e<8;++e){
          const int c = q*8+e;
          s[e] = bf16_((hn[c]-mu)*rs*n1w[c] + n1b[c]);
        }
        *(v8s*)&hlds[lane*72 + q*8] = s;
      }
    }
  }

  for(int h=0; h<2; ++h){
    if(h) __syncthreads();
    {
      const int jl = t >> 1, hc = (t & 1)*32;
      const float* src = ipw + (size_t)(h*128 + jl)*64 + hc;
      #pragma unroll
      for(int q=0;q<4;++q){
        const float4 fa = ((const float4*)src)[q*2];
        const float4 fb = ((const float4*)src)[q*2+1];
        v8s s;
        s[0]=bf16_(fa.x); s[1]=bf16_(fa.y); s[2]=bf16_(fa.z); s[3]=bf16_(fa.w);
        s[4]=bf16_(fb.x); s[5]=bf16_(fb.y); s[6]=bf16_(fb.z); s[7]=bf16_(fb.w);
        *(v8s*)&w1lds[jl*72 + hc + q*8] = s;
      }
    }
    __syncthreads();
    #pragma unroll 2
    for(int nt=0; nt<8; ++nt){
      v4f acc = (v4f){0.f,0.f,0.f,0.f};
      #pragma unroll
      for(int ks=0; ks<2; ++ks){
        const v8s a = *(const v8s*)&hlds[(wv*16 + m)*72 + ks*32 + quad*8];
        const v8s bb = *(const v8s*)&w1lds[(nt*16 + m)*72 + ks*32 + quad*8];
        acc = __builtin_amdgcn_mfma_f32_16x16x32_bf16(a, bb, acc, 0, 0, 0);
      }
      *(float4*)&outs[(nt*16 + m)*68 + wv*16 + quad*4] =
          make_float4(acc[0], acc[1], acc[2], acc[3]);
    }
    __syncthreads();
    const int jl = t >> 1, hc = (t & 1)*32;
    if(h==0){
      float* xcb = base + OFF_XCIN + (size_t)b*DI*LL + (size_t)jl*LL + l0 + hc;
      #pragma unroll
      for(int q=0;q<8;++q)
        ((float4*)xcb)[q] = *(const float4*)&outs[jl*68 + hc + q*4];
    } else {
      float* zr = base + OFF_Z + (size_t)jl*LB + p0 + hc;
      #pragma unroll
      for(int q=0;q<8;++q){
        const float4 v = *(const float4*)&outs[jl*68 + hc + q*4];
        ((float4*)zr)[q] = make_float4(silu_(v.x), silu_(v.y), silu_(v.z), silu_(v.w));
      }
    }
  }
}

// K2: depthwise 3x3 conv + silu; per (b,d) 64x64 tile via LDS; outputs bf16
// (row-major xconv + transposed xconvT).
__global__ __launch_bounds__(256) void k2_dwconv(
    const float* __restrict__ cw_, float* __restrict__ ws)
{
  const int i = blockIdx.y;
  const int bd = blockIdx.x;
  const int d = bd & (DI-1);
  const float* cw = cw_ + i*DI*9 + d*9;
  const float* xcin  = ws + (size_t)i*ISTRIDE + OFF_XCIN + (size_t)bd*LL;
  short* xconv  = (short*)(ws + (size_t)i*ISTRIDE + OFF_XCONV ) + (size_t)bd*LL;
  short* xconvT = (short*)(ws + (size_t)i*ISTRIDE + OFF_XCONVT) + (size_t)bd*LL;
  __shared__ float tin[64*65];
  __shared__ float tout[64*65];
  const int t = threadIdx.x;
  float w9[9];
  #pragma unroll
  for(int q=0;q<9;++q) w9[q] = cw[q];
  for(int idx=t; idx<4096; idx+=256)
    tin[(idx>>6)*65 + (idx&63)] = xcin[idx];
  __syncthreads();
  const int w = t & 63, hb = (t>>6)*16;
  #pragma unroll
  for(int r=0;r<16;++r){
    const int h = hb + r;
    float acc = 0.f;
    #pragma unroll
    for(int dy=0;dy<3;++dy){
      const int hh = h + dy - 1;
      if(hh>=0 && hh<64){
        #pragma unroll
        for(int dx=0;dx<3;++dx){
          const int ww = w + dx - 1;
          if(ww>=0 && ww<64) acc += tin[hh*65+ww]*w9[dy*3+dx];
        }
      }
    }
    const float o = silu_(acc);
    tout[h*65+w] = o;
    xconv[h*64+w] = bf16_(o);
  }
  __syncthreads();
  const int hcol = t & 63, wb = (t>>6)*16;
  #pragma unroll
  for(int r=0;r<16;++r){
    const int wp = wb + r;
    xconvT[wp*64 + hcol] = bf16_(tout[hcol*65 + wp]);
  }
}

// K3a v2: paired-direction x_proj from bf16 src; 12 FMAs per load.
__global__ __launch_bounds__(256) void k3a_xproj(
    const float* __restrict__ xpw_, float* __restrict__ ws)
{
  const int i = blockIdx.z;
  const int b = blockIdx.y >> 1;
  const int kp = blockIdx.y & 1;
  const int l = blockIdx.x*256 + threadIdx.x;   // source index
  const short* src = (const short*)(ws + (size_t)i*ISTRIDE + (kp? OFF_XCONVT : OFF_XCONV))
                     + (size_t)b*DI*LL;
  const float* xpwF = xpw_ + i*KK*6*DI + kp*6*DI;
  const float* xpwB = xpw_ + i*KK*6*DI + (kp+2)*6*DI;
  float accF[6] = {0,0,0,0,0,0};
  float accB[6] = {0,0,0,0,0,0};
  for(int d=0; d<DI; ++d){
    const float xv = bf2f_(src[(size_t)d*LL + l]);
    #pragma unroll
    for(int c=0;c<6;++c){
      accF[c] += xv * xpwF[c*DI + d];
      accB[c] += xv * xpwB[c*DI + d];
    }
  }
  float* xdF = ws + (size_t)i*ISTRIDE + OFF_XDBL + (size_t)(b*KK+kp  )*6*LL;
  float* xdB = ws + (size_t)i*ISTRIDE + OFF_XDBL + (size_t)(b*KK+kp+2)*6*LL;
  #pragma unroll
  for(int c=0;c<6;++c) xdF[(size_t)c*LL + l] = accF[c];
  #pragma unroll
  for(int c=0;c<6;++c) xdB[(size_t)c*LL + (LL-1-l)] = accB[c];
}

// K3b: paired fwd/bwd scan (bf16 src); wave shuffle scan, 1 barrier. (256,3).
__global__ __launch_bounds__(256,3) void k3b_scan(
    const float* __restrict__ dtw_, const float* __restrict__ dtb_,
    const float* __restrict__ alog_, const float* __restrict__ Ds_,
    float* __restrict__ ws)
{
  const int gid = blockIdx.x;           // b*256 + kp*128 + d
  const int i = blockIdx.y;
  const int d  = gid & (DI-1);
  const int kp = (gid >> 7) & 1;
  const int b  = gid >> 8;
  const int t = threadIdx.x, lane = t & 63, wv = t >> 6;
  float* base = ws + (size_t)i*ISTRIDE;
  const short* src = (const short*)(base + (kp? OFF_XCONVT : OFF_XCONV)) + (size_t)(b*DI+d)*LL;
  float*       dst = base + (kp? OFF_YT    : OFF_Y    ) + (size_t)(b*DI+d)*LL;
  const float* xdF = base + OFF_XDBL + (size_t)(b*KK+kp  )*6*LL;
  const float* xdB = base + OFF_XDBL + (size_t)(b*KK+kp+2)*6*LL;
  const int kdF = kp*DI + d, kdB = (kp+2)*DI + d;
  const float4 wF = ((const float4*)dtw_)[i*KK*DI + kdF];
  const float4 wB = ((const float4*)dtw_)[i*KK*DI + kdB];
  const float biasF = dtb_[i*KK*DI + kdF], biasB = dtb_[i*KK*DI + kdB];
  const float AvF = -fexp_(alog_[i*KK*DI + kdF]);
  const float AvB = -fexp_(alog_[i*KK*DI + kdB]);
  const float Dsum = Ds_[i*KK*DI + kdF] + Ds_[i*KK*DI + kdB];
  const int l0 = t*16;
  const int s0 = LL - 16 - l0;

  float vX[16], aF[16], bF[16], aB[16], bB[16];
  float fA = 1.f, fB = 0.f, gA = 1.f, gB = 0.f;
  LD16H(vX, src + l0);

  {
    float pre[16], r0[16];
    LD16(r0, xdF + 0*LL + l0);
    #pragma unroll
    for(int j=0;j<16;++j) pre[j] = biasF + wF.x*r0[j];
    LD16(r0, xdF + 1*LL + l0);
    #pragma unroll
    for(int j=0;j<16;++j) pre[j] += wF.y*r0[j];
    LD16(r0, xdF + 2*LL + l0);
    #pragma unroll
    for(int j=0;j<16;++j) pre[j] += wF.z*r0[j];
    LD16(r0, xdF + 3*LL + l0);
    #pragma unroll
    for(int j=0;j<16;++j) pre[j] += wF.w*r0[j];
    LD16(r0, xdF + 4*LL + l0);   // Bs
    #pragma unroll
    for(int j=0;j<16;++j){
      const float delta = softplusf_(pre[j]);
      aF[j] = fexp_(delta*AvF);
      bF[j] = delta*r0[j]*vX[j];
      fB = fB*aF[j] + bF[j];
      fA *= aF[j];
    }
  }
  {
    float pre[16], r0[16];
    LD16R(r0, xdB + 0*LL + s0);
    #pragma unroll
    for(int j=0;j<16;++j) pre[j] = biasB + wB.x*r0[j];
    LD16R(r0, xdB + 1*LL + s0);
    #pragma unroll
    for(int j=0;j<16;++j) pre[j] += wB.y*r0[j];
    LD16R(r0, xdB + 2*LL + s0);
    #pragma unroll
    for(int j=0;j<16;++j) pre[j] += wB.z*r0[j];
    LD16R(r0, xdB + 3*LL + s0);
    #pragma unroll
    for(int j=0;j<16;++j) pre[j] += wB.w*r0[j];
    LD16R(r0, xdB + 4*LL + s0);  // Bs reversed
    #pragma unroll
    for(int j=15;j>=0;--j){
      const float delta = softplusf_(pre[j]);
      aB[j] = fexp_(delta*AvB);
      bB[j] = delta*r0[j]*vX[j];
      gB = gB*aB[j] + bB[j];
      gA *= aB[j];
    }
  }

  #pragma unroll
  for(int off=1; off<64; off<<=1){
    const float aL = __shfl_up(fA, off);
    const float bL = __shfl_up(fB, off);
    if(lane >= off){ fB = bL*fA + fB; fA = aL*fA; }
  }
  float pA = __shfl_up(fA, 1), pB = __shfl_up(fB, 1);
  if(lane==0){ pA=1.f; pB=0.f; }
  #pragma unroll
  for(int off=1; off<64; off<<=1){
    const float aR = __shfl_down(gA, off);
    const float bR = __shfl_down(gB, off);
    if(lane + off < 64){ gB = gA*bR + gB; gA = gA*aR; }
  }
  float qA = __shfl_down(gA, 1), qB = __shfl_down(gB, 1);
  if(lane==63){ qA=1.f; qB=0.f; }

  __shared__ float wAg[4], wBg[4], vAg[4], vBg[4];
  if(lane==63){ wAg[wv]=fA; wBg[wv]=fB; }
  if(lane==0){ vAg[wv]=gA; vBg[wv]=gB; }
  __syncthreads();
  float eB=0.f;
  for(int u=0; u<wv; ++u){ eB = wAg[u]*eB + wBg[u]; }
  float rB=0.f;
  for(int u=3; u>wv; --u){ rB = vAg[u]*rB + vBg[u]; }

  float hf = pA*eB + pB;
  float hb = qA*rB + qB;

  float out[16], cc[16];
  LD16(cc, xdF + 5*LL + l0);
  #pragma unroll
  for(int j=0;j<16;++j){
    hf = aF[j]*hf + bF[j];
    out[j] = hf*cc[j] + Dsum*vX[j];
  }
  LD16R(cc, xdB + 5*LL + s0);
  #pragma unroll
  for(int j=15;j>=0;--j){
    hb = aB[j]*hb + bB[j];
    out[j] += hb*cc[j];
  }
  float4* d4 = (float4*)(dst + l0);
  d4[0] = make_float4(out[0],out[1],out[2],out[3]);
  d4[1] = make_float4(out[4],out[5],out[6],out[7]);
  d4[2] = make_float4(out[8],out[9],out[10],out[11]);
  d4[3] = make_float4(out[12],out[13],out[14],out[15]);
}

// K3c: combine y + transpose(yT) into d-major ycombT[d][b*LL+l].
__global__ __launch_bounds__(256) void k3c_combine(float* __restrict__ ws)
{
  const int i = blockIdx.y;
  const int b = blockIdx.x >> 4;
  const int tile = blockIdx.x & 15;
  const int h0 = (tile >> 2) * 16, w0 = (tile & 3) * 16;
  const int t = threadIdx.x;
  float* base = ws + (size_t)i*ISTRIDE;
  const float* y  = base + OFF_Y;
  const float* yT = base + OFF_YT;
  float* ycT = base + OFF_YCOMBT;
  __shared__ float ytile[16*16*16];
  __shared__ float ytT[16*16*17];
  const int r0 = t >> 4, c0 = t & 15;
  const int hi = t >> 4, wi = t & 15;
  const int l = (h0 + hi)*64 + (w0 + wi);
  for(int dc=0; dc<8; ++dc){
    #pragma unroll 4
    for(int dd=0; dd<16; ++dd){
      const int d = dc*16 + dd;
      const size_t rb = (size_t)(b*DI + d)*LL;
      ytile[dd*256 + t] = y[rb + (size_t)(h0 + r0)*64 + (w0 + c0)];
      ytT[dd*272 + r0*17 + c0] = yT[rb + (size_t)(w0 + r0)*64 + (h0 + c0)];
    }
    __syncthreads();
    #pragma unroll 4
    for(int dd=0; dd<16; ++dd){
      const int d = dc*16 + dd;
      ycT[(size_t)d*LB + b*LL + l] = ytile[dd*256 + t] + ytT[dd*272 + wi*17 + hi];
    }
    __syncthreads();
  }
}

// K4a v3 (MFMA): block = 64 pixels, 4 waves; LN via padded LDS stats; out_proj
// via mfma_f32_16x16x32_bf16; +xin -> xnew.
__global__ __launch_bounds__(256) void k4a_proj(
    const float* __restrict__ xmag, const float* __restrict__ xph,
    const float* __restrict__ onw_, const float* __restrict__ onb_,
    const float* __restrict__ opw_, float* __restrict__ ws)
{
  const int i = blockIdx.y;
  const float* xin = i ? xph : xmag;
  const float* onw = onw_ + i*DI;
  const float* onb = onb_ + i*DI;
  const float* opw = opw_ + i*CC*DI;     // [o][d] = [64][128]
  float* base = ws + (size_t)i*ISTRIDE;
  const float* ycT = base + OFF_YCOMBT;
  const float* zT  = base + OFF_Z;
  const int t = threadIdx.x, lane = t & 63;
  const int wv = __builtin_amdgcn_readfirstlane(t >> 6);
  const int m = lane & 15, quad = lane >> 4;
  const int p0 = blockIdx.x*64;
  const int p = p0 + lane;

  __shared__ short ynlds[64*136];
  __shared__ short wlds[64*136];
  __shared__ float st[64][9];

  float yv[32];
  float s1=0.f, s2=0.f;
  #pragma unroll 8
  for(int c=0;c<32;++c){
    const float v = ycT[(size_t)(wv*32+c)*LB + p];
    yv[c]=v; s1+=v; s2+=v*v;
  }
  st[lane][wv*2]=s1; st[lane][wv*2+1]=s2;
  __syncthreads();
  const float S1 = st[lane][0]+st[lane][2]+st[lane][4]+st[lane][6];
  const float S2 = st[lane][1]+st[lane][3]+st[lane][5]+st[lane][7];
  const float mu = S1*(1.f/DI);
  const float rs = rsqrtf(S2*(1.f/DI) - mu*mu + EPSF);
  #pragma unroll
  for(int cq=0;cq<8;++cq){
    short4 s4;
    #pragma unroll
    for(int e=0;e<4;++e){
      const int c = cq*4+e;
      const int d = wv*32 + c;
      ((short*)&s4)[e] = bf16_(((yv[c]-mu)*rs*onw[d] + onb[d]) * zT[(size_t)d*LB + p]);
    }
    *(short4*)&ynlds[lane*136 + wv*32 + cq*4] = s4;
  }
  {
    const int ol = t >> 2, seg = (t & 3)*32;
    const float* src = opw + (size_t)ol*DI + seg;
    #pragma unroll
    for(int q=0;q<4;++q){
      const float4 fa = ((const float4*)src)[q*2];
      const float4 fb = ((const float4*)src)[q*2+1];
      v8s s;
      s[0]=bf16_(fa.x); s[1]=bf16_(fa.y); s[2]=bf16_(fa.z); s[3]=bf16_(fa.w);
      s[4]=bf16_(fb.x); s[5]=bf16_(fb.y); s[6]=bf16_(fb.z); s[7]=bf16_(fb.w);
      *(v8s*)&wlds[ol*136 + seg + q*8] = s;
    }
  }
  __syncthreads();

  v4f accs[4];
  #pragma unroll
  for(int nt=0; nt<4; ++nt){
    v4f acc = (v4f){0.f,0.f,0.f,0.f};
    #pragma unroll
    for(int ks=0; ks<4; ++ks){
      const v8s a = *(const v8s*)&ynlds[(wv*16 + m)*136 + ks*32 + quad*8];
      const v8s b = *(const v8s*)&wlds[(nt*16 + m)*136 + ks*32 + quad*8];
      acc = __builtin_amdgcn_mfma_f32_16x16x32_bf16(a, b, acc, 0, 0, 0);
    }
    accs[nt] = acc;
  }
  float* xnew = base + OFF_XNEW;
  #pragma unroll
  for(int nt=0; nt<4; ++nt){
    #pragma unroll
    for(int r=0;r<4;++r){
      const int pp = p0 + wv*16 + quad*4 + r;
      const int o = nt*16 + m;
      xnew[(size_t)pp*CC + o] = accs[nt][r] + xin[(size_t)pp*CC + o];
    }
  }
}

// K4b v7 (MFMA): 64-pixel tile per block, 4 waves. LN (fp32) -> bf16 H in LDS;
// per 128-j half: stage F1/F2 bf16, fc1 mfma 16x16x32, GELU, fc2 mfma.
__global__ __launch_bounds__(256) void k4b_mlp(
    const float* __restrict__ n2w_, const float* __restrict__ n2b_,
    const float* __restrict__ f1w_, const float* __restrict__ f1b_,
    const float* __restrict__ f2w_, const float* __restrict__ f2b_,
    float* __restrict__ ws)
{
  const int i = blockIdx.y;
  const float* n2w = n2w_ + i*CC;
  const float* n2b = n2b_ + i*CC;
  const float* f1w = f1w_ + i*256*64;    // [j][c]
  const float* f1b = f1b_ + i*256;
  const float* f2w = f2w_ + i*64*256;    // [o][j]
  const float* f2b = f2b_ + i*CC;
  float* base = ws + (size_t)i*ISTRIDE;
  const float* xnew = base + OFF_XNEW;
  const int t = threadIdx.x, lane = t & 63;
  const int wv = __builtin_amdgcn_readfirstlane(t >> 6);
  const int m = lane & 15, quad = lane >> 4;
  const int p0 = blockIdx.x*64;

  __shared__ short hlds[64*72];
  __shared__ short w1lds[128*72];
  __shared__ short glds[64*136];
  __shared__ short w2lds[64*136];

  {
    float h2[64];
    const float* xr = xnew + (size_t)(p0 + lane)*CC;
    LD16(h2, xr); LD16((h2+16), xr+16); LD16((h2+32), xr+32); LD16((h2+48), xr+48);
    float s1=0.f, s2=0.f;
    #pragma unroll
    for(int c=0;c<CC;++c){ s1 += h2[c]; s2 += h2[c]*h2[c]; }
    const float mu = s1*(1.f/CC);
    const float rs = rsqrtf(s2*(1.f/CC) - mu*mu + EPSF);
    if(wv==0){
      #pragma unroll
      for(int q=0;q<8;++q){
        v8s s;
        #pragma unroll
        for(int e=0;e<8;++e){
          const int c = q*8+e;
          s[e] = bf16_((h2[c]-mu)*rs*n2w[c] + n2b[c]);
        }
        *(v8s*)&hlds[lane*72 + q*8] = s;
      }
    }
  }

  v4f acc2[4];
  #pragma unroll
  for(int n=0;n<4;++n) acc2[n] = (v4f){0.f,0.f,0.f,0.f};

  for(int h=0; h<2; ++h){
    if(h) __syncthreads();
    {
      const int jl = t >> 1, hc = (t & 1)*32;
      const float* src = f1w + (size_t)(h*128 + jl)*64 + hc;
      #pragma unroll
      for(int q=0;q<4;++q){
        const float4 fa = ((const float4*)src)[q*2];
        const float4 fb = ((const float4*)src)[q*2+1];
        v8s s;
        s[0]=bf16_(fa.x); s[1]=bf16_(fa.y); s[2]=bf16_(fa.z); s[3]=bf16_(fa.w);
        s[4]=bf16_(fb.x); s[5]=bf16_(fb.y); s[6]=bf16_(fb.z); s[7]=bf16_(fb.w);
        *(v8s*)&w1lds[jl*72 + hc + q*8] = s;
      }
    }
    {
      const int ol = t >> 2, seg = (t & 3)*32;
      const float* src = f2w + (size_t)ol*256 + h*128 + seg;
      #pragma unroll
      for(int q=0;q<4;++q){
        const float4 fa = ((const float4*)src)[q*2];
        const float4 fb = ((const float4*)src)[q*2+1];
        v8s s;
        s[0]=bf16_(fa.x); s[1]=bf16_(fa.y); s[2]=bf16_(fa.z); s[3]=bf16_(fa.w);
        s[4]=bf16_(fb.x); s[5]=bf16_(fb.y); s[6]=bf16_(fb.z); s[7]=bf16_(fb.w);
        *(v8s*)&w2lds[ol*136 + seg + q*8] = s;
      }
    }
    __syncthreads();
    #pragma unroll 2
    for(int nt=0; nt<8; ++nt){
      v4f acc = (v4f){0.f,0.f,0.f,0.f};
      #pragma unroll
      for(int ks=0; ks<2; ++ks){
        const v8s a = *(const v8s*)&hlds[(wv*16 + m)*72 + ks*32 + quad*8];
        const v8s b = *(const v8s*)&w1lds[(nt*16 + m)*72 + ks*32 + quad*8];
        acc = __builtin_amdgcn_mfma_f32_16x16x32_bf16(a, b, acc, 0, 0, 0);
      }
      const float bj = f1b[h*128 + nt*16 + m];
      #pragma unroll
      for(int r=0;r<4;++r){
        glds[(wv*16 + quad*4 + r)*136 + nt*16 + m] = bf16_(geluf_(acc[r] + bj));
      }
    }
    #pragma unroll
    for(int nt=0; nt<4; ++nt){
      v4f acc = acc2[nt];
      #pragma unroll
      for(int ks=0; ks<4; ++ks){
        const v8s a = *(const v8s*)&glds[(wv*16 + m)*136 + ks*32 + quad*8];
        const v8s b = *(const v8s*)&w2lds[(nt*16 + m)*136 + ks*32 + quad*8];
        acc = __builtin_amdgcn_mfma_f32_16x16x32_bf16(a, b, acc, 0, 0, 0);
      }
      acc2[nt] = acc;
    }
  }

  float* sb = base + OFF_SB;
  #pragma unroll
  for(int nt=0; nt<4; ++nt){
    const float bo = f2b[nt*16 + m];
    #pragma unroll
    for(int r=0;r<4;++r){
      const int p = p0 + wv*16 + quad*4 + r;
      const int o = nt*16 + m;
      sb[(size_t)p*CC + o] = acc2[nt][r] + bo + xnew[(size_t)p*CC + o];
    }
  }
}

// K5: s = inst0 + inst1; float4-vectorized; write both output halves
__global__ __launch_bounds__(256) void k5_final(
    const float* __restrict__ ws, float* __restrict__ out)
{
  const int idx = blockIdx.x*256 + threadIdx.x;   // float4 index
  const float4 a = ((const float4*)(ws + OFF_SB))[idx];
  const float4 b = ((const float4*)(ws + ISTRIDE + OFF_SB))[idx];
  const float4 v = make_float4(a.x+b.x, a.y+b.y, a.z+b.z, a.w+b.w);
  ((float4*)out)[idx] = v;
  ((float4*)out)[NPIX/4 + idx] = v;
}

extern "C" void kernel_launch(void* const* d_in, const int* in_sizes, int n_in,
                              void* d_out, int out_size, void* d_ws, size_t ws_size,
                              hipStream_t stream)
{
  const float* mag  = (const float*)d_in[0];
  const float* ph   = (const float*)d_in[1];
  const float* n1w  = (const float*)d_in[2];
  const float* n1b  = (const float*)d_in[3];
  const float* ipw  = (const float*)d_in[4];
  const float* cw   = (const float*)d_in[5];
  const float* xpw  = (const float*)d_in[6];
  const float* dtw  = (const float*)d_in[7];
  const float* dtb  = (const float*)d_in[8];
  const float* alog = (const float*)d_in[9];
  const float* Ds   = (const float*)d_in[10];
  const float* onw  = (const float*)d_in[11];
  const float* onb  = (const float*)d_in[12];
  const float* opw  = (const float*)d_in[13];
  const float* n2w  = (const float*)d_in[14];
  const float* n2b  = (const float*)d_in[15];
  const float* f1w  = (const float*)d_in[16];
  const float* f1b  = (const float*)d_in[17];
  const float* f2w  = (const float*)d_in[18];
  const float* f2b  = (const float*)d_in[19];
  float* ws = (float*)d_ws;
  float* out = (float*)d_out;

  k1_ln_inproj<<<dim3(512,2),  256, 0, stream>>>(mag, ph, n1w, n1b, ipw, ws);
  k2_dwconv   <<<dim3(1024,2), 256, 0, stream>>>(cw, ws);
  k3a_xproj   <<<dim3(16,16,2),256, 0, stream>>>(xpw, ws);
  k3b_scan    <<<dim3(2048,2), 256, 0, stream>>>(dtw, dtb, alog, Ds, ws);
  k3c_combine <<<dim3(128,2),  256, 0, stream>>>(ws);
  k4a_proj    <<<dim3(512,2),  256, 0, stream>>>(mag, ph, onw, onb, opw, ws);
  k4b_mlp     <<<dim3(512,2),  256, 0, stream>>>(n2w, n2b, f1w, f1b, f2w, f2b, ws);
  k5_final    <<<dim3(2048),   256, 0, stream>>>(ws, out);
}

// Round 18
// 314.257 us; speedup vs baseline: 2.8404x; 1.1296x over previous
//
#include <hip/hip_runtime.h>
#include <math.h>

// Problem constants
#define LL   4096      // H*W
#define DI   128       // 2*C
#define CC   64        // C
#define BB   8         // batch
#define KK   4         // scan directions
#define LB   32768     // pixels per instance
#define NPIX 2097152   // B*H*W*C elements of s
#define EPSF 1e-5f

// Workspace layout (floats, per instance). XCONV/XCONVT/XDBL and Y/YT regions
// hold bf16 (half-occupied; float offsets unchanged).
#define OFF_XCIN   ((size_t)0)
#define OFF_XCONV  ((size_t)4194304)
#define OFF_XCONVT ((size_t)8388608)
#define OFF_Z      ((size_t)12582912)
#define OFF_Y      ((size_t)16777216)
#define OFF_YT     ((size_t)20971520)
#define OFF_XDBL   ((size_t)25165824)
#define ISTRIDE    ((size_t)25952256)   // floats per instance
// Aliases (lifetime-disjoint reuse):
#define OFF_YCOMBT OFF_XCIN             // xcin dead after k2; ycombT (d-major) by k3c
#define OFF_XNEW   OFF_YT               // yT dead after k3c; xnew (pixel-major) by k4a
#define OFF_SB     OFF_Y                // y dead after k3c; sbuf by k4b

typedef short v8s __attribute__((ext_vector_type(8)));
typedef float v4f __attribute__((ext_vector_type(4)));

// Fast transcendentals: native v_exp/v_log paths (error ~1e-7, threshold 0.144)
__device__ __forceinline__ float fexp_(float x){ return __expf(x); }
__device__ __forceinline__ float silu_(float x){ return __fdividef(x, 1.f+__expf(-x)); }
__device__ __forceinline__ float softplusf_(float x){
  return fmaxf(x,0.f) + __logf(1.f + __expf(-fabsf(x)));
}
__device__ __forceinline__ float geluf_(float x){ return 0.5f*x*(1.f+erff(x*0.70710678118f)); }
__device__ __forceinline__ short bf16_(float x){
  unsigned u = __float_as_uint(x);
  u += 0x7FFF + ((u>>16)&1);     // RNE
  return (short)(u>>16);
}
__device__ __forceinline__ float bf2f_(short s){
  return __uint_as_float(((unsigned)(unsigned short)s)<<16);
}

#define LD16(dst, ptr) { const float4* p4_=(const float4*)(ptr);                 \
  float4 v0_=p4_[0], v1_=p4_[1], v2_=p4_[2], v3_=p4_[3];                         \
  dst[0]=v0_.x; dst[1]=v0_.y; dst[2]=v0_.z; dst[3]=v0_.w;                        \
  dst[4]=v1_.x; dst[5]=v1_.y; dst[6]=v1_.z; dst[7]=v1_.w;                        \
  dst[8]=v2_.x; dst[9]=v2_.y; dst[10]=v2_.z; dst[11]=v2_.w;                      \
  dst[12]=v3_.x; dst[13]=v3_.y; dst[14]=v3_.z; dst[15]=v3_.w; }
// 16 bf16 (32B) -> 16 floats
#define LD16H(dst, ptr) { const v8s* p8_=(const v8s*)(ptr);                      \
  v8s a0_=p8_[0], a1_=p8_[1];                                                    \
  _Pragma("unroll") for(int e_=0;e_<8;++e_){ dst[e_]=bf2f_(a0_[e_]);             \
                                             dst[8+e_]=bf2f_(a1_[e_]); } }
// 16 bf16 reversed: dst[15-m] = ptr[m]
#define LD16HR(dst, ptr) { const v8s* p8_=(const v8s*)(ptr);                     \
  v8s a0_=p8_[0], a1_=p8_[1];                                                    \
  _Pragma("unroll") for(int e_=0;e_<8;++e_){ dst[15-e_]=bf2f_(a0_[e_]);          \
                                             dst[7-e_]=bf2f_(a1_[e_]); } }

// K1 v5 (MFMA): block = 64 pixels, 4 waves. LN (fp32) -> bf16 hlds; per 128-row
// half of ipw: stage w1lds, 8 n-tiles x 2 k-steps mfma, outs -> coalesced stores.
__global__ __launch_bounds__(256) void k1_ln_inproj(
    const float* __restrict__ xmag, const float* __restrict__ xph,
    const float* __restrict__ n1w_, const float* __restrict__ n1b_,
    const float* __restrict__ ipw_, float* __restrict__ ws)
{
  const int i = blockIdx.y;
  const float* xin = i ? xph : xmag;
  const float* n1w = n1w_ + i*CC;
  const float* n1b = n1b_ + i*CC;
  const float* ipw = ipw_ + i*2*DI*CC;   // [256][64]
  float* base = ws + (size_t)i*ISTRIDE;
  const int t = threadIdx.x, lane = t & 63;
  const int wv = __builtin_amdgcn_readfirstlane(t >> 6);
  const int m = lane & 15, quad = lane >> 4;
  const int p0 = blockIdx.x*64;
  const int b = p0 >> 12, l0 = p0 & (LL-1);

  __shared__ short hlds[64*72];
  __shared__ short w1lds[128*72];
  __shared__ float outs[128*68];

  {
    float hn[CC];
    const float* xr = xin + (size_t)(p0 + lane)*CC;
    LD16(hn, xr); LD16((hn+16), xr+16); LD16((hn+32), xr+32); LD16((hn+48), xr+48);
    float s1=0.f, s2=0.f;
    #pragma unroll
    for(int c=0;c<CC;++c){ s1 += hn[c]; s2 += hn[c]*hn[c]; }
    const float mu = s1*(1.f/CC);
    const float rs = rsqrtf(s2*(1.f/CC) - mu*mu + EPSF);
    if(wv==0){
      #pragma unroll
      for(int q=0;q<8;++q){
        v8s s;
        #pragma unroll
        for(int e=0;e<8;++e){
          const int c = q*8+e;
          s[e] = bf16_((hn[c]-mu)*rs*n1w[c] + n1b[c]);
        }
        *(v8s*)&hlds[lane*72 + q*8] = s;
      }
    }
  }

  for(int h=0; h<2; ++h){
    if(h) __syncthreads();
    {
      const int jl = t >> 1, hc = (t & 1)*32;
      const float* src = ipw + (size_t)(h*128 + jl)*64 + hc;
      #pragma unroll
      for(int q=0;q<4;++q){
        const float4 fa = ((const float4*)src)[q*2];
        const float4 fb = ((const float4*)src)[q*2+1];
        v8s s;
        s[0]=bf16_(fa.x); s[1]=bf16_(fa.y); s[2]=bf16_(fa.z); s[3]=bf16_(fa.w);
        s[4]=bf16_(fb.x); s[5]=bf16_(fb.y); s[6]=bf16_(fb.z); s[7]=bf16_(fb.w);
        *(v8s*)&w1lds[jl*72 + hc + q*8] = s;
      }
    }
    __syncthreads();
    #pragma unroll 2
    for(int nt=0; nt<8; ++nt){
      v4f acc = (v4f){0.f,0.f,0.f,0.f};
      #pragma unroll
      for(int ks=0; ks<2; ++ks){
        const v8s a = *(const v8s*)&hlds[(wv*16 + m)*72 + ks*32 + quad*8];
        const v8s bb = *(const v8s*)&w1lds[(nt*16 + m)*72 + ks*32 + quad*8];
        acc = __builtin_amdgcn_mfma_f32_16x16x32_bf16(a, bb, acc, 0, 0, 0);
      }
      *(float4*)&outs[(nt*16 + m)*68 + wv*16 + quad*4] =
          make_float4(acc[0], acc[1], acc[2], acc[3]);
    }
    __syncthreads();
    const int jl = t >> 1, hc = (t & 1)*32;
    if(h==0){
      float* xcb = base + OFF_XCIN + (size_t)b*DI*LL + (size_t)jl*LL + l0 + hc;
      #pragma unroll
      for(int q=0;q<8;++q)
        ((float4*)xcb)[q] = *(const float4*)&outs[jl*68 + hc + q*4];
    } else {
      float* zr = base + OFF_Z + (size_t)jl*LB + p0 + hc;
      #pragma unroll
      for(int q=0;q<8;++q){
        const float4 v = *(const float4*)&outs[jl*68 + hc + q*4];
        ((float4*)zr)[q] = make_float4(silu_(v.x), silu_(v.y), silu_(v.z), silu_(v.w));
      }
    }
  }
}

// K2: depthwise 3x3 conv + silu; per (b,d) 64x64 tile via LDS; outputs bf16.
__global__ __launch_bounds__(256) void k2_dwconv(
    const float* __restrict__ cw_, float* __restrict__ ws)
{
  const int i = blockIdx.y;
  const int bd = blockIdx.x;
  const int d = bd & (DI-1);
  const float* cw = cw_ + i*DI*9 + d*9;
  const float* xcin  = ws + (size_t)i*ISTRIDE + OFF_XCIN + (size_t)bd*LL;
  short* xconv  = (short*)(ws + (size_t)i*ISTRIDE + OFF_XCONV ) + (size_t)bd*LL;
  short* xconvT = (short*)(ws + (size_t)i*ISTRIDE + OFF_XCONVT) + (size_t)bd*LL;
  __shared__ float tin[64*65];
  __shared__ float tout[64*65];
  const int t = threadIdx.x;
  float w9[9];
  #pragma unroll
  for(int q=0;q<9;++q) w9[q] = cw[q];
  for(int idx=t; idx<4096; idx+=256)
    tin[(idx>>6)*65 + (idx&63)] = xcin[idx];
  __syncthreads();
  const int w = t & 63, hb = (t>>6)*16;
  #pragma unroll
  for(int r=0;r<16;++r){
    const int h = hb + r;
    float acc = 0.f;
    #pragma unroll
    for(int dy=0;dy<3;++dy){
      const int hh = h + dy - 1;
      if(hh>=0 && hh<64){
        #pragma unroll
        for(int dx=0;dx<3;++dx){
          const int ww = w + dx - 1;
          if(ww>=0 && ww<64) acc += tin[hh*65+ww]*w9[dy*3+dx];
        }
      }
    }
    const float o = silu_(acc);
    tout[h*65+w] = o;
    xconv[h*64+w] = bf16_(o);
  }
  __syncthreads();
  const int hcol = t & 63, wb = (t>>6)*16;
  #pragma unroll
  for(int r=0;r<16;++r){
    const int wp = wb + r;
    xconvT[wp*64 + hcol] = bf16_(tout[hcol*65 + wp]);
  }
}

// K3a v2: paired-direction x_proj from bf16 src; xdbl stored bf16.
__global__ __launch_bounds__(256) void k3a_xproj(
    const float* __restrict__ xpw_, float* __restrict__ ws)
{
  const int i = blockIdx.z;
  const int b = blockIdx.y >> 1;
  const int kp = blockIdx.y & 1;
  const int l = blockIdx.x*256 + threadIdx.x;   // source index
  const short* src = (const short*)(ws + (size_t)i*ISTRIDE + (kp? OFF_XCONVT : OFF_XCONV))
                     + (size_t)b*DI*LL;
  const float* xpwF = xpw_ + i*KK*6*DI + kp*6*DI;
  const float* xpwB = xpw_ + i*KK*6*DI + (kp+2)*6*DI;
  float accF[6] = {0,0,0,0,0,0};
  float accB[6] = {0,0,0,0,0,0};
  for(int d=0; d<DI; ++d){
    const float xv = bf2f_(src[(size_t)d*LL + l]);
    #pragma unroll
    for(int c=0;c<6;++c){
      accF[c] += xv * xpwF[c*DI + d];
      accB[c] += xv * xpwB[c*DI + d];
    }
  }
  short* xdF = (short*)(ws + (size_t)i*ISTRIDE + OFF_XDBL) + (size_t)(b*KK+kp  )*6*LL;
  short* xdB = (short*)(ws + (size_t)i*ISTRIDE + OFF_XDBL) + (size_t)(b*KK+kp+2)*6*LL;
  #pragma unroll
  for(int c=0;c<6;++c) xdF[(size_t)c*LL + l] = bf16_(accF[c]);
  #pragma unroll
  for(int c=0;c<6;++c) xdB[(size_t)c*LL + (LL-1-l)] = bf16_(accB[c]);
}

// K3b: paired fwd/bwd scan (all streams bf16; scan state fp32); wave shuffle
// scan, 1 barrier. (256,3).
__global__ __launch_bounds__(256,3) void k3b_scan(
    const float* __restrict__ dtw_, const float* __restrict__ dtb_,
    const float* __restrict__ alog_, const float* __restrict__ Ds_,
    float* __restrict__ ws)
{
  const int gid = blockIdx.x;           // b*256 + kp*128 + d
  const int i = blockIdx.y;
  const int d  = gid & (DI-1);
  const int kp = (gid >> 7) & 1;
  const int b  = gid >> 8;
  const int t = threadIdx.x, lane = t & 63, wv = t >> 6;
  float* base = ws + (size_t)i*ISTRIDE;
  const short* src = (const short*)(base + (kp? OFF_XCONVT : OFF_XCONV)) + (size_t)(b*DI+d)*LL;
  short*       dst = (short*)(base + (kp? OFF_YT : OFF_Y)) + (size_t)(b*DI+d)*LL;
  const short* xdF = (const short*)(base + OFF_XDBL) + (size_t)(b*KK+kp  )*6*LL;
  const short* xdB = (const short*)(base + OFF_XDBL) + (size_t)(b*KK+kp+2)*6*LL;
  const int kdF = kp*DI + d, kdB = (kp+2)*DI + d;
  const float4 wF = ((const float4*)dtw_)[i*KK*DI + kdF];
  const float4 wB = ((const float4*)dtw_)[i*KK*DI + kdB];
  const float biasF = dtb_[i*KK*DI + kdF], biasB = dtb_[i*KK*DI + kdB];
  const float AvF = -fexp_(alog_[i*KK*DI + kdF]);
  const float AvB = -fexp_(alog_[i*KK*DI + kdB]);
  const float Dsum = Ds_[i*KK*DI + kdF] + Ds_[i*KK*DI + kdB];
  const int l0 = t*16;
  const int s0 = LL - 16 - l0;

  float vX[16], aF[16], bF[16], aB[16], bB[16];
  float fA = 1.f, fB = 0.f, gA = 1.f, gB = 0.f;
  LD16H(vX, src + l0);

  {
    float pre[16], r0[16];
    LD16H(r0, xdF + 0*LL + l0);
    #pragma unroll
    for(int j=0;j<16;++j) pre[j] = biasF + wF.x*r0[j];
    LD16H(r0, xdF + 1*LL + l0);
    #pragma unroll
    for(int j=0;j<16;++j) pre[j] += wF.y*r0[j];
    LD16H(r0, xdF + 2*LL + l0);
    #pragma unroll
    for(int j=0;j<16;++j) pre[j] += wF.z*r0[j];
    LD16H(r0, xdF + 3*LL + l0);
    #pragma unroll
    for(int j=0;j<16;++j) pre[j] += wF.w*r0[j];
    LD16H(r0, xdF + 4*LL + l0);   // Bs
    #pragma unroll
    for(int j=0;j<16;++j){
      const float delta = softplusf_(pre[j]);
      aF[j] = fexp_(delta*AvF);
      bF[j] = delta*r0[j]*vX[j];
      fB = fB*aF[j] + bF[j];
      fA *= aF[j];
    }
  }
  {
    float pre[16], r0[16];
    LD16HR(r0, xdB + 0*LL + s0);
    #pragma unroll
    for(int j=0;j<16;++j) pre[j] = biasB + wB.x*r0[j];
    LD16HR(r0, xdB + 1*LL + s0);
    #pragma unroll
    for(int j=0;j<16;++j) pre[j] += wB.y*r0[j];
    LD16HR(r0, xdB + 2*LL + s0);
    #pragma unroll
    for(int j=0;j<16;++j) pre[j] += wB.z*r0[j];
    LD16HR(r0, xdB + 3*LL + s0);
    #pragma unroll
    for(int j=0;j<16;++j) pre[j] += wB.w*r0[j];
    LD16HR(r0, xdB + 4*LL + s0);  // Bs reversed
    #pragma unroll
    for(int j=15;j>=0;--j){
      const float delta = softplusf_(pre[j]);
      aB[j] = fexp_(delta*AvB);
      bB[j] = delta*r0[j]*vX[j];
      gB = gB*aB[j] + bB[j];
      gA *= aB[j];
    }
  }

  #pragma unroll
  for(int off=1; off<64; off<<=1){
    const float aL = __shfl_up(fA, off);
    const float bL = __shfl_up(fB, off);
    if(lane >= off){ fB = bL*fA + fB; fA = aL*fA; }
  }
  float pA = __shfl_up(fA, 1), pB = __shfl_up(fB, 1);
  if(lane==0){ pA=1.f; pB=0.f; }
  #pragma unroll
  for(int off=1; off<64; off<<=1){
    const float aR = __shfl_down(gA, off);
    const float bR = __shfl_down(gB, off);
    if(lane + off < 64){ gB = gA*bR + gB; gA = gA*aR; }
  }
  float qA = __shfl_down(gA, 1), qB = __shfl_down(gB, 1);
  if(lane==63){ qA=1.f; qB=0.f; }

  __shared__ float wAg[4], wBg[4], vAg[4], vBg[4];
  if(lane==63){ wAg[wv]=fA; wBg[wv]=fB; }
  if(lane==0){ vAg[wv]=gA; vBg[wv]=gB; }
  __syncthreads();
  float eB=0.f;
  for(int u=0; u<wv; ++u){ eB = wAg[u]*eB + wBg[u]; }
  float rB=0.f;
  for(int u=3; u>wv; --u){ rB = vAg[u]*rB + vBg[u]; }

  float hf = pA*eB + pB;
  float hb = qA*rB + qB;

  float out[16], cc[16];
  LD16H(cc, xdF + 5*LL + l0);
  #pragma unroll
  for(int j=0;j<16;++j){
    hf = aF[j]*hf + bF[j];
    out[j] = hf*cc[j] + Dsum*vX[j];
  }
  LD16HR(cc, xdB + 5*LL + s0);
  #pragma unroll
  for(int j=15;j>=0;--j){
    hb = aB[j]*hb + bB[j];
    out[j] += hb*cc[j];
  }
  v8s o0, o1;
  #pragma unroll
  for(int e=0;e<8;++e){ o0[e]=bf16_(out[e]); o1[e]=bf16_(out[8+e]); }
  ((v8s*)(dst + l0))[0] = o0;
  ((v8s*)(dst + l0))[1] = o1;
}

// K3c: combine y + transpose(yT) (bf16 in) into d-major fp32 ycombT[d][b*LL+l].
__global__ __launch_bounds__(256) void k3c_combine(float* __restrict__ ws)
{
  const int i = blockIdx.y;
  const int b = blockIdx.x >> 4;
  const int tile = blockIdx.x & 15;
  const int h0 = (tile >> 2) * 16, w0 = (tile & 3) * 16;
  const int t = threadIdx.x;
  float* base = ws + (size_t)i*ISTRIDE;
  const short* y  = (const short*)(base + OFF_Y);
  const short* yT = (const short*)(base + OFF_YT);
  float* ycT = base + OFF_YCOMBT;
  __shared__ float ytile[16*16*16];
  __shared__ float ytT[16*16*17];
  const int r0 = t >> 4, c0 = t & 15;
  const int hi = t >> 4, wi = t & 15;
  const int l = (h0 + hi)*64 + (w0 + wi);
  for(int dc=0; dc<8; ++dc){
    #pragma unroll 4
    for(int dd=0; dd<16; ++dd){
      const int d = dc*16 + dd;
      const size_t rb = (size_t)(b*DI + d)*LL;
      ytile[dd*256 + t] = bf2f_(y[rb + (size_t)(h0 + r0)*64 + (w0 + c0)]);
      ytT[dd*272 + r0*17 + c0] = bf2f_(yT[rb + (size_t)(w0 + r0)*64 + (h0 + c0)]);
    }
    __syncthreads();
    #pragma unroll 4
    for(int dd=0; dd<16; ++dd){
      const int d = dc*16 + dd;
      ycT[(size_t)d*LB + b*LL + l] = ytile[dd*256 + t] + ytT[dd*272 + wi*17 + hi];
    }
    __syncthreads();
  }
}

// K4a v3 (MFMA): block = 64 pixels, 4 waves; LN via padded LDS stats; out_proj
// via mfma_f32_16x16x32_bf16; +xin -> xnew.
__global__ __launch_bounds__(256) void k4a_proj(
    const float* __restrict__ xmag, const float* __restrict__ xph,
    const float* __restrict__ onw_, const float* __restrict__ onb_,
    const float* __restrict__ opw_, float* __restrict__ ws)
{
  const int i = blockIdx.y;
  const float* xin = i ? xph : xmag;
  const float* onw = onw_ + i*DI;
  const float* onb = onb_ + i*DI;
  const float* opw = opw_ + i*CC*DI;     // [o][d] = [64][128]
  float* base = ws + (size_t)i*ISTRIDE;
  const float* ycT = base + OFF_YCOMBT;
  const float* zT  = base + OFF_Z;
  const int t = threadIdx.x, lane = t & 63;
  const int wv = __builtin_amdgcn_readfirstlane(t >> 6);
  const int m = lane & 15, quad = lane >> 4;
  const int p0 = blockIdx.x*64;
  const int p = p0 + lane;

  __shared__ short ynlds[64*136];
  __shared__ short wlds[64*136];
  __shared__ float st[64][9];

  float yv[32];
  float s1=0.f, s2=0.f;
  #pragma unroll 8
  for(int c=0;c<32;++c){
    const float v = ycT[(size_t)(wv*32+c)*LB + p];
    yv[c]=v; s1+=v; s2+=v*v;
  }
  st[lane][wv*2]=s1; st[lane][wv*2+1]=s2;
  __syncthreads();
  const float S1 = st[lane][0]+st[lane][2]+st[lane][4]+st[lane][6];
  const float S2 = st[lane][1]+st[lane][3]+st[lane][5]+st[lane][7];
  const float mu = S1*(1.f/DI);
  const float rs = rsqrtf(S2*(1.f/DI) - mu*mu + EPSF);
  #pragma unroll
  for(int cq=0;cq<8;++cq){
    short4 s4;
    #pragma unroll
    for(int e=0;e<4;++e){
      const int c = cq*4+e;
      const int d = wv*32 + c;
      ((short*)&s4)[e] = bf16_(((yv[c]-mu)*rs*onw[d] + onb[d]) * zT[(size_t)d*LB + p]);
    }
    *(short4*)&ynlds[lane*136 + wv*32 + cq*4] = s4;
  }
  {
    const int ol = t >> 2, seg = (t & 3)*32;
    const float* src = opw + (size_t)ol*DI + seg;
    #pragma unroll
    for(int q=0;q<4;++q){
      const float4 fa = ((const float4*)src)[q*2];
      const float4 fb = ((const float4*)src)[q*2+1];
      v8s s;
      s[0]=bf16_(fa.x); s[1]=bf16_(fa.y); s[2]=bf16_(fa.z); s[3]=bf16_(fa.w);
      s[4]=bf16_(fb.x); s[5]=bf16_(fb.y); s[6]=bf16_(fb.z); s[7]=bf16_(fb.w);
      *(v8s*)&wlds[ol*136 + seg + q*8] = s;
    }
  }
  __syncthreads();

  v4f accs[4];
  #pragma unroll
  for(int nt=0; nt<4; ++nt){
    v4f acc = (v4f){0.f,0.f,0.f,0.f};
    #pragma unroll
    for(int ks=0; ks<4; ++ks){
      const v8s a = *(const v8s*)&ynlds[(wv*16 + m)*136 + ks*32 + quad*8];
      const v8s b = *(const v8s*)&wlds[(nt*16 + m)*136 + ks*32 + quad*8];
      acc = __builtin_amdgcn_mfma_f32_16x16x32_bf16(a, b, acc, 0, 0, 0);
    }
    accs[nt] = acc;
  }
  float* xnew = base + OFF_XNEW;
  #pragma unroll
  for(int nt=0; nt<4; ++nt){
    #pragma unroll
    for(int r=0;r<4;++r){
      const int pp = p0 + wv*16 + quad*4 + r;
      const int o = nt*16 + m;
      xnew[(size_t)pp*CC + o] = accs[nt][r] + xin[(size_t)pp*CC + o];
    }
  }
}

// K4b v7 (MFMA): 64-pixel tile per block, 4 waves. LN (fp32) -> bf16 H in LDS;
// per 128-j half: stage F1/F2 bf16, fc1 mfma 16x16x32, GELU, fc2 mfma.
__global__ __launch_bounds__(256) void k4b_mlp(
    const float* __restrict__ n2w_, const float* __restrict__ n2b_,
    const float* __restrict__ f1w_, const float* __restrict__ f1b_,
    const float* __restrict__ f2w_, const float* __restrict__ f2b_,
    float* __restrict__ ws)
{
  const int i = blockIdx.y;
  const float* n2w = n2w_ + i*CC;
  const float* n2b = n2b_ + i*CC;
  const float* f1w = f1w_ + i*256*64;    // [j][c]
  const float* f1b = f1b_ + i*256;
  const float* f2w = f2w_ + i*64*256;    // [o][j]
  const float* f2b = f2b_ + i*CC;
  float* base = ws + (size_t)i*ISTRIDE;
  const float* xnew = base + OFF_XNEW;
  const int t = threadIdx.x, lane = t & 63;
  const int wv = __builtin_amdgcn_readfirstlane(t >> 6);
  const int m = lane & 15, quad = lane >> 4;
  const int p0 = blockIdx.x*64;

  __shared__ short hlds[64*72];
  __shared__ short w1lds[128*72];
  __shared__ short glds[64*136];
  __shared__ short w2lds[64*136];

  {
    float h2[64];
    const float* xr = xnew + (size_t)(p0 + lane)*CC;
    LD16(h2, xr); LD16((h2+16), xr+16); LD16((h2+32), xr+32); LD16((h2+48), xr+48);
    float s1=0.f, s2=0.f;
    #pragma unroll
    for(int c=0;c<CC;++c){ s1 += h2[c]; s2 += h2[c]*h2[c]; }
    const float mu = s1*(1.f/CC);
    const float rs = rsqrtf(s2*(1.f/CC) - mu*mu + EPSF);
    if(wv==0){
      #pragma unroll
      for(int q=0;q<8;++q){
        v8s s;
        #pragma unroll
        for(int e=0;e<8;++e){
          const int c = q*8+e;
          s[e] = bf16_((h2[c]-mu)*rs*n2w[c] + n2b[c]);
        }
        *(v8s*)&hlds[lane*72 + q*8] = s;
      }
    }
  }

  v4f acc2[4];
  #pragma unroll
  for(int n=0;n<4;++n) acc2[n] = (v4f){0.f,0.f,0.f,0.f};

  for(int h=0; h<2; ++h){
    if(h) __syncthreads();
    {
      const int jl = t >> 1, hc = (t & 1)*32;
      const float* src = f1w + (size_t)(h*128 + jl)*64 + hc;
      #pragma unroll
      for(int q=0;q<4;++q){
        const float4 fa = ((const float4*)src)[q*2];
        const float4 fb = ((const float4*)src)[q*2+1];
        v8s s;
        s[0]=bf16_(fa.x); s[1]=bf16_(fa.y); s[2]=bf16_(fa.z); s[3]=bf16_(fa.w);
        s[4]=bf16_(fb.x); s[5]=bf16_(fb.y); s[6]=bf16_(fb.z); s[7]=bf16_(fb.w);
        *(v8s*)&w1lds[jl*72 + hc + q*8] = s;
      }
    }
    {
      const int ol = t >> 2, seg = (t & 3)*32;
      const float* src = f2w + (size_t)ol*256 + h*128 + seg;
      #pragma unroll
      for(int q=0;q<4;++q){
        const float4 fa = ((const float4*)src)[q*2];
        const float4 fb = ((const float4*)src)[q*2+1];
        v8s s;
        s[0]=bf16_(fa.x); s[1]=bf16_(fa.y); s[2]=bf16_(fa.z); s[3]=bf16_(fa.w);
        s[4]=bf16_(fb.x); s[5]=bf16_(fb.y); s[6]=bf16_(fb.z); s[7]=bf16_(fb.w);
        *(v8s*)&w2lds[ol*136 + seg + q*8] = s;
      }
    }
    __syncthreads();
    #pragma unroll 2
    for(int nt=0; nt<8; ++nt){
      v4f acc = (v4f){0.f,0.f,0.f,0.f};
      #pragma unroll
      for(int ks=0; ks<2; ++ks){
        const v8s a = *(const v8s*)&hlds[(wv*16 + m)*72 + ks*32 + quad*8];
        const v8s b = *(const v8s*)&w1lds[(nt*16 + m)*72 + ks*32 + quad*8];
        acc = __builtin_amdgcn_mfma_f32_16x16x32_bf16(a, b, acc, 0, 0, 0);
      }
      const float bj = f1b[h*128 + nt*16 + m];
      #pragma unroll
      for(int r=0;r<4;++r){
        glds[(wv*16 + quad*4 + r)*136 + nt*16 + m] = bf16_(geluf_(acc[r] + bj));
      }
    }
    #pragma unroll
    for(int nt=0; nt<4; ++nt){
      v4f acc = acc2[nt];
      #pragma unroll
      for(int ks=0; ks<4; ++ks){
        const v8s a = *(const v8s*)&glds[(wv*16 + m)*136 + ks*32 + quad*8];
        const v8s b = *(const v8s*)&w2lds[(nt*16 + m)*136 + ks*32 + quad*8];
        acc = __builtin_amdgcn_mfma_f32_16x16x32_bf16(a, b, acc, 0, 0, 0);
      }
      acc2[nt] = acc;
    }
  }

  float* sb = base + OFF_SB;
  #pragma unroll
  for(int nt=0; nt<4; ++nt){
    const float bo = f2b[nt*16 + m];
    #pragma unroll
    for(int r=0;r<4;++r){
      const int p = p0 + wv*16 + quad*4 + r;
      const int o = nt*16 + m;
      sb[(size_t)p*CC + o] = acc2[nt][r] + bo + xnew[(size_t)p*CC + o];
    }
  }
}

// K5: s = inst0 + inst1; float4-vectorized; write both output halves
__global__ __launch_bounds__(256) void k5_final(
    const float* __restrict__ ws, float* __restrict__ out)
{
  const int idx = blockIdx.x*256 + threadIdx.x;   // float4 index
  const float4 a = ((const float4*)(ws + OFF_SB))[idx];
  const float4 b = ((const float4*)(ws + ISTRIDE + OFF_SB))[idx];
  const float4 v = make_float4(a.x+b.x, a.y+b.y, a.z+b.z, a.w+b.w);
  ((float4*)out)[idx] = v;
  ((float4*)out)[NPIX/4 + idx] = v;
}

extern "C" void kernel_launch(void* const* d_in, const int* in_sizes, int n_in,
                              void* d_out, int out_size, void* d_ws, size_t ws_size,
                              hipStream_t stream)
{
  const float* mag  = (const float*)d_in[0];
  const float* ph   = (const float*)d_in[1];
  const float* n1w  = (const float*)d_in[2];
  const float* n1b  = (const float*)d_in[3];
  const float* ipw  = (const float*)d_in[4];
  const float* cw   = (const float*)d_in[5];
  const float* xpw  = (const float*)d_in[6];
  const float* dtw  = (const float*)d_in[7];
  const float* dtb  = (const float*)d_in[8];
  const float* alog = (const float*)d_in[9];
  const float* Ds   = (const float*)d_in[10];
  const float* onw  = (const float*)d_in[11];
  const float* onb  = (const float*)d_in[12];
  const float* opw  = (const float*)d_in[13];
  const float* n2w  = (const float*)d_in[14];
  const float* n2b  = (const float*)d_in[15];
  const float* f1w  = (const float*)d_in[16];
  const float* f1b  = (const float*)d_in[17];
  const float* f2w  = (const float*)d_in[18];
  const float* f2b  = (const float*)d_in[19];
  float* ws = (float*)d_ws;
  float* out = (float*)d_out;

  k1_ln_inproj<<<dim3(512,2),  256, 0, stream>>>(mag, ph, n1w, n1b, ipw, ws);
  k2_dwconv   <<<dim3(1024,2), 256, 0, stream>>>(cw, ws);
  k3a_xproj   <<<dim3(16,16,2),256, 0, stream>>>(xpw, ws);
  k3b_scan    <<<dim3(2048,2), 256, 0, stream>>>(dtw, dtb, alog, Ds, ws);
  k3c_combine <<<dim3(128,2),  256, 0, stream>>>(ws);
  k4a_proj    <<<dim3(512,2),  256, 0, stream>>>(mag, ph, onw, onb, opw, ws);
  k4b_mlp     <<<dim3(512,2),  256, 0, stream>>>(n2w, n2b, f1w, f1b, f2w, f2b, ws);
  k5_final    <<<dim3(2048),   256, 0, stream>>>(ws, out);
}

// Round 19
// 299.431 us; speedup vs baseline: 2.9810x; 1.0495x over previous
//
#include <hip/hip_runtime.h>
#include <math.h>

// Problem constants
#define LL   4096      // H*W
#define DI   128       // 2*C
#define CC   64        // C
#define BB   8         // batch
#define KK   4         // scan directions
#define LB   32768     // pixels per instance
#define NPIX 2097152   // B*H*W*C elements of s
#define EPSF 1e-5f

// Workspace layout (float-indexed offsets; most regions hold bf16 now).
#define OFF_XCIN   ((size_t)0)
#define OFF_XCONV  ((size_t)4194304)
#define OFF_XCONVT ((size_t)8388608)
#define OFF_Z      ((size_t)12582912)
#define OFF_Y      ((size_t)16777216)
#define OFF_YT     ((size_t)20971520)
#define OFF_XDBL   ((size_t)25165824)
#define ISTRIDE    ((size_t)25952256)   // floats per instance
// Aliases (lifetime-disjoint reuse):
#define OFF_YCOMBT OFF_XCIN             // xcin dead after k2; ycombT (d-major) by k3c
#define OFF_XNEW   OFF_YT               // yT dead after k3c; xnew (pixel-major) by k4a
#define OFF_SB     OFF_Y                // y dead after k3c; sbuf by k4b

typedef short v8s __attribute__((ext_vector_type(8)));
typedef float v4f __attribute__((ext_vector_type(4)));

__device__ __forceinline__ float fexp_(float x){ return __expf(x); }
__device__ __forceinline__ float silu_(float x){ return __fdividef(x, 1.f+__expf(-x)); }
__device__ __forceinline__ float softplusf_(float x){
  return fmaxf(x,0.f) + __logf(1.f + __expf(-fabsf(x)));
}
__device__ __forceinline__ float geluf_(float x){ return 0.5f*x*(1.f+erff(x*0.70710678118f)); }
__device__ __forceinline__ short bf16_(float x){
  unsigned u = __float_as_uint(x);
  u += 0x7FFF + ((u>>16)&1);     // RNE
  return (short)(u>>16);
}
__device__ __forceinline__ float bf2f_(short s){
  return __uint_as_float(((unsigned)(unsigned short)s)<<16);
}

#define LD16(dst, ptr) { const float4* p4_=(const float4*)(ptr);                 \
  float4 v0_=p4_[0], v1_=p4_[1], v2_=p4_[2], v3_=p4_[3];                         \
  dst[0]=v0_.x; dst[1]=v0_.y; dst[2]=v0_.z; dst[3]=v0_.w;                        \
  dst[4]=v1_.x; dst[5]=v1_.y; dst[6]=v1_.z; dst[7]=v1_.w;                        \
  dst[8]=v2_.x; dst[9]=v2_.y; dst[10]=v2_.z; dst[11]=v2_.w;                      \
  dst[12]=v3_.x; dst[13]=v3_.y; dst[14]=v3_.z; dst[15]=v3_.w; }
// 16 bf16 (32B) -> 16 floats
#define LD16H(dst, ptr) { const v8s* p8_=(const v8s*)(ptr);                      \
  v8s a0_=p8_[0], a1_=p8_[1];                                                    \
  _Pragma("unroll") for(int e_=0;e_<8;++e_){ dst[e_]=bf2f_(a0_[e_]);             \
                                             dst[8+e_]=bf2f_(a1_[e_]); } }
// 16 bf16 reversed: dst[15-m] = ptr[m]
#define LD16HR(dst, ptr) { const v8s* p8_=(const v8s*)(ptr);                     \
  v8s a0_=p8_[0], a1_=p8_[1];                                                    \
  _Pragma("unroll") for(int e_=0;e_<8;++e_){ dst[15-e_]=bf2f_(a0_[e_]);          \
                                             dst[7-e_]=bf2f_(a1_[e_]); } }
// 16 floats -> 16 bf16 (2 v8s stores)
#define ST16H(ptr, srcv) { v8s o0_, o1_;                                         \
  _Pragma("unroll") for(int e_=0;e_<8;++e_){ o0_[e_]=bf16_(srcv[e_]);            \
                                             o1_[e_]=bf16_(srcv[8+e_]); }        \
  ((v8s*)(ptr))[0]=o0_; ((v8s*)(ptr))[1]=o1_; }

// K1 (MFMA): block = 64 pixels, 4 waves; LN -> bf16 hlds; ipw staged per half;
// outputs xcin (bf16, b,d,l) and zT (bf16, d-major silu).
__global__ __launch_bounds__(256) void k1_ln_inproj(
    const float* __restrict__ xmag, const float* __restrict__ xph,
    const float* __restrict__ n1w_, const float* __restrict__ n1b_,
    const float* __restrict__ ipw_, float* __restrict__ ws)
{
  const int i = blockIdx.y;
  const float* xin = i ? xph : xmag;
  const float* n1w = n1w_ + i*CC;
  const float* n1b = n1b_ + i*CC;
  const float* ipw = ipw_ + i*2*DI*CC;   // [256][64]
  float* base = ws + (size_t)i*ISTRIDE;
  const int t = threadIdx.x, lane = t & 63;
  const int wv = __builtin_amdgcn_readfirstlane(t >> 6);
  const int m = lane & 15, quad = lane >> 4;
  const int p0 = blockIdx.x*64;
  const int b = p0 >> 12, l0 = p0 & (LL-1);

  __shared__ short hlds[64*72];
  __shared__ short w1lds[128*72];
  __shared__ float outs[128*68];

  {
    float hn[CC];
    const float* xr = xin + (size_t)(p0 + lane)*CC;
    LD16(hn, xr); LD16((hn+16), xr+16); LD16((hn+32), xr+32); LD16((hn+48), xr+48);
    float s1=0.f, s2=0.f;
    #pragma unroll
    for(int c=0;c<CC;++c){ s1 += hn[c]; s2 += hn[c]*hn[c]; }
    const float mu = s1*(1.f/CC);
    const float rs = rsqrtf(s2*(1.f/CC) - mu*mu + EPSF);
    if(wv==0){
      #pragma unroll
      for(int q=0;q<8;++q){
        v8s s;
        #pragma unroll
        for(int e=0;e<8;++e){
          const int c = q*8+e;
          s[e] = bf16_((hn[c]-mu)*rs*n1w[c] + n1b[c]);
        }
        *(v8s*)&hlds[lane*72 + q*8] = s;
      }
    }
  }

  for(int h=0; h<2; ++h){
    if(h) __syncthreads();
    {
      const int jl = t >> 1, hc = (t & 1)*32;
      const float* src = ipw + (size_t)(h*128 + jl)*64 + hc;
      #pragma unroll
      for(int q=0;q<4;++q){
        const float4 fa = ((const float4*)src)[q*2];
        const float4 fb = ((const float4*)src)[q*2+1];
        v8s s;
        s[0]=bf16_(fa.x); s[1]=bf16_(fa.y); s[2]=bf16_(fa.z); s[3]=bf16_(fa.w);
        s[4]=bf16_(fb.x); s[5]=bf16_(fb.y); s[6]=bf16_(fb.z); s[7]=bf16_(fb.w);
        *(v8s*)&w1lds[jl*72 + hc + q*8] = s;
      }
    }
    __syncthreads();
    #pragma unroll 2
    for(int nt=0; nt<8; ++nt){
      v4f acc = (v4f){0.f,0.f,0.f,0.f};
      #pragma unroll
      for(int ks=0; ks<2; ++ks){
        const v8s a = *(const v8s*)&hlds[(wv*16 + m)*72 + ks*32 + quad*8];
        const v8s bb = *(const v8s*)&w1lds[(nt*16 + m)*72 + ks*32 + quad*8];
        acc = __builtin_amdgcn_mfma_f32_16x16x32_bf16(a, bb, acc, 0, 0, 0);
      }
      *(float4*)&outs[(nt*16 + m)*68 + wv*16 + quad*4] =
          make_float4(acc[0], acc[1], acc[2], acc[3]);
    }
    __syncthreads();
    const int jl = t >> 1, hc = (t & 1)*32;
    if(h==0){
      short* xcb = (short*)(base + OFF_XCIN) + (size_t)b*DI*LL + (size_t)jl*LL + l0 + hc;
      const float* so = &outs[jl*68 + hc];
      ST16H(xcb, so);
      ST16H(xcb+16, (so+16));
    } else {
      short* zr = (short*)(base + OFF_Z) + (size_t)jl*LB + p0 + hc;
      float tmp[32];
      #pragma unroll
      for(int e=0;e<32;++e) tmp[e] = silu_(outs[jl*68 + hc + e]);
      ST16H(zr, tmp);
      ST16H(zr+16, (tmp+16));
    }
  }
}

// K2: depthwise 3x3 conv + silu; bf16 in (xcin), bf16 out (xconv/xconvT).
__global__ __launch_bounds__(256) void k2_dwconv(
    const float* __restrict__ cw_, float* __restrict__ ws)
{
  const int i = blockIdx.y;
  const int bd = blockIdx.x;
  const int d = bd & (DI-1);
  const float* cw = cw_ + i*DI*9 + d*9;
  const short* xcin = (const short*)(ws + (size_t)i*ISTRIDE + OFF_XCIN) + (size_t)bd*LL;
  short* xconv  = (short*)(ws + (size_t)i*ISTRIDE + OFF_XCONV ) + (size_t)bd*LL;
  short* xconvT = (short*)(ws + (size_t)i*ISTRIDE + OFF_XCONVT) + (size_t)bd*LL;
  __shared__ float tin[64*65];
  __shared__ float tout[64*65];
  const int t = threadIdx.x;
  float w9[9];
  #pragma unroll
  for(int q=0;q<9;++q) w9[q] = cw[q];
  for(int idx=t; idx<4096; idx+=256)
    tin[(idx>>6)*65 + (idx&63)] = bf2f_(xcin[idx]);
  __syncthreads();
  const int w = t & 63, hb = (t>>6)*16;
  #pragma unroll
  for(int r=0;r<16;++r){
    const int h = hb + r;
    float acc = 0.f;
    #pragma unroll
    for(int dy=0;dy<3;++dy){
      const int hh = h + dy - 1;
      if(hh>=0 && hh<64){
        #pragma unroll
        for(int dx=0;dx<3;++dx){
          const int ww = w + dx - 1;
          if(ww>=0 && ww<64) acc += tin[hh*65+ww]*w9[dy*3+dx];
        }
      }
    }
    const float o = silu_(acc);
    tout[h*65+w] = o;
    xconv[h*64+w] = bf16_(o);
  }
  __syncthreads();
  const int hcol = t & 63, wb = (t>>6)*16;
  #pragma unroll
  for(int r=0;r<16;++r){
    const int wp = wb + r;
    xconvT[wp*64 + hcol] = bf16_(tout[hcol*65 + wp]);
  }
}

// K3a: paired-direction x_proj from bf16 src; xdbl stored bf16.
__global__ __launch_bounds__(256) void k3a_xproj(
    const float* __restrict__ xpw_, float* __restrict__ ws)
{
  const int i = blockIdx.z;
  const int b = blockIdx.y >> 1;
  const int kp = blockIdx.y & 1;
  const int l = blockIdx.x*256 + threadIdx.x;   // source index
  const short* src = (const short*)(ws + (size_t)i*ISTRIDE + (kp? OFF_XCONVT : OFF_XCONV))
                     + (size_t)b*DI*LL;
  const float* xpwF = xpw_ + i*KK*6*DI + kp*6*DI;
  const float* xpwB = xpw_ + i*KK*6*DI + (kp+2)*6*DI;
  float accF[6] = {0,0,0,0,0,0};
  float accB[6] = {0,0,0,0,0,0};
  for(int d=0; d<DI; ++d){
    const float xv = bf2f_(src[(size_t)d*LL + l]);
    #pragma unroll
    for(int c=0;c<6;++c){
      accF[c] += xv * xpwF[c*DI + d];
      accB[c] += xv * xpwB[c*DI + d];
    }
  }
  short* xdF = (short*)(ws + (size_t)i*ISTRIDE + OFF_XDBL) + (size_t)(b*KK+kp  )*6*LL;
  short* xdB = (short*)(ws + (size_t)i*ISTRIDE + OFF_XDBL) + (size_t)(b*KK+kp+2)*6*LL;
  #pragma unroll
  for(int c=0;c<6;++c) xdF[(size_t)c*LL + l] = bf16_(accF[c]);
  #pragma unroll
  for(int c=0;c<6;++c) xdB[(size_t)c*LL + (LL-1-l)] = bf16_(accB[c]);
}

// K3b: paired fwd/bwd scan (all streams bf16; scan state fp32). (256,3).
__global__ __launch_bounds__(256,3) void k3b_scan(
    const float* __restrict__ dtw_, const float* __restrict__ dtb_,
    const float* __restrict__ alog_, const float* __restrict__ Ds_,
    float* __restrict__ ws)
{
  const int gid = blockIdx.x;           // b*256 + kp*128 + d
  const int i = blockIdx.y;
  const int d  = gid & (DI-1);
  const int kp = (gid >> 7) & 1;
  const int b  = gid >> 8;
  const int t = threadIdx.x, lane = t & 63, wv = t >> 6;
  float* base = ws + (size_t)i*ISTRIDE;
  const short* src = (const short*)(base + (kp? OFF_XCONVT : OFF_XCONV)) + (size_t)(b*DI+d)*LL;
  short*       dst = (short*)(base + (kp? OFF_YT : OFF_Y)) + (size_t)(b*DI+d)*LL;
  const short* xdF = (const short*)(base + OFF_XDBL) + (size_t)(b*KK+kp  )*6*LL;
  const short* xdB = (const short*)(base + OFF_XDBL) + (size_t)(b*KK+kp+2)*6*LL;
  const int kdF = kp*DI + d, kdB = (kp+2)*DI + d;
  const float4 wF = ((const float4*)dtw_)[i*KK*DI + kdF];
  const float4 wB = ((const float4*)dtw_)[i*KK*DI + kdB];
  const float biasF = dtb_[i*KK*DI + kdF], biasB = dtb_[i*KK*DI + kdB];
  const float AvF = -fexp_(alog_[i*KK*DI + kdF]);
  const float AvB = -fexp_(alog_[i*KK*DI + kdB]);
  const float Dsum = Ds_[i*KK*DI + kdF] + Ds_[i*KK*DI + kdB];
  const int l0 = t*16;
  const int s0 = LL - 16 - l0;

  float vX[16], aF[16], bF[16], aB[16], bB[16];
  float fA = 1.f, fB = 0.f, gA = 1.f, gB = 0.f;
  LD16H(vX, src + l0);

  {
    float pre[16], r0[16];
    LD16H(r0, xdF + 0*LL + l0);
    #pragma unroll
    for(int j=0;j<16;++j) pre[j] = biasF + wF.x*r0[j];
    LD16H(r0, xdF + 1*LL + l0);
    #pragma unroll
    for(int j=0;j<16;++j) pre[j] += wF.y*r0[j];
    LD16H(r0, xdF + 2*LL + l0);
    #pragma unroll
    for(int j=0;j<16;++j) pre[j] += wF.z*r0[j];
    LD16H(r0, xdF + 3*LL + l0);
    #pragma unroll
    for(int j=0;j<16;++j) pre[j] += wF.w*r0[j];
    LD16H(r0, xdF + 4*LL + l0);   // Bs
    #pragma unroll
    for(int j=0;j<16;++j){
      const float delta = softplusf_(pre[j]);
      aF[j] = fexp_(delta*AvF);
      bF[j] = delta*r0[j]*vX[j];
      fB = fB*aF[j] + bF[j];
      fA *= aF[j];
    }
  }
  {
    float pre[16], r0[16];
    LD16HR(r0, xdB + 0*LL + s0);
    #pragma unroll
    for(int j=0;j<16;++j) pre[j] = biasB + wB.x*r0[j];
    LD16HR(r0, xdB + 1*LL + s0);
    #pragma unroll
    for(int j=0;j<16;++j) pre[j] += wB.y*r0[j];
    LD16HR(r0, xdB + 2*LL + s0);
    #pragma unroll
    for(int j=0;j<16;++j) pre[j] += wB.z*r0[j];
    LD16HR(r0, xdB + 3*LL + s0);
    #pragma unroll
    for(int j=0;j<16;++j) pre[j] += wB.w*r0[j];
    LD16HR(r0, xdB + 4*LL + s0);  // Bs reversed
    #pragma unroll
    for(int j=15;j>=0;--j){
      const float delta = softplusf_(pre[j]);
      aB[j] = fexp_(delta*AvB);
      bB[j] = delta*r0[j]*vX[j];
      gB = gB*aB[j] + bB[j];
      gA *= aB[j];
    }
  }

  #pragma unroll
  for(int off=1; off<64; off<<=1){
    const float aL = __shfl_up(fA, off);
    const float bL = __shfl_up(fB, off);
    if(lane >= off){ fB = bL*fA + fB; fA = aL*fA; }
  }
  float pA = __shfl_up(fA, 1), pB = __shfl_up(fB, 1);
  if(lane==0){ pA=1.f; pB=0.f; }
  #pragma unroll
  for(int off=1; off<64; off<<=1){
    const float aR = __shfl_down(gA, off);
    const float bR = __shfl_down(gB, off);
    if(lane + off < 64){ gB = gA*bR + gB; gA = gA*aR; }
  }
  float qA = __shfl_down(gA, 1), qB = __shfl_down(gB, 1);
  if(lane==63){ qA=1.f; qB=0.f; }

  __shared__ float wAg[4], wBg[4], vAg[4], vBg[4];
  if(lane==63){ wAg[wv]=fA; wBg[wv]=fB; }
  if(lane==0){ vAg[wv]=gA; vBg[wv]=gB; }
  __syncthreads();
  float eB=0.f;
  for(int u=0; u<wv; ++u){ eB = wAg[u]*eB + wBg[u]; }
  float rB=0.f;
  for(int u=3; u>wv; --u){ rB = vAg[u]*rB + vBg[u]; }

  float hf = pA*eB + pB;
  float hb = qA*rB + qB;

  float out[16], cc[16];
  LD16H(cc, xdF + 5*LL + l0);
  #pragma unroll
  for(int j=0;j<16;++j){
    hf = aF[j]*hf + bF[j];
    out[j] = hf*cc[j] + Dsum*vX[j];
  }
  LD16HR(cc, xdB + 5*LL + s0);
  #pragma unroll
  for(int j=15;j>=0;--j){
    hb = aB[j]*hb + bB[j];
    out[j] += hb*cc[j];
  }
  ST16H(dst + l0, out);
}

// K3c: combine y + transpose(yT) (bf16 in) into d-major bf16 ycombT[d][b*LL+l].
__global__ __launch_bounds__(256) void k3c_combine(float* __restrict__ ws)
{
  const int i = blockIdx.y;
  const int b = blockIdx.x >> 4;
  const int tile = blockIdx.x & 15;
  const int h0 = (tile >> 2) * 16, w0 = (tile & 3) * 16;
  const int t = threadIdx.x;
  float* base = ws + (size_t)i*ISTRIDE;
  const short* y  = (const short*)(base + OFF_Y);
  const short* yT = (const short*)(base + OFF_YT);
  short* ycT = (short*)(base + OFF_YCOMBT);
  __shared__ float ytile[16*16*16];
  __shared__ float ytT[16*16*17];
  const int r0 = t >> 4, c0 = t & 15;
  const int hi = t >> 4, wi = t & 15;
  const int l = (h0 + hi)*64 + (w0 + wi);
  for(int dc=0; dc<8; ++dc){
    #pragma unroll 4
    for(int dd=0; dd<16; ++dd){
      const int d = dc*16 + dd;
      const size_t rb = (size_t)(b*DI + d)*LL;
      ytile[dd*256 + t] = bf2f_(y[rb + (size_t)(h0 + r0)*64 + (w0 + c0)]);
      ytT[dd*272 + r0*17 + c0] = bf2f_(yT[rb + (size_t)(w0 + r0)*64 + (h0 + c0)]);
    }
    __syncthreads();
    #pragma unroll 4
    for(int dd=0; dd<16; ++dd){
      const int d = dc*16 + dd;
      ycT[(size_t)d*LB + b*LL + l] = bf16_(ytile[dd*256 + t] + ytT[dd*272 + wi*17 + hi]);
    }
    __syncthreads();
  }
}

// K4a (MFMA): block = 64 pixels, 4 waves; LN via padded LDS stats (bf16 in);
// out_proj mfma; +xin -> xnew (bf16).
__global__ __launch_bounds__(256) void k4a_proj(
    const float* __restrict__ xmag, const float* __restrict__ xph,
    const float* __restrict__ onw_, const float* __restrict__ onb_,
    const float* __restrict__ opw_, float* __restrict__ ws)
{
  const int i = blockIdx.y;
  const float* xin = i ? xph : xmag;
  const float* onw = onw_ + i*DI;
  const float* onb = onb_ + i*DI;
  const float* opw = opw_ + i*CC*DI;     // [o][d] = [64][128]
  float* base = ws + (size_t)i*ISTRIDE;
  const short* ycT = (const short*)(base + OFF_YCOMBT);
  const short* zT  = (const short*)(base + OFF_Z);
  const int t = threadIdx.x, lane = t & 63;
  const int wv = __builtin_amdgcn_readfirstlane(t >> 6);
  const int m = lane & 15, quad = lane >> 4;
  const int p0 = blockIdx.x*64;
  const int p = p0 + lane;

  __shared__ short ynlds[64*136];
  __shared__ short wlds[64*136];
  __shared__ float st[64][9];

  float yv[32];
  float s1=0.f, s2=0.f;
  #pragma unroll 8
  for(int c=0;c<32;++c){
    const float v = bf2f_(ycT[(size_t)(wv*32+c)*LB + p]);
    yv[c]=v; s1+=v; s2+=v*v;
  }
  st[lane][wv*2]=s1; st[lane][wv*2+1]=s2;
  __syncthreads();
  const float S1 = st[lane][0]+st[lane][2]+st[lane][4]+st[lane][6];
  const float S2 = st[lane][1]+st[lane][3]+st[lane][5]+st[lane][7];
  const float mu = S1*(1.f/DI);
  const float rs = rsqrtf(S2*(1.f/DI) - mu*mu + EPSF);
  #pragma unroll
  for(int cq=0;cq<8;++cq){
    short4 s4;
    #pragma unroll
    for(int e=0;e<4;++e){
      const int c = cq*4+e;
      const int d = wv*32 + c;
      ((short*)&s4)[e] = bf16_(((yv[c]-mu)*rs*onw[d] + onb[d]) * bf2f_(zT[(size_t)d*LB + p]));
    }
    *(short4*)&ynlds[lane*136 + wv*32 + cq*4] = s4;
  }
  {
    const int ol = t >> 2, seg = (t & 3)*32;
    const float* src = opw + (size_t)ol*DI + seg;
    #pragma unroll
    for(int q=0;q<4;++q){
      const float4 fa = ((const float4*)src)[q*2];
      const float4 fb = ((const float4*)src)[q*2+1];
      v8s s;
      s[0]=bf16_(fa.x); s[1]=bf16_(fa.y); s[2]=bf16_(fa.z); s[3]=bf16_(fa.w);
      s[4]=bf16_(fb.x); s[5]=bf16_(fb.y); s[6]=bf16_(fb.z); s[7]=bf16_(fb.w);
      *(v8s*)&wlds[ol*136 + seg + q*8] = s;
    }
  }
  __syncthreads();

  v4f accs[4];
  #pragma unroll
  for(int nt=0; nt<4; ++nt){
    v4f acc = (v4f){0.f,0.f,0.f,0.f};
    #pragma unroll
    for(int ks=0; ks<4; ++ks){
      const v8s a = *(const v8s*)&ynlds[(wv*16 + m)*136 + ks*32 + quad*8];
      const v8s b = *(const v8s*)&wlds[(nt*16 + m)*136 + ks*32 + quad*8];
      acc = __builtin_amdgcn_mfma_f32_16x16x32_bf16(a, b, acc, 0, 0, 0);
    }
    accs[nt] = acc;
  }
  short* xnew = (short*)(base + OFF_XNEW);
  #pragma unroll
  for(int nt=0; nt<4; ++nt){
    #pragma unroll
    for(int r=0;r<4;++r){
      const int pp = p0 + wv*16 + quad*4 + r;
      const int o = nt*16 + m;
      xnew[(size_t)pp*CC + o] = bf16_(accs[nt][r] + xin[(size_t)pp*CC + o]);
    }
  }
}

// K4b (MFMA): 64-pixel tile, 4 waves; xnew bf16 in; LN fp32 -> bf16 H; fc1/fc2
// mfma; sbuf bf16 out.
__global__ __launch_bounds__(256) void k4b_mlp(
    const float* __restrict__ n2w_, const float* __restrict__ n2b_,
    const float* __restrict__ f1w_, const float* __restrict__ f1b_,
    const float* __restrict__ f2w_, const float* __restrict__ f2b_,
    float* __restrict__ ws)
{
  const int i = blockIdx.y;
  const float* n2w = n2w_ + i*CC;
  const float* n2b = n2b_ + i*CC;
  const float* f1w = f1w_ + i*256*64;    // [j][c]
  const float* f1b = f1b_ + i*256;
  const float* f2w = f2w_ + i*64*256;    // [o][j]
  const float* f2b = f2b_ + i*CC;
  float* base = ws + (size_t)i*ISTRIDE;
  const short* xnew = (const short*)(base + OFF_XNEW);
  const int t = threadIdx.x, lane = t & 63;
  const int wv = __builtin_amdgcn_readfirstlane(t >> 6);
  const int m = lane & 15, quad = lane >> 4;
  const int p0 = blockIdx.x*64;

  __shared__ short hlds[64*72];
  __shared__ short w1lds[128*72];
  __shared__ short glds[64*136];
  __shared__ short w2lds[64*136];

  {
    float h2[64];
    const short* xr = xnew + (size_t)(p0 + lane)*CC;
    LD16H(h2, xr); LD16H((h2+16), xr+16); LD16H((h2+32), xr+32); LD16H((h2+48), xr+48);
    float s1=0.f, s2=0.f;
    #pragma unroll
    for(int c=0;c<CC;++c){ s1 += h2[c]; s2 += h2[c]*h2[c]; }
    const float mu = s1*(1.f/CC);
    const float rs = rsqrtf(s2*(1.f/CC) - mu*mu + EPSF);
    if(wv==0){
      #pragma unroll
      for(int q=0;q<8;++q){
        v8s s;
        #pragma unroll
        for(int e=0;e<8;++e){
          const int c = q*8+e;
          s[e] = bf16_((h2[c]-mu)*rs*n2w[c] + n2b[c]);
        }
        *(v8s*)&hlds[lane*72 + q*8] = s;
      }
    }
  }

  v4f acc2[4];
  #pragma unroll
  for(int n=0;n<4;++n) acc2[n] = (v4f){0.f,0.f,0.f,0.f};

  for(int h=0; h<2; ++h){
    if(h) __syncthreads();
    {
      const int jl = t >> 1, hc = (t & 1)*32;
      const float* src = f1w + (size_t)(h*128 + jl)*64 + hc;
      #pragma unroll
      for(int q=0;q<4;++q){
        const float4 fa = ((const float4*)src)[q*2];
        const float4 fb = ((const float4*)src)[q*2+1];
        v8s s;
        s[0]=bf16_(fa.x); s[1]=bf16_(fa.y); s[2]=bf16_(fa.z); s[3]=bf16_(fa.w);
        s[4]=bf16_(fb.x); s[5]=bf16_(fb.y); s[6]=bf16_(fb.z); s[7]=bf16_(fb.w);
        *(v8s*)&w1lds[jl*72 + hc + q*8] = s;
      }
    }
    {
      const int ol = t >> 2, seg = (t & 3)*32;
      const float* src = f2w + (size_t)ol*256 + h*128 + seg;
      #pragma unroll
      for(int q=0;q<4;++q){
        const float4 fa = ((const float4*)src)[q*2];
        const float4 fb = ((const float4*)src)[q*2+1];
        v8s s;
        s[0]=bf16_(fa.x); s[1]=bf16_(fa.y); s[2]=bf16_(fa.z); s[3]=bf16_(fa.w);
        s[4]=bf16_(fb.x); s[5]=bf16_(fb.y); s[6]=bf16_(fb.z); s[7]=bf16_(fb.w);
        *(v8s*)&w2lds[ol*136 + seg + q*8] = s;
      }
    }
    __syncthreads();
    #pragma unroll 2
    for(int nt=0; nt<8; ++nt){
      v4f acc = (v4f){0.f,0.f,0.f,0.f};
      #pragma unroll
      for(int ks=0; ks<2; ++ks){
        const v8s a = *(const v8s*)&hlds[(wv*16 + m)*72 + ks*32 + quad*8];
        const v8s b = *(const v8s*)&w1lds[(nt*16 + m)*72 + ks*32 + quad*8];
        acc = __builtin_amdgcn_mfma_f32_16x16x32_bf16(a, b, acc, 0, 0, 0);
      }
      const float bj = f1b[h*128 + nt*16 + m];
      #pragma unroll
      for(int r=0;r<4;++r){
        glds[(wv*16 + quad*4 + r)*136 + nt*16 + m] = bf16_(geluf_(acc[r] + bj));
      }
    }
    #pragma unroll
    for(int nt=0; nt<4; ++nt){
      v4f acc = acc2[nt];
      #pragma unroll
      for(int ks=0; ks<4; ++ks){
        const v8s a = *(const v8s*)&glds[(wv*16 + m)*136 + ks*32 + quad*8];
        const v8s b = *(const v8s*)&w2lds[(nt*16 + m)*136 + ks*32 + quad*8];
        acc = __builtin_amdgcn_mfma_f32_16x16x32_bf16(a, b, acc, 0, 0, 0);
      }
      acc2[nt] = acc;
    }
  }

  short* sb = (short*)(base + OFF_SB);
  #pragma unroll
  for(int nt=0; nt<4; ++nt){
    const float bo = f2b[nt*16 + m];
    #pragma unroll
    for(int r=0;r<4;++r){
      const int p = p0 + wv*16 + quad*4 + r;
      const int o = nt*16 + m;
      sb[(size_t)p*CC + o] = bf16_(acc2[nt][r] + bo + bf2f_(xnew[(size_t)p*CC + o]));
    }
  }
}

// K5: s = inst0 + inst1 (bf16 in, fp32 out); 8 elems/thread; both output halves
__global__ __launch_bounds__(256) void k5_final(
    const float* __restrict__ ws, float* __restrict__ out)
{
  const int idx = blockIdx.x*256 + threadIdx.x;   // v8s index
  const v8s a = ((const v8s*)(ws + OFF_SB))[idx];
  const v8s b = ((const v8s*)(ws + ISTRIDE + OFF_SB))[idx];
  float4 v0, v1;
  v0.x = bf2f_(a[0])+bf2f_(b[0]); v0.y = bf2f_(a[1])+bf2f_(b[1]);
  v0.z = bf2f_(a[2])+bf2f_(b[2]); v0.w = bf2f_(a[3])+bf2f_(b[3]);
  v1.x = bf2f_(a[4])+bf2f_(b[4]); v1.y = bf2f_(a[5])+bf2f_(b[5]);
  v1.z = bf2f_(a[6])+bf2f_(b[6]); v1.w = bf2f_(a[7])+bf2f_(b[7]);
  ((float4*)out)[idx*2]   = v0;
  ((float4*)out)[idx*2+1] = v1;
  ((float4*)out)[NPIX/4 + idx*2]   = v0;
  ((float4*)out)[NPIX/4 + idx*2+1] = v1;
}

extern "C" void kernel_launch(void* const* d_in, const int* in_sizes, int n_in,
                              void* d_out, int out_size, void* d_ws, size_t ws_size,
                              hipStream_t stream)
{
  const float* mag  = (const float*)d_in[0];
  const float* ph   = (const float*)d_in[1];
  const float* n1w  = (const float*)d_in[2];
  const float* n1b  = (const float*)d_in[3];
  const float* ipw  = (const float*)d_in[4];
  const float* cw   = (const float*)d_in[5];
  const float* xpw  = (const float*)d_in[6];
  const float* dtw  = (const float*)d_in[7];
  const float* dtb  = (const float*)d_in[8];
  const float* alog = (const float*)d_in[9];
  const float* Ds   = (const float*)d_in[10];
  const float* onw  = (const float*)d_in[11];
  const float* onb  = (const float*)d_in[12];
  const float* opw  = (const float*)d_in[13];
  const float* n2w  = (const float*)d_in[14];
  const float* n2b  = (const float*)d_in[15];
  const float* f1w  = (const float*)d_in[16];
  const float* f1b  = (const float*)d_in[17];
  const float* f2w  = (const float*)d_in[18];
  const float* f2b  = (const float*)d_in[19];
  float* ws = (float*)d_ws;
  float* out = (float*)d_out;

  k1_ln_inproj<<<dim3(512,2),  256, 0, stream>>>(mag, ph, n1w, n1b, ipw, ws);
  k2_dwconv   <<<dim3(1024,2), 256, 0, stream>>>(cw, ws);
  k3a_xproj   <<<dim3(16,16,2),256, 0, stream>>>(xpw, ws);
  k3b_scan    <<<dim3(2048,2), 256, 0, stream>>>(dtw, dtb, alog, Ds, ws);
  k3c_combine <<<dim3(128,2),  256, 0, stream>>>(ws);
  k4a_proj    <<<dim3(512,2),  256, 0, stream>>>(mag, ph, onw, onb, opw, ws);
  k4b_mlp     <<<dim3(512,2),  256, 0, stream>>>(n2w, n2b, f1w, f1b, f2w, f2b, ws);
  k5_final    <<<dim3(1024),   256, 0, stream>>>(ws, out);
}